// Round 5
// baseline (1913.926 us; speedup 1.0000x reference)
//
#include <hip/hip_runtime.h>
#include <cmath>

// ---- constants from the reference ----
constexpr float ACT_NORM = 1.6789717f;
constexpr float PW0      = 0.20412414523193154f;   // sqrt(1/24)  (== pw1/sqrt3)
constexpr float PW1      = 0.35355339059327373f;   // sqrt(3/24)
constexpr float PWREC    = 0.05590169943749474f;   // sqrt(1/320)
constexpr float INV_SQ3  = 0.57735026918962576f;

__device__ __forceinline__ float silu_n(float x) {
  return x / (1.f + __expf(-x)) * ACT_NORM;
}

__device__ __forceinline__ float bcast_lane(float v, int k) {
  return __int_as_float(__builtin_amdgcn_readlane(__float_as_int(v), k));
}

// ---------------- node embedding: node[:, :16] = mlp(x), geo = 0 ----------------
__global__ __launch_bounds__(256)
void emb_kernel(const float* __restrict__ x, const float* __restrict__ w0,
                const float* __restrict__ w1, float* __restrict__ node, int N) {
  const int lane = threadIdx.x & 63;
  const int lw   = threadIdx.x >> 6;
  const int gw   = blockIdx.x * 4 + lw;
  __shared__ float sH[4][64];
  const bool valid = gw < N;
  const int n = valid ? gw : 0;
  float acc = 0.f;
#pragma unroll
  for (int a = 0; a < 10; ++a) acc = fmaf(x[n * 10 + a], w0[a * 64 + lane], acc);
  acc *= 0.31622776601683794f;   // 1/sqrt(10)
  sH[lw][lane] = silu_n(acc);
  __syncthreads();
  if (valid) {
    if (lane < 16) {
      float o = 0.f;
#pragma unroll
      for (int k = 0; k < 64; ++k) o = fmaf(sH[lw][k], w1[k * 16 + lane], o);
      node[(size_t)n * 40 + lane] = o * 0.125f;  // 1/sqrt(64)
    } else if (lane < 40) {
      node[(size_t)n * 40 + lane] = 0.f;
    }
  }
}

// ---------------- node update (per mp step) ----------------
__global__ __launch_bounds__(256)
void upd_kernel(float* __restrict__ node, const float* __restrict__ msgs,
                const float* __restrict__ w0, const float* __restrict__ w1,
                const float* __restrict__ imp, float geo_scale, float inv_sqrt_deg, int N) {
  const int lane = threadIdx.x & 63;
  const int lw   = threadIdx.x >> 6;
  const int gw   = blockIdx.x * 4 + lw;
  __shared__ float sIn[4][32];
  __shared__ float sH[4][64];
  const bool valid = gw < N;
  const int n = valid ? gw : 0;
  const float mscale = imp[0] * inv_sqrt_deg;
  if (lane < 16)      sIn[lw][lane] = msgs[(size_t)n * 40 + lane] * mscale;
  else if (lane < 32) sIn[lw][lane] = node[(size_t)n * 40 + lane - 16];
  __syncthreads();
  float acc = 0.f;
#pragma unroll
  for (int a = 0; a < 32; ++a) acc = fmaf(sIn[lw][a], w0[a * 64 + lane], acc);
  acc *= 0.17677669529663687f;   // 1/sqrt(32)
  sH[lw][lane] = silu_n(acc);
  __syncthreads();
  if (valid) {
    if (lane < 16) {
      float o = 0.f;
#pragma unroll
      for (int k = 0; k < 64; ++k) o = fmaf(sH[lw][k], w1[k * 16 + lane], o);
      node[(size_t)n * 40 + lane] = o * 0.125f;
    } else if (lane < 40) {
      const size_t gi = (size_t)n * 40 + lane;
      node[gi] = fmaf(msgs[gi], mscale, node[gi]) * geo_scale;
    }
  }
}

// ---------------- inter-edge: distance embedding -> both hidden vectors ----------------
__global__ __launch_bounds__(256)
void inter_h_kernel(const float* __restrict__ pos, const int* __restrict__ iei,
                    const float* __restrict__ lw0, const float* __restrict__ rw0,
                    float* __restrict__ hL, float* __restrict__ hR, int EI) {
  const int lane = threadIdx.x & 63;
  const int lw   = threadIdx.x >> 6;
  const int gw   = blockIdx.x * 4 + lw;
  __shared__ float sD[4][20];
  const bool valid = gw < EI;
  const int e = valid ? gw : 0;
  const int rec = iei[e], lig = iei[EI + e];
  const float dx = pos[lig * 3]     - pos[rec * 3];
  const float dy = pos[lig * 3 + 1] - pos[rec * 3 + 1];
  const float dz = pos[lig * 3 + 2] - pos[rec * 3 + 2];
  const float d = sqrtf(dx * dx + dy * dy + dz * dz);
  if (lane < 20) {
    const float diff = d * 4.2f - (float)(lane + 1);
    const float t1 = diff + 1.f, t2 = 1.f - diff;
    float v = 0.f;
    if (t1 > 0.f && t2 > 0.f) {
      const float C = 1.14136f * 7.3890560989306495f * 4.4721359549995794f; // 1.14136*e^2*sqrt(20)
      v = C * __expf(-1.f / t1 - 1.f / t2);
    }
    sD[lw][lane] = v;
  }
  __syncthreads();
  float a0 = 0.f, a1 = 0.f;
#pragma unroll
  for (int b = 0; b < 20; ++b) {
    const float db = sD[lw][b];
    a0 = fmaf(db, lw0[b * 64 + lane], a0);
    a1 = fmaf(db, rw0[b * 64 + lane], a1);
  }
  a0 *= 0.22360679774997896f;  // 1/sqrt(20)
  a1 *= 0.22360679774997896f;
  if (valid) {
    hL[(size_t)e * 64 + lane] = silu_n(a0);
    hR[(size_t)e * 64 + lane] = silu_n(a1);
  }
}

// ---------------- fused edge MLP (layer2) + node x sh tensor product ----------------
// h lives in 1 VGPR/edge (broadcast per-k via v_readlane); weight cols t=0..3 in LDS
// [k][lane][4]; cols t=4..8 double-buffer-prefetched from global (L2-hot).
// LDS 75.5KB -> 2 blocks/CU. S=6 edges/wave. Layer scale 1/8 folded into h.
template <int MODE>
__global__ __launch_bounds__(512, 4)
void tp_kernel(const float* __restrict__ node, const float* __restrict__ pos,
               const int* __restrict__ ei, const float* __restrict__ eattr,
               const float* __restrict__ w0, const float* __restrict__ W1,
               const float* __restrict__ hSrc, float* __restrict__ out, int E) {
  __shared__ __align__(16) float sA[64 * 64 * 4];   // 65536 B: cols t=0..3
  __shared__ float sF[8][6][52];                    //  9984 B -> 75520 B total
  const int tid  = threadIdx.x;
  const int lane = tid & 63;
  const int wv   = tid >> 6;

  // stage sA once per block (cols 0..255 -> [k][lane][4])
  for (int j = tid; j < 4096; j += 512) {
    const int k = j >> 6, l = j & 63;
    const float* src = &W1[k * 576 + l];
    float4 va;
    va.x = src[0]; va.y = src[64]; va.z = src[128]; va.w = src[192];
    *(float4*)&sA[j * 4] = va;
  }
  __syncthreads();

  float w0r[5];
  if (MODE == 0) {
#pragma unroll
    for (int a = 0; a < 5; ++a) w0r[a] = w0[a * 64 + lane] * 0.4472135954999579f; // 1/sqrt(5)
  }
  const float* Wg = W1 + 256;   // cols t=4..8: Wg[k*576 + j*64 + lane], j=0..4

  const int nB = (E + 47) / 48;
  for (int b = blockIdx.x; b < nB; b += (int)gridDim.x) {
    const int ebase = b * 48 + wv * 6;
    int outn[6];
    bool val[6];
    float h[6];
#pragma unroll
    for (int s = 0; s < 6; ++s) {
      const int e0 = ebase + s;
      val[s] = e0 < E;
      const int e = val[s] ? e0 : 0;
      const int ia = ei[e], ib = ei[E + e];
      int nsrc;
      if (MODE == 0) { nsrc = ia; outn[s] = ib; }   // src features, scatter to dst
      else           { nsrc = ib; outn[s] = e;  }   // lig features, store per edge
      const float vx = pos[ib * 3]     - pos[ia * 3];
      const float vy = pos[ib * 3 + 1] - pos[ia * 3 + 1];
      const float vz = pos[ib * 3 + 2] - pos[ia * 3 + 2];
      const float rn = rsqrtf(vx * vx + vy * vy + vz * vz);
      const float rx = vx * rn, ry = vy * rn, rz = vz * rn;
      if (MODE == 0) {
        float acc = 0.f;
#pragma unroll
        for (int a = 0; a < 5; ++a) acc = fmaf(eattr[(size_t)e * 5 + a], w0r[a], acc);
        h[s] = silu_n(acc) * 0.125f;          // fold 1/sqrt(64)
      } else {
        h[s] = hSrc[(size_t)e * 64 + lane] * 0.125f;
      }
      if (lane < 16) {
        sF[wv][s][lane] = node[(size_t)nsrc * 40 + lane];           // xs
      } else if (lane < 24) {
        const int u = lane - 16;
        const float x0 = node[(size_t)nsrc * 40 + 16 + u * 3];
        const float x1 = node[(size_t)nsrc * 40 + 16 + u * 3 + 1];
        const float x2 = node[(size_t)nsrc * 40 + 16 + u * 3 + 2];
        sF[wv][s][16 + u]         = x0 * rx + x1 * ry + x2 * rz;    // dot(xv, r^)
        sF[wv][s][24 + u * 3]     = x0;                             // xv
        sF[wv][s][24 + u * 3 + 1] = x1;
        sF[wv][s][24 + u * 3 + 2] = x2;
      } else if (lane < 27) {
        sF[wv][s][48 + (lane - 24)] = (lane == 24) ? rx : ((lane == 25) ? ry : rz);
      }
    }
    // no barrier: sF slices per-wave private; h per-lane registers

    float wacc[6][9];
#pragma unroll
    for (int s = 0; s < 6; ++s)
#pragma unroll
      for (int t = 0; t < 9; ++t) wacc[s][t] = 0.f;

    float bufA[4][5], bufB[4][5];
    auto loadbuf = [&](int kbase, float (&buf)[4][5]) {
#pragma unroll
      for (int kk = 0; kk < 4; ++kk)
#pragma unroll
        for (int j = 0; j < 5; ++j)
          buf[kk][j] = Wg[(size_t)(kbase + kk) * 576 + j * 64 + lane];
    };
    auto compute4 = [&](int kbase, const float (&buf)[4][5]) {
#pragma unroll
      for (int kk = 0; kk < 4; ++kk) {
        const int k = kbase + kk;
        const float4 wa = *(const float4*)&sA[(k * 64 + lane) * 4];
#pragma unroll
        for (int s = 0; s < 6; ++s) {
          const float hv = bcast_lane(h[s], k);
          wacc[s][0] = fmaf(hv, wa.x,       wacc[s][0]);
          wacc[s][1] = fmaf(hv, wa.y,       wacc[s][1]);
          wacc[s][2] = fmaf(hv, wa.z,       wacc[s][2]);
          wacc[s][3] = fmaf(hv, wa.w,       wacc[s][3]);
          wacc[s][4] = fmaf(hv, buf[kk][0], wacc[s][4]);
          wacc[s][5] = fmaf(hv, buf[kk][1], wacc[s][5]);
          wacc[s][6] = fmaf(hv, buf[kk][2], wacc[s][6]);
          wacc[s][7] = fmaf(hv, buf[kk][3], wacc[s][7]);
          wacc[s][8] = fmaf(hv, buf[kk][4], wacc[s][8]);
        }
      }
    };

    loadbuf(0, bufA);
    for (int k8 = 0; k8 < 64; k8 += 8) {
      loadbuf(k8 + 4, bufB);       // in flight during bufA compute
      compute4(k8, bufA);
      if (k8 < 56) loadbuf(k8 + 8, bufA);
      compute4(k8 + 4, bufB);
    }

    // TP epilogue. t=0..5 scalar-path (out col = lane&15, U=(lane>>4)+4t),
    // t=6..8 vector-path (out col = lane&7, U=(lane>>3)+8(t-6)).
    const int ub  = lane >> 4;
    const int ub2 = lane >> 3;
#pragma unroll
    for (int s = 0; s < 6; ++s) {
      float cs = 0.f;
#pragma unroll
      for (int t = 0; t < 6; ++t)
        cs = fmaf(PW0 * sF[wv][s][ub + 4 * t], wacc[s][t], cs);
      cs += __shfl_xor(cs, 16);
      cs += __shfl_xor(cs, 32);

      const float rx = sF[wv][s][48], ry = sF[wv][s][49], rz = sF[wv][s][50];
      const float sxw = PW1 * (sF[wv][s][ub2] * wacc[s][6] + sF[wv][s][ub2 + 8] * wacc[s][7]);
      float cv0 = fmaf(PW0 * sF[wv][s][24 + ub2 * 3],     wacc[s][8], sxw * rx);
      float cv1 = fmaf(PW0 * sF[wv][s][24 + ub2 * 3 + 1], wacc[s][8], sxw * ry);
      float cv2 = fmaf(PW0 * sF[wv][s][24 + ub2 * 3 + 2], wacc[s][8], sxw * rz);
      cv0 += __shfl_xor(cv0, 8); cv0 += __shfl_xor(cv0, 16); cv0 += __shfl_xor(cv0, 32);
      cv1 += __shfl_xor(cv1, 8); cv1 += __shfl_xor(cv1, 16); cv1 += __shfl_xor(cv1, 32);
      cv2 += __shfl_xor(cv2, 8); cv2 += __shfl_xor(cv2, 16); cv2 += __shfl_xor(cv2, 32);

      if (val[s]) {
        const size_t ob = (size_t)outn[s] * 40;
        if (MODE == 0) {
          if (lane < 16) atomicAdd(&out[ob + lane], cs);
          if (lane < 8) {
            atomicAdd(&out[ob + 16 + lane * 3],     cv0);
            atomicAdd(&out[ob + 16 + lane * 3 + 1], cv1);
            atomicAdd(&out[ob + 16 + lane * 3 + 2], cv2);
          }
        } else {
          if (lane < 16) out[ob + lane] = cs;
          if (lane < 8) {
            out[ob + 16 + lane * 3]     = cv0;
            out[ob + 16 + lane * 3 + 1] = cv1;
            out[ob + 16 + lane * 3 + 2] = cv2;
          }
        }
      }
    }
  }
}

// ---------------- rec MLP (layer2, 64x2560) + node x node -> 8x0e TP ----------------
// Persistent 512-col weight chunk per block (blockIdx.y = chunk 0..4), staged ONCE.
// Edge loop barrier-free; partial outputs accumulated via atomicAdd (out zeroed first).
// Chunk cg<4 is entirely the scalar CG region (uv<256); cg==4 entirely vector.
__global__ __launch_bounds__(512, 2)
void rec_kernel(const float* __restrict__ node, const float* __restrict__ ligE,
                const int* __restrict__ iei, const float* __restrict__ RW1,
                const float* __restrict__ hR, float* __restrict__ out, int EI) {
  __shared__ __align__(16) float sWa[64 * 64 * 4];  // 65536 B: cols t=0..3 of chunk
  __shared__ __align__(16) float sWb[64 * 64 * 4];  // 65536 B: cols t=4..7
  __shared__ float sF[8][8][80];                    // 20480 B -> 151552 B total
  const int tid  = threadIdx.x;
  const int lane = tid & 63;
  const int wv   = tid >> 6;
  const int cg   = blockIdx.y;                      // 0..4

  for (int j = tid; j < 4096; j += 512) {
    const int k = j >> 6, l = j & 63;
    const float* src = &RW1[(size_t)k * 2560 + cg * 512 + l];
    float4 a, bb;
    a.x  = src[0];   a.y  = src[64];  a.z  = src[128]; a.w  = src[192];
    bb.x = src[256]; bb.y = src[320]; bb.z = src[384]; bb.w = src[448];
    *(float4*)&sWa[j * 4] = a;
    *(float4*)&sWb[j * 4] = bb;
  }
  __syncthreads();

  const int nB = (EI + 63) >> 6;
  for (int b = blockIdx.x; b < nB; b += (int)gridDim.x) {
    const int ebase = b * 64 + wv * 8;
    bool val[8]; int eidx[8]; float h[8];
#pragma unroll
    for (int s = 0; s < 8; ++s) {
      const int e0 = ebase + s;
      val[s] = e0 < EI;
      const int e = val[s] ? e0 : 0;
      eidx[s] = e;
      h[s] = hR[(size_t)e * 64 + lane] * 0.125f;    // fold 1/sqrt(64)
      const int rec = iei[e];
      if (lane < 40) {
        sF[wv][s][lane]      = ligE[(size_t)e * 40 + lane];        // xs_l[0:16], xv_l[16:40]
        sF[wv][s][40 + lane] = node[(size_t)rec * 40 + lane];      // ys_r[40:56], yv_r[56:80]
      }
    }

    float wacc[8][8];
#pragma unroll
    for (int s = 0; s < 8; ++s)
#pragma unroll
      for (int t = 0; t < 8; ++t) wacc[s][t] = 0.f;

    for (int k4 = 0; k4 < 64; k4 += 4) {
#pragma unroll
      for (int kk = 0; kk < 4; ++kk) {
        const int k = k4 + kk;
        const float4 wa = *(const float4*)&sWa[(k * 64 + lane) * 4];
        const float4 wb = *(const float4*)&sWb[(k * 64 + lane) * 4];
#pragma unroll
        for (int s = 0; s < 8; ++s) {
          const float hv = bcast_lane(h[s], k);
          wacc[s][0] = fmaf(hv, wa.x, wacc[s][0]);
          wacc[s][1] = fmaf(hv, wa.y, wacc[s][1]);
          wacc[s][2] = fmaf(hv, wa.z, wacc[s][2]);
          wacc[s][3] = fmaf(hv, wa.w, wacc[s][3]);
          wacc[s][4] = fmaf(hv, wb.x, wacc[s][4]);
          wacc[s][5] = fmaf(hv, wb.y, wacc[s][5]);
          wacc[s][6] = fmaf(hv, wb.z, wacc[s][6]);
          wacc[s][7] = fmaf(hv, wb.w, wacc[s][7]);
        }
      }
    }

    // epilogue: m = cg*512 + t*64 + lane ; col = lane&7 ; uv = cg*64 + t*8 + (lane>>3)
    const int l3 = lane >> 3;
    if (cg < 4) {                 // scalar path: uv < 256
#pragma unroll
      for (int s = 0; s < 8; ++s) {
        float o = 0.f;
#pragma unroll
        for (int t = 0; t < 8; ++t) {
          const int uv = cg * 64 + t * 8 + l3;
          const int u = uv >> 4, v = uv & 15;
          o = fmaf(sF[wv][s][u] * sF[wv][s][40 + v], wacc[s][t], o);
        }
        o += __shfl_xor(o, 8); o += __shfl_xor(o, 16); o += __shfl_xor(o, 32);
        if (val[s] && lane < 8) atomicAdd(&out[(size_t)eidx[s] * 8 + lane], o * PWREC);
      }
    } else {                      // vector path: u = t, v = l3
#pragma unroll
      for (int s = 0; s < 8; ++s) {
        float o = 0.f;
#pragma unroll
        for (int t = 0; t < 8; ++t) {
          const float dp = sF[wv][s][16 + t * 3]     * sF[wv][s][56 + l3 * 3]
                         + sF[wv][s][16 + t * 3 + 1] * sF[wv][s][56 + l3 * 3 + 1]
                         + sF[wv][s][16 + t * 3 + 2] * sF[wv][s][56 + l3 * 3 + 2];
          o = fmaf(dp * INV_SQ3, wacc[s][t], o);
        }
        o += __shfl_xor(o, 8); o += __shfl_xor(o, 16); o += __shfl_xor(o, 32);
        if (val[s] && lane < 8) atomicAdd(&out[(size_t)eidx[s] * 8 + lane], o * PWREC);
      }
    }
  }
}

extern "C" void kernel_launch(void* const* d_in, const int* in_sizes, int n_in,
                              void* d_out, int out_size, void* d_ws, size_t ws_size,
                              hipStream_t stream) {
  (void)n_in; (void)ws_size;
  const float* x      = (const float*)d_in[0];
  const float* pos    = (const float*)d_in[1];
  const int*   ei     = (const int*)  d_in[2];
  const float* eattr  = (const float*)d_in[3];
  const int*   iei    = (const int*)  d_in[4];
  const float* emb_w0 = (const float*)d_in[5];
  const float* emb_w1 = (const float*)d_in[6];
  const float* imp0   = (const float*)d_in[7];
  const float* m0w0   = (const float*)d_in[8];
  const float* m0w1   = (const float*)d_in[9];
  const float* u0w0   = (const float*)d_in[10];
  const float* u0w1   = (const float*)d_in[11];
  const float* imp1   = (const float*)d_in[12];
  const float* m1w0   = (const float*)d_in[13];
  const float* m1w1   = (const float*)d_in[14];
  const float* u1w0   = (const float*)d_in[15];
  const float* u1w1   = (const float*)d_in[16];
  const float* lw0    = (const float*)d_in[17];
  const float* lw1    = (const float*)d_in[18];
  const float* rw0    = (const float*)d_in[19];
  const float* rw1    = (const float*)d_in[20];

  const int N  = in_sizes[1] / 3;
  const int E  = in_sizes[2] / 2;
  const int EI = in_sizes[4] / 2;

  float* node = (float*)d_ws;
  float* msgs = node + (size_t)N * 40;
  float* hL   = msgs + (size_t)N * 40;
  float* hR   = hL + (size_t)EI * 64;
  float* ligE = hR + (size_t)EI * 64;
  float* outp = (float*)d_out;

  const float inv_sqrt_deg = 1.0f / sqrtf((float)E / (float)N);

  const int nodeBlocks  = (N + 3) / 4;
  const int interBlocks = (EI + 3) / 4;

  emb_kernel<<<nodeBlocks, 256, 0, stream>>>(x, emb_w0, emb_w1, node, N);

  // message pass 0
  hipMemsetAsync(msgs, 0, (size_t)N * 40 * sizeof(float), stream);
  tp_kernel<0><<<500, 512, 0, stream>>>(node, pos, ei, eattr, m0w0, m0w1, nullptr, msgs, E);
  upd_kernel<<<nodeBlocks, 256, 0, stream>>>(node, msgs, u0w0, u0w1, imp0, 1.0f, inv_sqrt_deg, N);

  // message pass 1
  hipMemsetAsync(msgs, 0, (size_t)N * 40 * sizeof(float), stream);
  tp_kernel<0><<<500, 512, 0, stream>>>(node, pos, ei, eattr, m1w0, m1w1, nullptr, msgs, E);
  upd_kernel<<<nodeBlocks, 256, 0, stream>>>(node, msgs, u1w0, u1w1, imp1, 0.5f, inv_sqrt_deg, N);

  // inter edges
  inter_h_kernel<<<interBlocks, 256, 0, stream>>>(pos, iei, lw0, rw0, hL, hR, EI);
  tp_kernel<1><<<417, 512, 0, stream>>>(node, pos, iei, nullptr, nullptr, lw1, hL, ligE, EI);

  hipMemsetAsync(outp, 0, (size_t)out_size * sizeof(float), stream);
  rec_kernel<<<dim3(51, 5), 512, 0, stream>>>(node, ligE, iei, rw1, hR, outp, EI);
}

// Round 6
// 824.997 us; speedup vs baseline: 2.3199x; 2.3199x over previous
//
#include <hip/hip_runtime.h>
#include <cmath>

// ---- constants from the reference ----
constexpr float ACT_NORM = 1.6789717f;
constexpr float PW0      = 0.20412414523193154f;   // sqrt(1/24)  (== pw1/sqrt3)
constexpr float PW1      = 0.35355339059327373f;   // sqrt(3/24)
constexpr float PWREC    = 0.05590169943749474f;   // sqrt(1/320)
constexpr float INV_SQ3  = 0.57735026918962576f;

__device__ __forceinline__ float silu_n(float x) {
  return x / (1.f + __expf(-x)) * ACT_NORM;
}

__device__ __forceinline__ float bcast_lane(float v, int k) {
  return __int_as_float(__builtin_amdgcn_readlane(__float_as_int(v), k));
}

// ---------------- node embedding: node[:, :16] = mlp(x), geo = 0 ----------------
__global__ __launch_bounds__(256)
void emb_kernel(const float* __restrict__ x, const float* __restrict__ w0,
                const float* __restrict__ w1, float* __restrict__ node, int N) {
  const int lane = threadIdx.x & 63;
  const int lw   = threadIdx.x >> 6;
  const int gw   = blockIdx.x * 4 + lw;
  __shared__ float sH[4][64];
  const bool valid = gw < N;
  const int n = valid ? gw : 0;
  float acc = 0.f;
#pragma unroll
  for (int a = 0; a < 10; ++a) acc = fmaf(x[n * 10 + a], w0[a * 64 + lane], acc);
  acc *= 0.31622776601683794f;   // 1/sqrt(10)
  sH[lw][lane] = silu_n(acc);
  __syncthreads();
  if (valid) {
    if (lane < 16) {
      float o = 0.f;
#pragma unroll
      for (int k = 0; k < 64; ++k) o = fmaf(sH[lw][k], w1[k * 16 + lane], o);
      node[(size_t)n * 40 + lane] = o * 0.125f;  // 1/sqrt(64)
    } else if (lane < 40) {
      node[(size_t)n * 40 + lane] = 0.f;
    }
  }
}

// ---------------- node update (per mp step) ----------------
__global__ __launch_bounds__(256)
void upd_kernel(float* __restrict__ node, const float* __restrict__ msgs,
                const float* __restrict__ w0, const float* __restrict__ w1,
                const float* __restrict__ imp, float geo_scale, float inv_sqrt_deg, int N) {
  const int lane = threadIdx.x & 63;
  const int lw   = threadIdx.x >> 6;
  const int gw   = blockIdx.x * 4 + lw;
  __shared__ float sIn[4][32];
  __shared__ float sH[4][64];
  const bool valid = gw < N;
  const int n = valid ? gw : 0;
  const float mscale = imp[0] * inv_sqrt_deg;
  if (lane < 16)      sIn[lw][lane] = msgs[(size_t)n * 40 + lane] * mscale;
  else if (lane < 32) sIn[lw][lane] = node[(size_t)n * 40 + lane - 16];
  __syncthreads();
  float acc = 0.f;
#pragma unroll
  for (int a = 0; a < 32; ++a) acc = fmaf(sIn[lw][a], w0[a * 64 + lane], acc);
  acc *= 0.17677669529663687f;   // 1/sqrt(32)
  sH[lw][lane] = silu_n(acc);
  __syncthreads();
  if (valid) {
    if (lane < 16) {
      float o = 0.f;
#pragma unroll
      for (int k = 0; k < 64; ++k) o = fmaf(sH[lw][k], w1[k * 16 + lane], o);
      node[(size_t)n * 40 + lane] = o * 0.125f;
    } else if (lane < 40) {
      const size_t gi = (size_t)n * 40 + lane;
      node[gi] = fmaf(msgs[gi], mscale, node[gi]) * geo_scale;
    }
  }
}

// ---------------- inter-edge: distance embedding -> both hidden vectors ----------------
__global__ __launch_bounds__(256)
void inter_h_kernel(const float* __restrict__ pos, const int* __restrict__ iei,
                    const float* __restrict__ lw0, const float* __restrict__ rw0,
                    float* __restrict__ hL, float* __restrict__ hR, int EI) {
  const int lane = threadIdx.x & 63;
  const int lw   = threadIdx.x >> 6;
  const int gw   = blockIdx.x * 4 + lw;
  __shared__ float sD[4][20];
  const bool valid = gw < EI;
  const int e = valid ? gw : 0;
  const int rec = iei[e], lig = iei[EI + e];
  const float dx = pos[lig * 3]     - pos[rec * 3];
  const float dy = pos[lig * 3 + 1] - pos[rec * 3 + 1];
  const float dz = pos[lig * 3 + 2] - pos[rec * 3 + 2];
  const float d = sqrtf(dx * dx + dy * dy + dz * dz);
  if (lane < 20) {
    const float diff = d * 4.2f - (float)(lane + 1);
    const float t1 = diff + 1.f, t2 = 1.f - diff;
    float v = 0.f;
    if (t1 > 0.f && t2 > 0.f) {
      const float C = 1.14136f * 7.3890560989306495f * 4.4721359549995794f; // 1.14136*e^2*sqrt(20)
      v = C * __expf(-1.f / t1 - 1.f / t2);
    }
    sD[lw][lane] = v;
  }
  __syncthreads();
  float a0 = 0.f, a1 = 0.f;
#pragma unroll
  for (int b = 0; b < 20; ++b) {
    const float db = sD[lw][b];
    a0 = fmaf(db, lw0[b * 64 + lane], a0);
    a1 = fmaf(db, rw0[b * 64 + lane], a1);
  }
  a0 *= 0.22360679774997896f;  // 1/sqrt(20)
  a1 *= 0.22360679774997896f;
  if (valid) {
    hL[(size_t)e * 64 + lane] = silu_n(a0);
    hR[(size_t)e * 64 + lane] = silu_n(a1);
  }
}

// ---------------- fused edge MLP (layer2) + node x sh tensor product ----------------
// Weight cols t=0..7 in LDS as sA/sB [k][lane][4] (wide conflict-free b128 reads);
// col t=8 double-buffered from global (L2-hot, 8 regs only — round-5's 40-reg version
// spilled; this is the proven round-4 shape). h lives in 1 VGPR/edge, broadcast per-k
// via v_readlane (keeps the h-broadcast off the LDS pipe). S=8 edges/wave.
// LDS 141.5KB -> 1 block/CU. Layer scale 1/8 folded into h; epilogue uses PW0/PW1 raw.
template <int MODE>
__global__ __launch_bounds__(512, 2)
void tp_kernel(const float* __restrict__ node, const float* __restrict__ pos,
               const int* __restrict__ ei, const float* __restrict__ eattr,
               const float* __restrict__ w0, const float* __restrict__ W1,
               const float* __restrict__ hSrc, float* __restrict__ out, int E) {
  __shared__ __align__(16) float sA[64 * 64 * 4];   // 65536 B: cols t=0..3 (raw)
  __shared__ __align__(16) float sB[64 * 64 * 4];   // 65536 B: cols t=4..7 (raw)
  __shared__ float sF[8][8][52];                    // 13312 B -> 144384 B total
  const int tid  = threadIdx.x;
  const int lane = tid & 63;
  const int wv   = tid >> 6;

  // stage sA/sB once per block ([k][m] -> [k][lane][t]); coalesced global reads
  for (int j = tid; j < 4096; j += 512) {
    const int k = j >> 6, l = j & 63;
    const float* src = &W1[k * 576 + l];
    float4 va, vb;
    va.x = src[0];   va.y = src[64];  va.z = src[128]; va.w = src[192];
    vb.x = src[256]; vb.y = src[320]; vb.z = src[384]; vb.w = src[448];
    *(float4*)&sA[j * 4] = va;
    *(float4*)&sB[j * 4] = vb;
  }
  __syncthreads();

  float w0r[5];
  if (MODE == 0) {
#pragma unroll
    for (int a = 0; a < 5; ++a) w0r[a] = w0[a * 64 + lane] * 0.4472135954999579f; // 1/sqrt(5)
  }
  const float* Wc = W1 + 512;   // col t=8: Wc[k*576 + lane]

  const int nB = (E + 63) >> 6;
  for (int b = blockIdx.x; b < nB; b += (int)gridDim.x) {
    const int ebase = b * 64 + wv * 8;
    int outn[8];
    bool val[8];
    float h[8];
#pragma unroll
    for (int s = 0; s < 8; ++s) {
      const int e0 = ebase + s;
      val[s] = e0 < E;
      const int e = val[s] ? e0 : 0;
      const int ia = ei[e], ib = ei[E + e];
      int nsrc;
      if (MODE == 0) { nsrc = ia; outn[s] = ib; }   // src features, scatter to dst
      else           { nsrc = ib; outn[s] = e;  }   // lig features, store per edge
      const float vx = pos[ib * 3]     - pos[ia * 3];
      const float vy = pos[ib * 3 + 1] - pos[ia * 3 + 1];
      const float vz = pos[ib * 3 + 2] - pos[ia * 3 + 2];
      const float rn = rsqrtf(vx * vx + vy * vy + vz * vz);
      const float rx = vx * rn, ry = vy * rn, rz = vz * rn;
      if (MODE == 0) {
        float acc = 0.f;
#pragma unroll
        for (int a = 0; a < 5; ++a) acc = fmaf(eattr[(size_t)e * 5 + a], w0r[a], acc);
        h[s] = silu_n(acc) * 0.125f;          // fold 1/sqrt(64)
      } else {
        h[s] = hSrc[(size_t)e * 64 + lane] * 0.125f;
      }
      if (lane < 16) {
        sF[wv][s][lane] = node[(size_t)nsrc * 40 + lane];           // xs
      } else if (lane < 24) {
        const int u = lane - 16;
        const float x0 = node[(size_t)nsrc * 40 + 16 + u * 3];
        const float x1 = node[(size_t)nsrc * 40 + 16 + u * 3 + 1];
        const float x2 = node[(size_t)nsrc * 40 + 16 + u * 3 + 2];
        sF[wv][s][16 + u]         = x0 * rx + x1 * ry + x2 * rz;    // dot(xv, r^)
        sF[wv][s][24 + u * 3]     = x0;                             // xv
        sF[wv][s][24 + u * 3 + 1] = x1;
        sF[wv][s][24 + u * 3 + 2] = x2;
      } else if (lane < 27) {
        sF[wv][s][48 + (lane - 24)] = (lane == 24) ? rx : ((lane == 25) ? ry : rz);
      }
    }
    // no barrier: sF slices per-wave private; h per-lane registers

    float wacc[8][9];
#pragma unroll
    for (int s = 0; s < 8; ++s)
#pragma unroll
      for (int t = 0; t < 9; ++t) wacc[s][t] = 0.f;

    float wcur[4], wnxt[4];
#pragma unroll
    for (int kk = 0; kk < 4; ++kk) wcur[kk] = Wc[kk * 576 + lane];

    for (int k4 = 0; k4 < 64; k4 += 4) {
      if (k4 < 60) {
#pragma unroll
        for (int kk = 0; kk < 4; ++kk) wnxt[kk] = Wc[(size_t)(k4 + 4 + kk) * 576 + lane];
      }
#pragma unroll
      for (int kk = 0; kk < 4; ++kk) {
        const int k = k4 + kk;
        const float4 wa = *(const float4*)&sA[(k * 64 + lane) * 4];
        const float4 wb = *(const float4*)&sB[(k * 64 + lane) * 4];
        const float  wc = wcur[kk];
#pragma unroll
        for (int s = 0; s < 8; ++s) {
          const float hv = bcast_lane(h[s], k);
          wacc[s][0] = fmaf(hv, wa.x, wacc[s][0]);
          wacc[s][1] = fmaf(hv, wa.y, wacc[s][1]);
          wacc[s][2] = fmaf(hv, wa.z, wacc[s][2]);
          wacc[s][3] = fmaf(hv, wa.w, wacc[s][3]);
          wacc[s][4] = fmaf(hv, wb.x, wacc[s][4]);
          wacc[s][5] = fmaf(hv, wb.y, wacc[s][5]);
          wacc[s][6] = fmaf(hv, wb.z, wacc[s][6]);
          wacc[s][7] = fmaf(hv, wb.w, wacc[s][7]);
          wacc[s][8] = fmaf(hv, wc,   wacc[s][8]);
        }
      }
      if (k4 < 60) {
#pragma unroll
        for (int kk = 0; kk < 4; ++kk) wcur[kk] = wnxt[kk];
      }
    }

    // TP epilogue. t=0..5 scalar-path (out col = lane&15, U=(lane>>4)+4t),
    // t=6..8 vector-path (out col = lane&7, U=(lane>>3)+8(t-6)).
    const int ub  = lane >> 4;
    const int ub2 = lane >> 3;
#pragma unroll
    for (int s = 0; s < 8; ++s) {
      float cs = 0.f;
#pragma unroll
      for (int t = 0; t < 6; ++t)
        cs = fmaf(PW0 * sF[wv][s][ub + 4 * t], wacc[s][t], cs);
      cs += __shfl_xor(cs, 16);
      cs += __shfl_xor(cs, 32);

      const float rx = sF[wv][s][48], ry = sF[wv][s][49], rz = sF[wv][s][50];
      const float sxw = PW1 * (sF[wv][s][ub2] * wacc[s][6] + sF[wv][s][ub2 + 8] * wacc[s][7]);
      float cv0 = fmaf(PW0 * sF[wv][s][24 + ub2 * 3],     wacc[s][8], sxw * rx);
      float cv1 = fmaf(PW0 * sF[wv][s][24 + ub2 * 3 + 1], wacc[s][8], sxw * ry);
      float cv2 = fmaf(PW0 * sF[wv][s][24 + ub2 * 3 + 2], wacc[s][8], sxw * rz);
      cv0 += __shfl_xor(cv0, 8); cv0 += __shfl_xor(cv0, 16); cv0 += __shfl_xor(cv0, 32);
      cv1 += __shfl_xor(cv1, 8); cv1 += __shfl_xor(cv1, 16); cv1 += __shfl_xor(cv1, 32);
      cv2 += __shfl_xor(cv2, 8); cv2 += __shfl_xor(cv2, 16); cv2 += __shfl_xor(cv2, 32);

      if (val[s]) {
        const size_t ob = (size_t)outn[s] * 40;
        if (MODE == 0) {
          if (lane < 16) atomicAdd(&out[ob + lane], cs);
          if (lane < 8) {
            atomicAdd(&out[ob + 16 + lane * 3],     cv0);
            atomicAdd(&out[ob + 16 + lane * 3 + 1], cv1);
            atomicAdd(&out[ob + 16 + lane * 3 + 2], cv2);
          }
        } else {
          if (lane < 16) out[ob + lane] = cs;
          if (lane < 8) {
            out[ob + 16 + lane * 3]     = cv0;
            out[ob + 16 + lane * 3 + 1] = cv1;
            out[ob + 16 + lane * 3 + 2] = cv2;
          }
        }
      }
    }
  }
}

// ---------------- rec MLP (layer2, 64x2560) + node x node -> 8x0e TP ----------------
// Persistent 512-col weight chunk per block (blockIdx.y = chunk 0..4), staged ONCE.
// Edge loop barrier-free; partial outputs accumulated via atomicAdd (out zeroed first).
// Chunk cg<4 is entirely the scalar CG region (uv<256); cg==4 entirely vector.
__global__ __launch_bounds__(512, 2)
void rec_kernel(const float* __restrict__ node, const float* __restrict__ ligE,
                const int* __restrict__ iei, const float* __restrict__ RW1,
                const float* __restrict__ hR, float* __restrict__ out, int EI) {
  __shared__ __align__(16) float sWa[64 * 64 * 4];  // 65536 B: cols t=0..3 of chunk
  __shared__ __align__(16) float sWb[64 * 64 * 4];  // 65536 B: cols t=4..7
  __shared__ float sF[8][8][80];                    // 20480 B -> 151552 B total
  const int tid  = threadIdx.x;
  const int lane = tid & 63;
  const int wv   = tid >> 6;
  const int cg   = blockIdx.y;                      // 0..4

  for (int j = tid; j < 4096; j += 512) {
    const int k = j >> 6, l = j & 63;
    const float* src = &RW1[(size_t)k * 2560 + cg * 512 + l];
    float4 a, bb;
    a.x  = src[0];   a.y  = src[64];  a.z  = src[128]; a.w  = src[192];
    bb.x = src[256]; bb.y = src[320]; bb.z = src[384]; bb.w = src[448];
    *(float4*)&sWa[j * 4] = a;
    *(float4*)&sWb[j * 4] = bb;
  }
  __syncthreads();

  const int nB = (EI + 63) >> 6;
  for (int b = blockIdx.x; b < nB; b += (int)gridDim.x) {
    const int ebase = b * 64 + wv * 8;
    bool val[8]; int eidx[8]; float h[8];
#pragma unroll
    for (int s = 0; s < 8; ++s) {
      const int e0 = ebase + s;
      val[s] = e0 < EI;
      const int e = val[s] ? e0 : 0;
      eidx[s] = e;
      h[s] = hR[(size_t)e * 64 + lane] * 0.125f;    // fold 1/sqrt(64)
      const int rec = iei[e];
      if (lane < 40) {
        sF[wv][s][lane]      = ligE[(size_t)e * 40 + lane];        // xs_l[0:16], xv_l[16:40]
        sF[wv][s][40 + lane] = node[(size_t)rec * 40 + lane];      // ys_r[40:56], yv_r[56:80]
      }
    }

    float wacc[8][8];
#pragma unroll
    for (int s = 0; s < 8; ++s)
#pragma unroll
      for (int t = 0; t < 8; ++t) wacc[s][t] = 0.f;

    for (int k4 = 0; k4 < 64; k4 += 4) {
#pragma unroll
      for (int kk = 0; kk < 4; ++kk) {
        const int k = k4 + kk;
        const float4 wa = *(const float4*)&sWa[(k * 64 + lane) * 4];
        const float4 wb = *(const float4*)&sWb[(k * 64 + lane) * 4];
#pragma unroll
        for (int s = 0; s < 8; ++s) {
          const float hv = bcast_lane(h[s], k);
          wacc[s][0] = fmaf(hv, wa.x, wacc[s][0]);
          wacc[s][1] = fmaf(hv, wa.y, wacc[s][1]);
          wacc[s][2] = fmaf(hv, wa.z, wacc[s][2]);
          wacc[s][3] = fmaf(hv, wa.w, wacc[s][3]);
          wacc[s][4] = fmaf(hv, wb.x, wacc[s][4]);
          wacc[s][5] = fmaf(hv, wb.y, wacc[s][5]);
          wacc[s][6] = fmaf(hv, wb.z, wacc[s][6]);
          wacc[s][7] = fmaf(hv, wb.w, wacc[s][7]);
        }
      }
    }

    // epilogue: m = cg*512 + t*64 + lane ; col = lane&7 ; uv = cg*64 + t*8 + (lane>>3)
    const int l3 = lane >> 3;
    if (cg < 4) {                 // scalar path: uv < 256
#pragma unroll
      for (int s = 0; s < 8; ++s) {
        float o = 0.f;
#pragma unroll
        for (int t = 0; t < 8; ++t) {
          const int uv = cg * 64 + t * 8 + l3;
          const int u = uv >> 4, v = uv & 15;
          o = fmaf(sF[wv][s][u] * sF[wv][s][40 + v], wacc[s][t], o);
        }
        o += __shfl_xor(o, 8); o += __shfl_xor(o, 16); o += __shfl_xor(o, 32);
        if (val[s] && lane < 8) atomicAdd(&out[(size_t)eidx[s] * 8 + lane], o * PWREC);
      }
    } else {                      // vector path: u = t, v = l3
#pragma unroll
      for (int s = 0; s < 8; ++s) {
        float o = 0.f;
#pragma unroll
        for (int t = 0; t < 8; ++t) {
          const float dp = sF[wv][s][16 + t * 3]     * sF[wv][s][56 + l3 * 3]
                         + sF[wv][s][16 + t * 3 + 1] * sF[wv][s][56 + l3 * 3 + 1]
                         + sF[wv][s][16 + t * 3 + 2] * sF[wv][s][56 + l3 * 3 + 2];
          o = fmaf(dp * INV_SQ3, wacc[s][t], o);
        }
        o += __shfl_xor(o, 8); o += __shfl_xor(o, 16); o += __shfl_xor(o, 32);
        if (val[s] && lane < 8) atomicAdd(&out[(size_t)eidx[s] * 8 + lane], o * PWREC);
      }
    }
  }
}

extern "C" void kernel_launch(void* const* d_in, const int* in_sizes, int n_in,
                              void* d_out, int out_size, void* d_ws, size_t ws_size,
                              hipStream_t stream) {
  (void)n_in; (void)ws_size;
  const float* x      = (const float*)d_in[0];
  const float* pos    = (const float*)d_in[1];
  const int*   ei     = (const int*)  d_in[2];
  const float* eattr  = (const float*)d_in[3];
  const int*   iei    = (const int*)  d_in[4];
  const float* emb_w0 = (const float*)d_in[5];
  const float* emb_w1 = (const float*)d_in[6];
  const float* imp0   = (const float*)d_in[7];
  const float* m0w0   = (const float*)d_in[8];
  const float* m0w1   = (const float*)d_in[9];
  const float* u0w0   = (const float*)d_in[10];
  const float* u0w1   = (const float*)d_in[11];
  const float* imp1   = (const float*)d_in[12];
  const float* m1w0   = (const float*)d_in[13];
  const float* m1w1   = (const float*)d_in[14];
  const float* u1w0   = (const float*)d_in[15];
  const float* u1w1   = (const float*)d_in[16];
  const float* lw0    = (const float*)d_in[17];
  const float* lw1    = (const float*)d_in[18];
  const float* rw0    = (const float*)d_in[19];
  const float* rw1    = (const float*)d_in[20];

  const int N  = in_sizes[1] / 3;
  const int E  = in_sizes[2] / 2;
  const int EI = in_sizes[4] / 2;

  float* node = (float*)d_ws;
  float* msgs = node + (size_t)N * 40;
  float* hL   = msgs + (size_t)N * 40;
  float* hR   = hL + (size_t)EI * 64;
  float* ligE = hR + (size_t)EI * 64;
  float* outp = (float*)d_out;

  const float inv_sqrt_deg = 1.0f / sqrtf((float)E / (float)N);

  const int nodeBlocks  = (N + 3) / 4;
  const int interBlocks = (EI + 3) / 4;

  emb_kernel<<<nodeBlocks, 256, 0, stream>>>(x, emb_w0, emb_w1, node, N);

  // message pass 0
  hipMemsetAsync(msgs, 0, (size_t)N * 40 * sizeof(float), stream);
  tp_kernel<0><<<256, 512, 0, stream>>>(node, pos, ei, eattr, m0w0, m0w1, nullptr, msgs, E);
  upd_kernel<<<nodeBlocks, 256, 0, stream>>>(node, msgs, u0w0, u0w1, imp0, 1.0f, inv_sqrt_deg, N);

  // message pass 1
  hipMemsetAsync(msgs, 0, (size_t)N * 40 * sizeof(float), stream);
  tp_kernel<0><<<256, 512, 0, stream>>>(node, pos, ei, eattr, m1w0, m1w1, nullptr, msgs, E);
  upd_kernel<<<nodeBlocks, 256, 0, stream>>>(node, msgs, u1w0, u1w1, imp1, 0.5f, inv_sqrt_deg, N);

  // inter edges
  inter_h_kernel<<<interBlocks, 256, 0, stream>>>(pos, iei, lw0, rw0, hL, hR, EI);
  tp_kernel<1><<<256, 512, 0, stream>>>(node, pos, iei, nullptr, nullptr, lw1, hL, ligE, EI);

  hipMemsetAsync(outp, 0, (size_t)out_size * sizeof(float), stream);
  rec_kernel<<<dim3(51, 5), 512, 0, stream>>>(node, ligE, iei, rw1, hR, outp, EI);
}

// Round 7
// 797.338 us; speedup vs baseline: 2.4004x; 1.0347x over previous
//
#include <hip/hip_runtime.h>
#include <hip/hip_bf16.h>
#include <cmath>

// ---- constants from the reference ----
constexpr float ACT_NORM = 1.6789717f;
constexpr float PW0      = 0.20412414523193154f;   // sqrt(1/24)  (== pw1/sqrt3)
constexpr float PW1      = 0.35355339059327373f;   // sqrt(3/24)
constexpr float PWREC    = 0.05590169943749474f;   // sqrt(1/320)
constexpr float INV_SQ3  = 0.57735026918962576f;

__device__ __forceinline__ float silu_n(float x) {
  return x / (1.f + __expf(-x)) * ACT_NORM;
}

__device__ __forceinline__ float bcast_lane(float v, int k) {
  return __int_as_float(__builtin_amdgcn_readlane(__float_as_int(v), k));
}

// round-to-nearest-even fp32 -> bf16 (weights only; no NaN/inf in randn weights)
__device__ __forceinline__ unsigned bf16r(float f) {
  unsigned u = __float_as_uint(f);
  return (u + 0x7fffu + ((u >> 16) & 1u)) >> 16;
}
__device__ __forceinline__ unsigned pack_bf2(float lo, float hi) {
  return bf16r(lo) | (bf16r(hi) << 16);
}
__device__ __forceinline__ float unpk_lo(unsigned q) { return __uint_as_float(q << 16); }
__device__ __forceinline__ float unpk_hi(unsigned q) { return __uint_as_float(q & 0xffff0000u); }

// ---------------- node embedding: node[:, :16] = mlp(x), geo = 0 ----------------
__global__ __launch_bounds__(256)
void emb_kernel(const float* __restrict__ x, const float* __restrict__ w0,
                const float* __restrict__ w1, float* __restrict__ node, int N) {
  const int lane = threadIdx.x & 63;
  const int lw   = threadIdx.x >> 6;
  const int gw   = blockIdx.x * 4 + lw;
  __shared__ float sH[4][64];
  const bool valid = gw < N;
  const int n = valid ? gw : 0;
  float acc = 0.f;
#pragma unroll
  for (int a = 0; a < 10; ++a) acc = fmaf(x[n * 10 + a], w0[a * 64 + lane], acc);
  acc *= 0.31622776601683794f;   // 1/sqrt(10)
  sH[lw][lane] = silu_n(acc);
  __syncthreads();
  if (valid) {
    if (lane < 16) {
      float o = 0.f;
#pragma unroll
      for (int k = 0; k < 64; ++k) o = fmaf(sH[lw][k], w1[k * 16 + lane], o);
      node[(size_t)n * 40 + lane] = o * 0.125f;  // 1/sqrt(64)
    } else if (lane < 40) {
      node[(size_t)n * 40 + lane] = 0.f;
    }
  }
}

// ---------------- node update (per mp step) ----------------
__global__ __launch_bounds__(256)
void upd_kernel(float* __restrict__ node, const float* __restrict__ msgs,
                const float* __restrict__ w0, const float* __restrict__ w1,
                const float* __restrict__ imp, float geo_scale, float inv_sqrt_deg, int N) {
  const int lane = threadIdx.x & 63;
  const int lw   = threadIdx.x >> 6;
  const int gw   = blockIdx.x * 4 + lw;
  __shared__ float sIn[4][32];
  __shared__ float sH[4][64];
  const bool valid = gw < N;
  const int n = valid ? gw : 0;
  const float mscale = imp[0] * inv_sqrt_deg;
  if (lane < 16)      sIn[lw][lane] = msgs[(size_t)n * 40 + lane] * mscale;
  else if (lane < 32) sIn[lw][lane] = node[(size_t)n * 40 + lane - 16];
  __syncthreads();
  float acc = 0.f;
#pragma unroll
  for (int a = 0; a < 32; ++a) acc = fmaf(sIn[lw][a], w0[a * 64 + lane], acc);
  acc *= 0.17677669529663687f;   // 1/sqrt(32)
  sH[lw][lane] = silu_n(acc);
  __syncthreads();
  if (valid) {
    if (lane < 16) {
      float o = 0.f;
#pragma unroll
      for (int k = 0; k < 64; ++k) o = fmaf(sH[lw][k], w1[k * 16 + lane], o);
      node[(size_t)n * 40 + lane] = o * 0.125f;
    } else if (lane < 40) {
      const size_t gi = (size_t)n * 40 + lane;
      node[gi] = fmaf(msgs[gi], mscale, node[gi]) * geo_scale;
    }
  }
}

// ---------------- inter-edge: distance embedding -> both hidden vectors ----------------
__global__ __launch_bounds__(256)
void inter_h_kernel(const float* __restrict__ pos, const int* __restrict__ iei,
                    const float* __restrict__ lw0, const float* __restrict__ rw0,
                    float* __restrict__ hL, float* __restrict__ hR, int EI) {
  const int lane = threadIdx.x & 63;
  const int lw   = threadIdx.x >> 6;
  const int gw   = blockIdx.x * 4 + lw;
  __shared__ float sD[4][20];
  const bool valid = gw < EI;
  const int e = valid ? gw : 0;
  const int rec = iei[e], lig = iei[EI + e];
  const float dx = pos[lig * 3]     - pos[rec * 3];
  const float dy = pos[lig * 3 + 1] - pos[rec * 3 + 1];
  const float dz = pos[lig * 3 + 2] - pos[rec * 3 + 2];
  const float d = sqrtf(dx * dx + dy * dy + dz * dz);
  if (lane < 20) {
    const float diff = d * 4.2f - (float)(lane + 1);
    const float t1 = diff + 1.f, t2 = 1.f - diff;
    float v = 0.f;
    if (t1 > 0.f && t2 > 0.f) {
      const float C = 1.14136f * 7.3890560989306495f * 4.4721359549995794f; // 1.14136*e^2*sqrt(20)
      v = C * __expf(-1.f / t1 - 1.f / t2);
    }
    sD[lw][lane] = v;
  }
  __syncthreads();
  float a0 = 0.f, a1 = 0.f;
#pragma unroll
  for (int b = 0; b < 20; ++b) {
    const float db = sD[lw][b];
    a0 = fmaf(db, lw0[b * 64 + lane], a0);
    a1 = fmaf(db, rw0[b * 64 + lane], a1);
  }
  a0 *= 0.22360679774997896f;  // 1/sqrt(20)
  a1 *= 0.22360679774997896f;
  if (valid) {
    hL[(size_t)e * 64 + lane] = silu_n(a0);
    hR[(size_t)e * 64 + lane] = silu_n(a1);
  }
}

// ---------------- fused edge MLP (layer2) + node x sh tensor product ----------------
// Weight cols t=0..7 packed bf16 in LDS as [k][lane][uint4] (one b128 per k delivers
// all 8 cols); col t=8 fp32 double-buffered from global (proven 8-reg pattern).
// h in 1 VGPR/edge broadcast via v_readlane. S=6 edges/wave, LDS 75.5 KB ->
// 2 blocks/CU (4 waves/SIMD). launch_bounds(512,4) caps VGPR at 128 (est ~105).
template <int MODE>
__global__ __launch_bounds__(512, 4)
void tp_kernel(const float* __restrict__ node, const float* __restrict__ pos,
               const int* __restrict__ ei, const float* __restrict__ eattr,
               const float* __restrict__ w0, const float* __restrict__ W1,
               const float* __restrict__ hSrc, float* __restrict__ out, int E) {
  __shared__ uint4 sAB[64 * 64];                    // 65536 B: cols t=0..7 bf16-packed
  __shared__ float sF[8][6][52];                    //  9984 B -> 75520 B total
  const int tid  = threadIdx.x;
  const int lane = tid & 63;
  const int wv   = tid >> 6;

  // stage packed weights once per block ([k][m] -> [k][lane][8 bf16])
  for (int j = tid; j < 4096; j += 512) {
    const int k = j >> 6, l = j & 63;
    const float* src = &W1[k * 576 + l];
    uint4 q;
    q.x = pack_bf2(src[0],   src[64]);
    q.y = pack_bf2(src[128], src[192]);
    q.z = pack_bf2(src[256], src[320]);
    q.w = pack_bf2(src[384], src[448]);
    sAB[j] = q;
  }
  __syncthreads();

  float w0r[5];
  if (MODE == 0) {
#pragma unroll
    for (int a = 0; a < 5; ++a) w0r[a] = w0[a * 64 + lane] * 0.4472135954999579f; // 1/sqrt(5)
  }
  const float* Wc = W1 + 512;   // col t=8 (fp32): Wc[k*576 + lane]

  const int nB = (E + 47) / 48;
  for (int b = blockIdx.x; b < nB; b += (int)gridDim.x) {
    const int ebase = b * 48 + wv * 6;
    int outn[6];
    bool val[6];
    float h[6];
#pragma unroll
    for (int s = 0; s < 6; ++s) {
      const int e0 = ebase + s;
      val[s] = e0 < E;
      const int e = val[s] ? e0 : 0;
      const int ia = ei[e], ib = ei[E + e];
      int nsrc;
      if (MODE == 0) { nsrc = ia; outn[s] = ib; }   // src features, scatter to dst
      else           { nsrc = ib; outn[s] = e;  }   // lig features, store per edge
      const float vx = pos[ib * 3]     - pos[ia * 3];
      const float vy = pos[ib * 3 + 1] - pos[ia * 3 + 1];
      const float vz = pos[ib * 3 + 2] - pos[ia * 3 + 2];
      const float rn = rsqrtf(vx * vx + vy * vy + vz * vz);
      const float rx = vx * rn, ry = vy * rn, rz = vz * rn;
      if (MODE == 0) {
        float acc = 0.f;
#pragma unroll
        for (int a = 0; a < 5; ++a) acc = fmaf(eattr[(size_t)e * 5 + a], w0r[a], acc);
        h[s] = silu_n(acc) * 0.125f;          // fold 1/sqrt(64)
      } else {
        h[s] = hSrc[(size_t)e * 64 + lane] * 0.125f;
      }
      if (lane < 16) {
        sF[wv][s][lane] = node[(size_t)nsrc * 40 + lane];           // xs
      } else if (lane < 24) {
        const int u = lane - 16;
        const float x0 = node[(size_t)nsrc * 40 + 16 + u * 3];
        const float x1 = node[(size_t)nsrc * 40 + 16 + u * 3 + 1];
        const float x2 = node[(size_t)nsrc * 40 + 16 + u * 3 + 2];
        sF[wv][s][16 + u]         = x0 * rx + x1 * ry + x2 * rz;    // dot(xv, r^)
        sF[wv][s][24 + u * 3]     = x0;                             // xv
        sF[wv][s][24 + u * 3 + 1] = x1;
        sF[wv][s][24 + u * 3 + 2] = x2;
      } else if (lane < 27) {
        sF[wv][s][48 + (lane - 24)] = (lane == 24) ? rx : ((lane == 25) ? ry : rz);
      }
    }
    // no barrier: sF slices per-wave private; h per-lane registers

    float wacc[6][9];
#pragma unroll
    for (int s = 0; s < 6; ++s)
#pragma unroll
      for (int t = 0; t < 9; ++t) wacc[s][t] = 0.f;

    float wcur[4], wnxt[4];
#pragma unroll
    for (int kk = 0; kk < 4; ++kk) wcur[kk] = Wc[kk * 576 + lane];

    for (int k4 = 0; k4 < 64; k4 += 4) {
      if (k4 < 60) {
#pragma unroll
        for (int kk = 0; kk < 4; ++kk) wnxt[kk] = Wc[(size_t)(k4 + 4 + kk) * 576 + lane];
      }
#pragma unroll
      for (int kk = 0; kk < 4; ++kk) {
        const int k = k4 + kk;
        const uint4 q = sAB[k * 64 + lane];
        const float wA0 = unpk_lo(q.x), wA1 = unpk_hi(q.x);
        const float wA2 = unpk_lo(q.y), wA3 = unpk_hi(q.y);
        const float wB0 = unpk_lo(q.z), wB1 = unpk_hi(q.z);
        const float wB2 = unpk_lo(q.w), wB3 = unpk_hi(q.w);
        const float wc  = wcur[kk];
#pragma unroll
        for (int s = 0; s < 6; ++s) {
          const float hv = bcast_lane(h[s], k);
          wacc[s][0] = fmaf(hv, wA0, wacc[s][0]);
          wacc[s][1] = fmaf(hv, wA1, wacc[s][1]);
          wacc[s][2] = fmaf(hv, wA2, wacc[s][2]);
          wacc[s][3] = fmaf(hv, wA3, wacc[s][3]);
          wacc[s][4] = fmaf(hv, wB0, wacc[s][4]);
          wacc[s][5] = fmaf(hv, wB1, wacc[s][5]);
          wacc[s][6] = fmaf(hv, wB2, wacc[s][6]);
          wacc[s][7] = fmaf(hv, wB3, wacc[s][7]);
          wacc[s][8] = fmaf(hv, wc,  wacc[s][8]);
        }
      }
      if (k4 < 60) {
#pragma unroll
        for (int kk = 0; kk < 4; ++kk) wcur[kk] = wnxt[kk];
      }
    }

    // TP epilogue. t=0..5 scalar-path (out col = lane&15, U=(lane>>4)+4t),
    // t=6..8 vector-path (out col = lane&7, U=(lane>>3)+8(t-6)).
    const int ub  = lane >> 4;
    const int ub2 = lane >> 3;
#pragma unroll
    for (int s = 0; s < 6; ++s) {
      float cs = 0.f;
#pragma unroll
      for (int t = 0; t < 6; ++t)
        cs = fmaf(PW0 * sF[wv][s][ub + 4 * t], wacc[s][t], cs);
      cs += __shfl_xor(cs, 16);
      cs += __shfl_xor(cs, 32);

      const float rx = sF[wv][s][48], ry = sF[wv][s][49], rz = sF[wv][s][50];
      const float sxw = PW1 * (sF[wv][s][ub2] * wacc[s][6] + sF[wv][s][ub2 + 8] * wacc[s][7]);
      float cv0 = fmaf(PW0 * sF[wv][s][24 + ub2 * 3],     wacc[s][8], sxw * rx);
      float cv1 = fmaf(PW0 * sF[wv][s][24 + ub2 * 3 + 1], wacc[s][8], sxw * ry);
      float cv2 = fmaf(PW0 * sF[wv][s][24 + ub2 * 3 + 2], wacc[s][8], sxw * rz);
      cv0 += __shfl_xor(cv0, 8); cv0 += __shfl_xor(cv0, 16); cv0 += __shfl_xor(cv0, 32);
      cv1 += __shfl_xor(cv1, 8); cv1 += __shfl_xor(cv1, 16); cv1 += __shfl_xor(cv1, 32);
      cv2 += __shfl_xor(cv2, 8); cv2 += __shfl_xor(cv2, 16); cv2 += __shfl_xor(cv2, 32);

      if (val[s]) {
        const size_t ob = (size_t)outn[s] * 40;
        if (MODE == 0) {
          if (lane < 16) atomicAdd(&out[ob + lane], cs);
          if (lane < 8) {
            atomicAdd(&out[ob + 16 + lane * 3],     cv0);
            atomicAdd(&out[ob + 16 + lane * 3 + 1], cv1);
            atomicAdd(&out[ob + 16 + lane * 3 + 2], cv2);
          }
        } else {
          if (lane < 16) out[ob + lane] = cs;
          if (lane < 8) {
            out[ob + 16 + lane * 3]     = cv0;
            out[ob + 16 + lane * 3 + 1] = cv1;
            out[ob + 16 + lane * 3 + 2] = cv2;
          }
        }
      }
    }
  }
}

// ---------------- rec MLP (layer2, 64x2560) + node x node -> 8x0e TP ----------------
// Persistent 512-col bf16 weight chunk per block (blockIdx.y = chunk 0..4), staged
// ONCE. Edge loop barrier-free; partials atomicAdd'd (out zeroed first). S=6,
// LDS 80.9 KB -> 2 blocks/CU. Chunk cg<4 scalar CG region; cg==4 vector.
__global__ __launch_bounds__(512, 4)
void rec_kernel(const float* __restrict__ node, const float* __restrict__ ligE,
                const int* __restrict__ iei, const float* __restrict__ RW1,
                const float* __restrict__ hR, float* __restrict__ out, int EI) {
  __shared__ uint4 sW[64 * 64];                     // 65536 B: chunk cols t=0..7 bf16
  __shared__ float sF[8][6][80];                    // 15360 B -> 80896 B total
  const int tid  = threadIdx.x;
  const int lane = tid & 63;
  const int wv   = tid >> 6;
  const int cg   = blockIdx.y;                      // 0..4

  for (int j = tid; j < 4096; j += 512) {
    const int k = j >> 6, l = j & 63;
    const float* src = &RW1[(size_t)k * 2560 + cg * 512 + l];
    uint4 q;
    q.x = pack_bf2(src[0],   src[64]);
    q.y = pack_bf2(src[128], src[192]);
    q.z = pack_bf2(src[256], src[320]);
    q.w = pack_bf2(src[384], src[448]);
    sW[j] = q;
  }
  __syncthreads();

  const int nB = (EI + 47) / 48;
  for (int b = blockIdx.x; b < nB; b += (int)gridDim.x) {
    const int ebase = b * 48 + wv * 6;
    bool val[6]; int eidx[6]; float h[6];
#pragma unroll
    for (int s = 0; s < 6; ++s) {
      const int e0 = ebase + s;
      val[s] = e0 < EI;
      const int e = val[s] ? e0 : 0;
      eidx[s] = e;
      h[s] = hR[(size_t)e * 64 + lane] * 0.125f;    // fold 1/sqrt(64)
      const int rec = iei[e];
      if (lane < 40) {
        sF[wv][s][lane]      = ligE[(size_t)e * 40 + lane];        // xs_l[0:16], xv_l[16:40]
        sF[wv][s][40 + lane] = node[(size_t)rec * 40 + lane];      // ys_r[40:56], yv_r[56:80]
      }
    }

    float wacc[6][8];
#pragma unroll
    for (int s = 0; s < 6; ++s)
#pragma unroll
      for (int t = 0; t < 8; ++t) wacc[s][t] = 0.f;

    for (int k4 = 0; k4 < 64; k4 += 4) {
#pragma unroll
      for (int kk = 0; kk < 4; ++kk) {
        const int k = k4 + kk;
        const uint4 q = sW[k * 64 + lane];
        const float w0v = unpk_lo(q.x), w1v = unpk_hi(q.x);
        const float w2v = unpk_lo(q.y), w3v = unpk_hi(q.y);
        const float w4v = unpk_lo(q.z), w5v = unpk_hi(q.z);
        const float w6v = unpk_lo(q.w), w7v = unpk_hi(q.w);
#pragma unroll
        for (int s = 0; s < 6; ++s) {
          const float hv = bcast_lane(h[s], k);
          wacc[s][0] = fmaf(hv, w0v, wacc[s][0]);
          wacc[s][1] = fmaf(hv, w1v, wacc[s][1]);
          wacc[s][2] = fmaf(hv, w2v, wacc[s][2]);
          wacc[s][3] = fmaf(hv, w3v, wacc[s][3]);
          wacc[s][4] = fmaf(hv, w4v, wacc[s][4]);
          wacc[s][5] = fmaf(hv, w5v, wacc[s][5]);
          wacc[s][6] = fmaf(hv, w6v, wacc[s][6]);
          wacc[s][7] = fmaf(hv, w7v, wacc[s][7]);
        }
      }
    }

    // epilogue: m = cg*512 + t*64 + lane ; col = lane&7 ; uv = cg*64 + t*8 + (lane>>3)
    const int l3 = lane >> 3;
    if (cg < 4) {                 // scalar path: uv < 256
#pragma unroll
      for (int s = 0; s < 6; ++s) {
        float o = 0.f;
#pragma unroll
        for (int t = 0; t < 8; ++t) {
          const int uv = cg * 64 + t * 8 + l3;
          const int u = uv >> 4, v = uv & 15;
          o = fmaf(sF[wv][s][u] * sF[wv][s][40 + v], wacc[s][t], o);
        }
        o += __shfl_xor(o, 8); o += __shfl_xor(o, 16); o += __shfl_xor(o, 32);
        if (val[s] && lane < 8) atomicAdd(&out[(size_t)eidx[s] * 8 + lane], o * PWREC);
      }
    } else {                      // vector path: u = t, v = l3
#pragma unroll
      for (int s = 0; s < 6; ++s) {
        float o = 0.f;
#pragma unroll
        for (int t = 0; t < 8; ++t) {
          const float dp = sF[wv][s][16 + t * 3]     * sF[wv][s][56 + l3 * 3]
                         + sF[wv][s][16 + t * 3 + 1] * sF[wv][s][56 + l3 * 3 + 1]
                         + sF[wv][s][16 + t * 3 + 2] * sF[wv][s][56 + l3 * 3 + 2];
          o = fmaf(dp * INV_SQ3, wacc[s][t], o);
        }
        o += __shfl_xor(o, 8); o += __shfl_xor(o, 16); o += __shfl_xor(o, 32);
        if (val[s] && lane < 8) atomicAdd(&out[(size_t)eidx[s] * 8 + lane], o * PWREC);
      }
    }
  }
}

extern "C" void kernel_launch(void* const* d_in, const int* in_sizes, int n_in,
                              void* d_out, int out_size, void* d_ws, size_t ws_size,
                              hipStream_t stream) {
  (void)n_in; (void)ws_size;
  const float* x      = (const float*)d_in[0];
  const float* pos    = (const float*)d_in[1];
  const int*   ei     = (const int*)  d_in[2];
  const float* eattr  = (const float*)d_in[3];
  const int*   iei    = (const int*)  d_in[4];
  const float* emb_w0 = (const float*)d_in[5];
  const float* emb_w1 = (const float*)d_in[6];
  const float* imp0   = (const float*)d_in[7];
  const float* m0w0   = (const float*)d_in[8];
  const float* m0w1   = (const float*)d_in[9];
  const float* u0w0   = (const float*)d_in[10];
  const float* u0w1   = (const float*)d_in[11];
  const float* imp1   = (const float*)d_in[12];
  const float* m1w0   = (const float*)d_in[13];
  const float* m1w1   = (const float*)d_in[14];
  const float* u1w0   = (const float*)d_in[15];
  const float* u1w1   = (const float*)d_in[16];
  const float* lw0    = (const float*)d_in[17];
  const float* lw1    = (const float*)d_in[18];
  const float* rw0    = (const float*)d_in[19];
  const float* rw1    = (const float*)d_in[20];

  const int N  = in_sizes[1] / 3;
  const int E  = in_sizes[2] / 2;
  const int EI = in_sizes[4] / 2;

  float* node = (float*)d_ws;
  float* msgs = node + (size_t)N * 40;
  float* hL   = msgs + (size_t)N * 40;
  float* hR   = hL + (size_t)EI * 64;
  float* ligE = hR + (size_t)EI * 64;
  float* outp = (float*)d_out;

  const float inv_sqrt_deg = 1.0f / sqrtf((float)E / (float)N);

  const int nodeBlocks  = (N + 3) / 4;
  const int interBlocks = (EI + 3) / 4;

  emb_kernel<<<nodeBlocks, 256, 0, stream>>>(x, emb_w0, emb_w1, node, N);

  // message pass 0
  hipMemsetAsync(msgs, 0, (size_t)N * 40 * sizeof(float), stream);
  tp_kernel<0><<<512, 512, 0, stream>>>(node, pos, ei, eattr, m0w0, m0w1, nullptr, msgs, E);
  upd_kernel<<<nodeBlocks, 256, 0, stream>>>(node, msgs, u0w0, u0w1, imp0, 1.0f, inv_sqrt_deg, N);

  // message pass 1
  hipMemsetAsync(msgs, 0, (size_t)N * 40 * sizeof(float), stream);
  tp_kernel<0><<<512, 512, 0, stream>>>(node, pos, ei, eattr, m1w0, m1w1, nullptr, msgs, E);
  upd_kernel<<<nodeBlocks, 256, 0, stream>>>(node, msgs, u1w0, u1w1, imp1, 0.5f, inv_sqrt_deg, N);

  // inter edges
  inter_h_kernel<<<interBlocks, 256, 0, stream>>>(pos, iei, lw0, rw0, hL, hR, EI);
  tp_kernel<1><<<512, 512, 0, stream>>>(node, pos, iei, nullptr, nullptr, lw1, hL, ligE, EI);

  hipMemsetAsync(outp, 0, (size_t)out_size * sizeof(float), stream);
  rec_kernel<<<dim3(102, 5), 512, 0, stream>>>(node, ligE, iei, rw1, hR, outp, EI);
}

// Round 8
// 765.232 us; speedup vs baseline: 2.5011x; 1.0420x over previous
//
#include <hip/hip_runtime.h>
#include <hip/hip_bf16.h>
#include <cmath>

// ---- constants from the reference ----
constexpr float ACT_NORM = 1.6789717f;
constexpr float PW0      = 0.20412414523193154f;   // sqrt(1/24)  (== pw1/sqrt3)
constexpr float PW1      = 0.35355339059327373f;   // sqrt(3/24)
constexpr float PWREC    = 0.05590169943749474f;   // sqrt(1/320)
constexpr float INV_SQ3  = 0.57735026918962576f;

__device__ __forceinline__ float silu_n(float x) {
  return x / (1.f + __expf(-x)) * ACT_NORM;
}

__device__ __forceinline__ float bcast_lane(float v, int k) {
  return __int_as_float(__builtin_amdgcn_readlane(__float_as_int(v), k));
}

// round-to-nearest-even fp32 -> bf16 (weights only; no NaN/inf in randn weights)
__device__ __forceinline__ unsigned bf16r(float f) {
  unsigned u = __float_as_uint(f);
  return (u + 0x7fffu + ((u >> 16) & 1u)) >> 16;
}
__device__ __forceinline__ unsigned pack_bf2(float lo, float hi) {
  return bf16r(lo) | (bf16r(hi) << 16);
}
__device__ __forceinline__ float unpk_lo(unsigned q) { return __uint_as_float(q << 16); }
__device__ __forceinline__ float unpk_hi(unsigned q) { return __uint_as_float(q & 0xffff0000u); }

// ---------------- node embedding: node[:, :16] = mlp(x), geo = 0 ----------------
__global__ __launch_bounds__(256)
void emb_kernel(const float* __restrict__ x, const float* __restrict__ w0,
                const float* __restrict__ w1, float* __restrict__ node, int N) {
  const int lane = threadIdx.x & 63;
  const int lw   = threadIdx.x >> 6;
  const int gw   = blockIdx.x * 4 + lw;
  __shared__ float sH[4][64];
  const bool valid = gw < N;
  const int n = valid ? gw : 0;
  float acc = 0.f;
#pragma unroll
  for (int a = 0; a < 10; ++a) acc = fmaf(x[n * 10 + a], w0[a * 64 + lane], acc);
  acc *= 0.31622776601683794f;   // 1/sqrt(10)
  sH[lw][lane] = silu_n(acc);
  __syncthreads();
  if (valid) {
    if (lane < 16) {
      float o = 0.f;
#pragma unroll
      for (int k = 0; k < 64; ++k) o = fmaf(sH[lw][k], w1[k * 16 + lane], o);
      node[(size_t)n * 40 + lane] = o * 0.125f;  // 1/sqrt(64)
    } else if (lane < 40) {
      node[(size_t)n * 40 + lane] = 0.f;
    }
  }
}

// ---------------- node update (per mp step) ----------------
__global__ __launch_bounds__(256)
void upd_kernel(float* __restrict__ node, const float* __restrict__ msgs,
                const float* __restrict__ w0, const float* __restrict__ w1,
                const float* __restrict__ imp, float geo_scale, float inv_sqrt_deg, int N) {
  const int lane = threadIdx.x & 63;
  const int lw   = threadIdx.x >> 6;
  const int gw   = blockIdx.x * 4 + lw;
  __shared__ float sIn[4][32];
  __shared__ float sH[4][64];
  const bool valid = gw < N;
  const int n = valid ? gw : 0;
  const float mscale = imp[0] * inv_sqrt_deg;
  if (lane < 16)      sIn[lw][lane] = msgs[(size_t)n * 40 + lane] * mscale;
  else if (lane < 32) sIn[lw][lane] = node[(size_t)n * 40 + lane - 16];
  __syncthreads();
  float acc = 0.f;
#pragma unroll
  for (int a = 0; a < 32; ++a) acc = fmaf(sIn[lw][a], w0[a * 64 + lane], acc);
  acc *= 0.17677669529663687f;   // 1/sqrt(32)
  sH[lw][lane] = silu_n(acc);
  __syncthreads();
  if (valid) {
    if (lane < 16) {
      float o = 0.f;
#pragma unroll
      for (int k = 0; k < 64; ++k) o = fmaf(sH[lw][k], w1[k * 16 + lane], o);
      node[(size_t)n * 40 + lane] = o * 0.125f;
    } else if (lane < 40) {
      const size_t gi = (size_t)n * 40 + lane;
      node[gi] = fmaf(msgs[gi], mscale, node[gi]) * geo_scale;
    }
  }
}

// ---------------- inter-edge: distance embedding -> both hidden vectors ----------------
__global__ __launch_bounds__(256)
void inter_h_kernel(const float* __restrict__ pos, const int* __restrict__ iei,
                    const float* __restrict__ lw0, const float* __restrict__ rw0,
                    float* __restrict__ hL, float* __restrict__ hR, int EI) {
  const int lane = threadIdx.x & 63;
  const int lw   = threadIdx.x >> 6;
  const int gw   = blockIdx.x * 4 + lw;
  __shared__ float sD[4][20];
  const bool valid = gw < EI;
  const int e = valid ? gw : 0;
  const int rec = iei[e], lig = iei[EI + e];
  const float dx = pos[lig * 3]     - pos[rec * 3];
  const float dy = pos[lig * 3 + 1] - pos[rec * 3 + 1];
  const float dz = pos[lig * 3 + 2] - pos[rec * 3 + 2];
  const float d = sqrtf(dx * dx + dy * dy + dz * dz);
  if (lane < 20) {
    const float diff = d * 4.2f - (float)(lane + 1);
    const float t1 = diff + 1.f, t2 = 1.f - diff;
    float v = 0.f;
    if (t1 > 0.f && t2 > 0.f) {
      const float C = 1.14136f * 7.3890560989306495f * 4.4721359549995794f; // 1.14136*e^2*sqrt(20)
      v = C * __expf(-1.f / t1 - 1.f / t2);
    }
    sD[lw][lane] = v;
  }
  __syncthreads();
  float a0 = 0.f, a1 = 0.f;
#pragma unroll
  for (int b = 0; b < 20; ++b) {
    const float db = sD[lw][b];
    a0 = fmaf(db, lw0[b * 64 + lane], a0);
    a1 = fmaf(db, rw0[b * 64 + lane], a1);
  }
  a0 *= 0.22360679774997896f;  // 1/sqrt(20)
  a1 *= 0.22360679774997896f;
  if (valid) {
    hL[(size_t)e * 64 + lane] = silu_n(a0);
    hR[(size_t)e * 64 + lane] = silu_n(a1);
  }
}

// ---------------- fused edge MLP (layer2) + node x sh tensor product ----------------
// Weight cols t=0..7 packed bf16 in LDS as [k][lane][uint4]; col t=8 fp32
// double-buffered from global (8 regs). h in 1 VGPR/edge via v_readlane.
// S=6 edges/wave, LDS 75.5 KB -> 2 blocks/CU. launch_bounds(512,2): rounds 4/6
// proved this lands ~90-120 VGPR with NO spill; (512,4) squeezed to 64 and spilled.
template <int MODE>
__global__ __launch_bounds__(512, 2)
void tp_kernel(const float* __restrict__ node, const float* __restrict__ pos,
               const int* __restrict__ ei, const float* __restrict__ eattr,
               const float* __restrict__ w0, const float* __restrict__ W1,
               const float* __restrict__ hSrc, float* __restrict__ out, int E) {
  __shared__ uint4 sAB[64 * 64];                    // 65536 B: cols t=0..7 bf16-packed
  __shared__ float sF[8][6][52];                    //  9984 B -> 75520 B total
  const int tid  = threadIdx.x;
  const int lane = tid & 63;
  const int wv   = tid >> 6;

  // stage packed weights once per block ([k][m] -> [k][lane][8 bf16])
  for (int j = tid; j < 4096; j += 512) {
    const int k = j >> 6, l = j & 63;
    const float* src = &W1[k * 576 + l];
    uint4 q;
    q.x = pack_bf2(src[0],   src[64]);
    q.y = pack_bf2(src[128], src[192]);
    q.z = pack_bf2(src[256], src[320]);
    q.w = pack_bf2(src[384], src[448]);
    sAB[j] = q;
  }
  __syncthreads();

  float w0r[5];
  if (MODE == 0) {
#pragma unroll
    for (int a = 0; a < 5; ++a) w0r[a] = w0[a * 64 + lane] * 0.4472135954999579f; // 1/sqrt(5)
  }
  const float* Wc = W1 + 512;   // col t=8 (fp32): Wc[k*576 + lane]

  const int nB = (E + 47) / 48;
  for (int b = blockIdx.x; b < nB; b += (int)gridDim.x) {
    const int ebase = b * 48 + wv * 6;
    int outn[6];
    bool val[6];
    float h[6];
#pragma unroll
    for (int s = 0; s < 6; ++s) {
      const int e0 = ebase + s;
      val[s] = e0 < E;
      const int e = val[s] ? e0 : 0;
      const int ia = ei[e], ib = ei[E + e];
      int nsrc;
      if (MODE == 0) { nsrc = ia; outn[s] = ib; }   // src features, scatter to dst
      else           { nsrc = ib; outn[s] = e;  }   // lig features, store per edge
      const float vx = pos[ib * 3]     - pos[ia * 3];
      const float vy = pos[ib * 3 + 1] - pos[ia * 3 + 1];
      const float vz = pos[ib * 3 + 2] - pos[ia * 3 + 2];
      const float rn = rsqrtf(vx * vx + vy * vy + vz * vz);
      const float rx = vx * rn, ry = vy * rn, rz = vz * rn;
      if (MODE == 0) {
        float acc = 0.f;
#pragma unroll
        for (int a = 0; a < 5; ++a) acc = fmaf(eattr[(size_t)e * 5 + a], w0r[a], acc);
        h[s] = silu_n(acc) * 0.125f;          // fold 1/sqrt(64)
      } else {
        h[s] = hSrc[(size_t)e * 64 + lane] * 0.125f;
      }
      if (lane < 16) {
        sF[wv][s][lane] = node[(size_t)nsrc * 40 + lane];           // xs
      } else if (lane < 24) {
        const int u = lane - 16;
        const float x0 = node[(size_t)nsrc * 40 + 16 + u * 3];
        const float x1 = node[(size_t)nsrc * 40 + 16 + u * 3 + 1];
        const float x2 = node[(size_t)nsrc * 40 + 16 + u * 3 + 2];
        sF[wv][s][16 + u]         = x0 * rx + x1 * ry + x2 * rz;    // dot(xv, r^)
        sF[wv][s][24 + u * 3]     = x0;                             // xv
        sF[wv][s][24 + u * 3 + 1] = x1;
        sF[wv][s][24 + u * 3 + 2] = x2;
      } else if (lane < 27) {
        sF[wv][s][48 + (lane - 24)] = (lane == 24) ? rx : ((lane == 25) ? ry : rz);
      }
    }
    // no barrier: sF slices per-wave private; h per-lane registers

    float wacc[6][9];
#pragma unroll
    for (int s = 0; s < 6; ++s)
#pragma unroll
      for (int t = 0; t < 9; ++t) wacc[s][t] = 0.f;

    float wcur[4], wnxt[4];
#pragma unroll
    for (int kk = 0; kk < 4; ++kk) wcur[kk] = Wc[kk * 576 + lane];

    for (int k4 = 0; k4 < 64; k4 += 4) {
      if (k4 < 60) {
#pragma unroll
        for (int kk = 0; kk < 4; ++kk) wnxt[kk] = Wc[(size_t)(k4 + 4 + kk) * 576 + lane];
      }
#pragma unroll
      for (int kk = 0; kk < 4; ++kk) {
        const int k = k4 + kk;
        const uint4 q = sAB[k * 64 + lane];
        const float wA0 = unpk_lo(q.x), wA1 = unpk_hi(q.x);
        const float wA2 = unpk_lo(q.y), wA3 = unpk_hi(q.y);
        const float wB0 = unpk_lo(q.z), wB1 = unpk_hi(q.z);
        const float wB2 = unpk_lo(q.w), wB3 = unpk_hi(q.w);
        const float wc  = wcur[kk];
#pragma unroll
        for (int s = 0; s < 6; ++s) {
          const float hv = bcast_lane(h[s], k);
          wacc[s][0] = fmaf(hv, wA0, wacc[s][0]);
          wacc[s][1] = fmaf(hv, wA1, wacc[s][1]);
          wacc[s][2] = fmaf(hv, wA2, wacc[s][2]);
          wacc[s][3] = fmaf(hv, wA3, wacc[s][3]);
          wacc[s][4] = fmaf(hv, wB0, wacc[s][4]);
          wacc[s][5] = fmaf(hv, wB1, wacc[s][5]);
          wacc[s][6] = fmaf(hv, wB2, wacc[s][6]);
          wacc[s][7] = fmaf(hv, wB3, wacc[s][7]);
          wacc[s][8] = fmaf(hv, wc,  wacc[s][8]);
        }
      }
      if (k4 < 60) {
#pragma unroll
        for (int kk = 0; kk < 4; ++kk) wcur[kk] = wnxt[kk];
      }
    }

    // TP epilogue. t=0..5 scalar-path (out col = lane&15, U=(lane>>4)+4t),
    // t=6..8 vector-path (out col = lane&7, U=(lane>>3)+8(t-6)).
    const int ub  = lane >> 4;
    const int ub2 = lane >> 3;
#pragma unroll
    for (int s = 0; s < 6; ++s) {
      float cs = 0.f;
#pragma unroll
      for (int t = 0; t < 6; ++t)
        cs = fmaf(PW0 * sF[wv][s][ub + 4 * t], wacc[s][t], cs);
      cs += __shfl_xor(cs, 16);
      cs += __shfl_xor(cs, 32);

      const float rx = sF[wv][s][48], ry = sF[wv][s][49], rz = sF[wv][s][50];
      const float sxw = PW1 * (sF[wv][s][ub2] * wacc[s][6] + sF[wv][s][ub2 + 8] * wacc[s][7]);
      float cv0 = fmaf(PW0 * sF[wv][s][24 + ub2 * 3],     wacc[s][8], sxw * rx);
      float cv1 = fmaf(PW0 * sF[wv][s][24 + ub2 * 3 + 1], wacc[s][8], sxw * ry);
      float cv2 = fmaf(PW0 * sF[wv][s][24 + ub2 * 3 + 2], wacc[s][8], sxw * rz);
      cv0 += __shfl_xor(cv0, 8); cv0 += __shfl_xor(cv0, 16); cv0 += __shfl_xor(cv0, 32);
      cv1 += __shfl_xor(cv1, 8); cv1 += __shfl_xor(cv1, 16); cv1 += __shfl_xor(cv1, 32);
      cv2 += __shfl_xor(cv2, 8); cv2 += __shfl_xor(cv2, 16); cv2 += __shfl_xor(cv2, 32);

      if (val[s]) {
        const size_t ob = (size_t)outn[s] * 40;
        if (MODE == 0) {
          if (lane < 16) atomicAdd(&out[ob + lane], cs);
          if (lane < 8) {
            atomicAdd(&out[ob + 16 + lane * 3],     cv0);
            atomicAdd(&out[ob + 16 + lane * 3 + 1], cv1);
            atomicAdd(&out[ob + 16 + lane * 3 + 2], cv2);
          }
        } else {
          if (lane < 16) out[ob + lane] = cs;
          if (lane < 8) {
            out[ob + 16 + lane * 3]     = cv0;
            out[ob + 16 + lane * 3 + 1] = cv1;
            out[ob + 16 + lane * 3 + 2] = cv2;
          }
        }
      }
    }
  }
}

// ---------------- rec MLP (layer2, 64x2560) + node x node -> 8x0e TP ----------------
// Persistent 512-col bf16 weight chunk per block (blockIdx.y = chunk 0..4), staged
// ONCE. Edge loop barrier-free; partials atomicAdd'd (out zeroed first). S=6,
// LDS 80.9 KB -> 2 blocks/CU. launch_bounds(512,2): no VGPR squeeze (see tp note).
__global__ __launch_bounds__(512, 2)
void rec_kernel(const float* __restrict__ node, const float* __restrict__ ligE,
                const int* __restrict__ iei, const float* __restrict__ RW1,
                const float* __restrict__ hR, float* __restrict__ out, int EI) {
  __shared__ uint4 sW[64 * 64];                     // 65536 B: chunk cols t=0..7 bf16
  __shared__ float sF[8][6][80];                    // 15360 B -> 80896 B total
  const int tid  = threadIdx.x;
  const int lane = tid & 63;
  const int wv   = tid >> 6;
  const int cg   = blockIdx.y;                      // 0..4

  for (int j = tid; j < 4096; j += 512) {
    const int k = j >> 6, l = j & 63;
    const float* src = &RW1[(size_t)k * 2560 + cg * 512 + l];
    uint4 q;
    q.x = pack_bf2(src[0],   src[64]);
    q.y = pack_bf2(src[128], src[192]);
    q.z = pack_bf2(src[256], src[320]);
    q.w = pack_bf2(src[384], src[448]);
    sW[j] = q;
  }
  __syncthreads();

  const int nB = (EI + 47) / 48;
  for (int b = blockIdx.x; b < nB; b += (int)gridDim.x) {
    const int ebase = b * 48 + wv * 6;
    bool val[6]; int eidx[6]; float h[6];
#pragma unroll
    for (int s = 0; s < 6; ++s) {
      const int e0 = ebase + s;
      val[s] = e0 < EI;
      const int e = val[s] ? e0 : 0;
      eidx[s] = e;
      h[s] = hR[(size_t)e * 64 + lane] * 0.125f;    // fold 1/sqrt(64)
      const int rec = iei[e];
      if (lane < 40) {
        sF[wv][s][lane]      = ligE[(size_t)e * 40 + lane];        // xs_l[0:16], xv_l[16:40]
        sF[wv][s][40 + lane] = node[(size_t)rec * 40 + lane];      // ys_r[40:56], yv_r[56:80]
      }
    }

    float wacc[6][8];
#pragma unroll
    for (int s = 0; s < 6; ++s)
#pragma unroll
      for (int t = 0; t < 8; ++t) wacc[s][t] = 0.f;

    for (int k4 = 0; k4 < 64; k4 += 4) {
#pragma unroll
      for (int kk = 0; kk < 4; ++kk) {
        const int k = k4 + kk;
        const uint4 q = sW[k * 64 + lane];
        const float w0v = unpk_lo(q.x), w1v = unpk_hi(q.x);
        const float w2v = unpk_lo(q.y), w3v = unpk_hi(q.y);
        const float w4v = unpk_lo(q.z), w5v = unpk_hi(q.z);
        const float w6v = unpk_lo(q.w), w7v = unpk_hi(q.w);
#pragma unroll
        for (int s = 0; s < 6; ++s) {
          const float hv = bcast_lane(h[s], k);
          wacc[s][0] = fmaf(hv, w0v, wacc[s][0]);
          wacc[s][1] = fmaf(hv, w1v, wacc[s][1]);
          wacc[s][2] = fmaf(hv, w2v, wacc[s][2]);
          wacc[s][3] = fmaf(hv, w3v, wacc[s][3]);
          wacc[s][4] = fmaf(hv, w4v, wacc[s][4]);
          wacc[s][5] = fmaf(hv, w5v, wacc[s][5]);
          wacc[s][6] = fmaf(hv, w6v, wacc[s][6]);
          wacc[s][7] = fmaf(hv, w7v, wacc[s][7]);
        }
      }
    }

    // epilogue: m = cg*512 + t*64 + lane ; col = lane&7 ; uv = cg*64 + t*8 + (lane>>3)
    const int l3 = lane >> 3;
    if (cg < 4) {                 // scalar path: uv < 256
#pragma unroll
      for (int s = 0; s < 6; ++s) {
        float o = 0.f;
#pragma unroll
        for (int t = 0; t < 8; ++t) {
          const int uv = cg * 64 + t * 8 + l3;
          const int u = uv >> 4, v = uv & 15;
          o = fmaf(sF[wv][s][u] * sF[wv][s][40 + v], wacc[s][t], o);
        }
        o += __shfl_xor(o, 8); o += __shfl_xor(o, 16); o += __shfl_xor(o, 32);
        if (val[s] && lane < 8) atomicAdd(&out[(size_t)eidx[s] * 8 + lane], o * PWREC);
      }
    } else {                      // vector path: u = t, v = l3
#pragma unroll
      for (int s = 0; s < 6; ++s) {
        float o = 0.f;
#pragma unroll
        for (int t = 0; t < 8; ++t) {
          const float dp = sF[wv][s][16 + t * 3]     * sF[wv][s][56 + l3 * 3]
                         + sF[wv][s][16 + t * 3 + 1] * sF[wv][s][56 + l3 * 3 + 1]
                         + sF[wv][s][16 + t * 3 + 2] * sF[wv][s][56 + l3 * 3 + 2];
          o = fmaf(dp * INV_SQ3, wacc[s][t], o);
        }
        o += __shfl_xor(o, 8); o += __shfl_xor(o, 16); o += __shfl_xor(o, 32);
        if (val[s] && lane < 8) atomicAdd(&out[(size_t)eidx[s] * 8 + lane], o * PWREC);
      }
    }
  }
}

extern "C" void kernel_launch(void* const* d_in, const int* in_sizes, int n_in,
                              void* d_out, int out_size, void* d_ws, size_t ws_size,
                              hipStream_t stream) {
  (void)n_in; (void)ws_size;
  const float* x      = (const float*)d_in[0];
  const float* pos    = (const float*)d_in[1];
  const int*   ei     = (const int*)  d_in[2];
  const float* eattr  = (const float*)d_in[3];
  const int*   iei    = (const int*)  d_in[4];
  const float* emb_w0 = (const float*)d_in[5];
  const float* emb_w1 = (const float*)d_in[6];
  const float* imp0   = (const float*)d_in[7];
  const float* m0w0   = (const float*)d_in[8];
  const float* m0w1   = (const float*)d_in[9];
  const float* u0w0   = (const float*)d_in[10];
  const float* u0w1   = (const float*)d_in[11];
  const float* imp1   = (const float*)d_in[12];
  const float* m1w0   = (const float*)d_in[13];
  const float* m1w1   = (const float*)d_in[14];
  const float* u1w0   = (const float*)d_in[15];
  const float* u1w1   = (const float*)d_in[16];
  const float* lw0    = (const float*)d_in[17];
  const float* lw1    = (const float*)d_in[18];
  const float* rw0    = (const float*)d_in[19];
  const float* rw1    = (const float*)d_in[20];

  const int N  = in_sizes[1] / 3;
  const int E  = in_sizes[2] / 2;
  const int EI = in_sizes[4] / 2;

  float* node = (float*)d_ws;
  float* msgs = node + (size_t)N * 40;
  float* hL   = msgs + (size_t)N * 40;
  float* hR   = hL + (size_t)EI * 64;
  float* ligE = hR + (size_t)EI * 64;
  float* outp = (float*)d_out;

  const float inv_sqrt_deg = 1.0f / sqrtf((float)E / (float)N);

  const int nodeBlocks  = (N + 3) / 4;
  const int interBlocks = (EI + 3) / 4;

  emb_kernel<<<nodeBlocks, 256, 0, stream>>>(x, emb_w0, emb_w1, node, N);

  // message pass 0
  hipMemsetAsync(msgs, 0, (size_t)N * 40 * sizeof(float), stream);
  tp_kernel<0><<<512, 512, 0, stream>>>(node, pos, ei, eattr, m0w0, m0w1, nullptr, msgs, E);
  upd_kernel<<<nodeBlocks, 256, 0, stream>>>(node, msgs, u0w0, u0w1, imp0, 1.0f, inv_sqrt_deg, N);

  // message pass 1
  hipMemsetAsync(msgs, 0, (size_t)N * 40 * sizeof(float), stream);
  tp_kernel<0><<<512, 512, 0, stream>>>(node, pos, ei, eattr, m1w0, m1w1, nullptr, msgs, E);
  upd_kernel<<<nodeBlocks, 256, 0, stream>>>(node, msgs, u1w0, u1w1, imp1, 0.5f, inv_sqrt_deg, N);

  // inter edges
  inter_h_kernel<<<interBlocks, 256, 0, stream>>>(pos, iei, lw0, rw0, hL, hR, EI);
  tp_kernel<1><<<512, 512, 0, stream>>>(node, pos, iei, nullptr, nullptr, lw1, hL, ligE, EI);

  hipMemsetAsync(outp, 0, (size_t)out_size * sizeof(float), stream);
  rec_kernel<<<dim3(102, 5), 512, 0, stream>>>(node, ligE, iei, rw1, hR, outp, EI);
}

// Round 9
// 641.195 us; speedup vs baseline: 2.9849x; 1.1934x over previous
//
#include <hip/hip_runtime.h>
#include <hip/hip_fp16.h>
#include <cmath>

// ---- constants from the reference ----
constexpr float ACT_NORM = 1.6789717f;
constexpr float PW0      = 0.20412414523193154f;   // sqrt(1/24)  (== pw1/sqrt3)
constexpr float PW1      = 0.35355339059327373f;   // sqrt(3/24)
constexpr float PWREC    = 0.05590169943749474f;   // sqrt(1/320)
constexpr float INV_SQ3  = 0.57735026918962576f;
// second-layer 1/sqrt(64) folded into the epilogue constants (keeps h in fp16 range)
constexpr float PW0s     = PW0 * 0.125f;
constexpr float PW1s     = PW1 * 0.125f;
constexpr float PWRECs   = PWREC * 0.125f;

__device__ __forceinline__ float silu_n(float x) {
  return x / (1.f + __expf(-x)) * ACT_NORM;
}

__device__ __forceinline__ float bcast_lane(float v, int k) {
  return __int_as_float(__builtin_amdgcn_readlane(__float_as_int(v), k));
}
__device__ __forceinline__ unsigned ubcast_lane(unsigned v, int k) {
  return (unsigned)__builtin_amdgcn_readlane((int)v, k);
}

// fp16 pair pack / dot2 (v_dot2_f32_f16: 2 MACs per issue, fp32 accumulate)
typedef _Float16 h2v __attribute__((ext_vector_type(2)));
__device__ __forceinline__ unsigned packh2(float a, float b) {
  h2v p; p.x = (_Float16)a; p.y = (_Float16)b;
  return __builtin_bit_cast(unsigned, p);
}
__device__ __forceinline__ float dot2h(unsigned w2, unsigned h2, float acc) {
  return __builtin_amdgcn_fdot2(__builtin_bit_cast(h2v, w2),
                                __builtin_bit_cast(h2v, h2), acc, false);
}

// ---------------- node embedding: node[:, :16] = mlp(x), geo = 0 ----------------
__global__ __launch_bounds__(256)
void emb_kernel(const float* __restrict__ x, const float* __restrict__ w0,
                const float* __restrict__ w1, float* __restrict__ node, int N) {
  const int lane = threadIdx.x & 63;
  const int lw   = threadIdx.x >> 6;
  const int gw   = blockIdx.x * 4 + lw;
  __shared__ float sH[4][64];
  const bool valid = gw < N;
  const int n = valid ? gw : 0;
  float acc = 0.f;
#pragma unroll
  for (int a = 0; a < 10; ++a) acc = fmaf(x[n * 10 + a], w0[a * 64 + lane], acc);
  acc *= 0.31622776601683794f;   // 1/sqrt(10)
  sH[lw][lane] = silu_n(acc);
  __syncthreads();
  if (valid) {
    if (lane < 16) {
      float o = 0.f;
#pragma unroll
      for (int k = 0; k < 64; ++k) o = fmaf(sH[lw][k], w1[k * 16 + lane], o);
      node[(size_t)n * 40 + lane] = o * 0.125f;  // 1/sqrt(64)
    } else if (lane < 40) {
      node[(size_t)n * 40 + lane] = 0.f;
    }
  }
}

// ---------------- node update (per mp step) ----------------
__global__ __launch_bounds__(256)
void upd_kernel(float* __restrict__ node, const float* __restrict__ msgs,
                const float* __restrict__ w0, const float* __restrict__ w1,
                const float* __restrict__ imp, float geo_scale, float inv_sqrt_deg, int N) {
  const int lane = threadIdx.x & 63;
  const int lw   = threadIdx.x >> 6;
  const int gw   = blockIdx.x * 4 + lw;
  __shared__ float sIn[4][32];
  __shared__ float sH[4][64];
  const bool valid = gw < N;
  const int n = valid ? gw : 0;
  const float mscale = imp[0] * inv_sqrt_deg;
  if (lane < 16)      sIn[lw][lane] = msgs[(size_t)n * 40 + lane] * mscale;
  else if (lane < 32) sIn[lw][lane] = node[(size_t)n * 40 + lane - 16];
  __syncthreads();
  float acc = 0.f;
#pragma unroll
  for (int a = 0; a < 32; ++a) acc = fmaf(sIn[lw][a], w0[a * 64 + lane], acc);
  acc *= 0.17677669529663687f;   // 1/sqrt(32)
  sH[lw][lane] = silu_n(acc);
  __syncthreads();
  if (valid) {
    if (lane < 16) {
      float o = 0.f;
#pragma unroll
      for (int k = 0; k < 64; ++k) o = fmaf(sH[lw][k], w1[k * 16 + lane], o);
      node[(size_t)n * 40 + lane] = o * 0.125f;
    } else if (lane < 40) {
      const size_t gi = (size_t)n * 40 + lane;
      node[gi] = fmaf(msgs[gi], mscale, node[gi]) * geo_scale;
    }
  }
}

// ---------------- inter-edge: distance embedding -> both hidden vectors ----------------
__global__ __launch_bounds__(256)
void inter_h_kernel(const float* __restrict__ pos, const int* __restrict__ iei,
                    const float* __restrict__ lw0, const float* __restrict__ rw0,
                    float* __restrict__ hL, float* __restrict__ hR, int EI) {
  const int lane = threadIdx.x & 63;
  const int lw   = threadIdx.x >> 6;
  const int gw   = blockIdx.x * 4 + lw;
  __shared__ float sD[4][20];
  const bool valid = gw < EI;
  const int e = valid ? gw : 0;
  const int rec = iei[e], lig = iei[EI + e];
  const float dx = pos[lig * 3]     - pos[rec * 3];
  const float dy = pos[lig * 3 + 1] - pos[rec * 3 + 1];
  const float dz = pos[lig * 3 + 2] - pos[rec * 3 + 2];
  const float d = sqrtf(dx * dx + dy * dy + dz * dz);
  if (lane < 20) {
    const float diff = d * 4.2f - (float)(lane + 1);
    const float t1 = diff + 1.f, t2 = 1.f - diff;
    float v = 0.f;
    if (t1 > 0.f && t2 > 0.f) {
      const float C = 1.14136f * 7.3890560989306495f * 4.4721359549995794f; // 1.14136*e^2*sqrt(20)
      v = C * __expf(-1.f / t1 - 1.f / t2);
    }
    sD[lw][lane] = v;
  }
  __syncthreads();
  float a0 = 0.f, a1 = 0.f;
#pragma unroll
  for (int b = 0; b < 20; ++b) {
    const float db = sD[lw][b];
    a0 = fmaf(db, lw0[b * 64 + lane], a0);
    a1 = fmaf(db, rw0[b * 64 + lane], a1);
  }
  a0 *= 0.22360679774997896f;  // 1/sqrt(20)
  a1 *= 0.22360679774997896f;
  if (valid) {
    hL[(size_t)e * 64 + lane] = silu_n(a0);
    hR[(size_t)e * 64 + lane] = silu_n(a1);
  }
}

// ---------------- fused edge MLP (layer2) + node x sh tensor product ----------------
// Weight cols t=0..7 in LDS as k-pair-packed fp16: sWa[kp][lane] = cols 0-3,
// sWb = cols 4-7 (16B/lane stride, proven conflict-free). Inner loop uses
// v_dot2_f32_f16 (2 MACs/issue, fp32 accum). h packed to fp16 k-pairs per edge
// (hp) + kept fp32 for the t=8 column (fp32 global-prefetch, proven 8-reg path).
// S=6 edges/wave, LDS 75.5 KB -> 2 blocks/CU, launch_bounds(512,2) (no VGPR squeeze).
template <int MODE>
__global__ __launch_bounds__(512, 2)
void tp_kernel(const float* __restrict__ node, const float* __restrict__ pos,
               const int* __restrict__ ei, const float* __restrict__ eattr,
               const float* __restrict__ w0, const float* __restrict__ W1,
               const float* __restrict__ hSrc, float* __restrict__ out, int E) {
  __shared__ __align__(16) uint4 sWa[32 * 64];      // 32768 B: cols t=0..3, k-paired
  __shared__ __align__(16) uint4 sWb[32 * 64];      // 32768 B: cols t=4..7
  __shared__ float sF[8][6][52];                    //  9984 B -> 75520 B total
  const int tid  = threadIdx.x;
  const int lane = tid & 63;
  const int wv   = tid >> 6;

  // stage packed weights once per block: dword = (W[2kp][m], W[2kp+1][m]) fp16
  for (int j = tid; j < 2048; j += 512) {
    const int kp = j >> 6, l = j & 63;
    const float* s0 = &W1[(2 * kp) * 576 + l];
    const float* s1 = s0 + 576;
    uint4 qa, qb;
    qa.x = packh2(s0[0],   s1[0]);
    qa.y = packh2(s0[64],  s1[64]);
    qa.z = packh2(s0[128], s1[128]);
    qa.w = packh2(s0[192], s1[192]);
    qb.x = packh2(s0[256], s1[256]);
    qb.y = packh2(s0[320], s1[320]);
    qb.z = packh2(s0[384], s1[384]);
    qb.w = packh2(s0[448], s1[448]);
    sWa[j] = qa;
    sWb[j] = qb;
  }
  __syncthreads();

  float w0r[5];
  if (MODE == 0) {
#pragma unroll
    for (int a = 0; a < 5; ++a) w0r[a] = w0[a * 64 + lane] * 0.4472135954999579f; // 1/sqrt(5)
  }
  const float* Wc = W1 + 512;   // col t=8 (fp32): Wc[k*576 + lane]
  const int kl2 = (lane & 31) * 2;

  const int nB = (E + 47) / 48;
  for (int b = blockIdx.x; b < nB; b += (int)gridDim.x) {
    const int ebase = b * 48 + wv * 6;
    int outn[6];
    bool val[6];
    float h[6];
    unsigned hp[6];
#pragma unroll
    for (int s = 0; s < 6; ++s) {
      const int e0 = ebase + s;
      val[s] = e0 < E;
      const int e = val[s] ? e0 : 0;
      const int ia = ei[e], ib = ei[E + e];
      int nsrc;
      if (MODE == 0) { nsrc = ia; outn[s] = ib; }   // src features, scatter to dst
      else           { nsrc = ib; outn[s] = e;  }   // lig features, store per edge
      const float vx = pos[ib * 3]     - pos[ia * 3];
      const float vy = pos[ib * 3 + 1] - pos[ia * 3 + 1];
      const float vz = pos[ib * 3 + 2] - pos[ia * 3 + 2];
      const float rn = rsqrtf(vx * vx + vy * vy + vz * vz);
      const float rx = vx * rn, ry = vy * rn, rz = vz * rn;
      if (MODE == 0) {
        float acc = 0.f;
#pragma unroll
        for (int a = 0; a < 5; ++a) acc = fmaf(eattr[(size_t)e * 5 + a], w0r[a], acc);
        h[s] = silu_n(acc);                 // unscaled; 1/8 folded into epilogue
      } else {
        h[s] = hSrc[(size_t)e * 64 + lane];
      }
      hp[s] = packh2(__shfl(h[s], kl2), __shfl(h[s], kl2 + 1));   // fp16 k-pair
      if (lane < 16) {
        sF[wv][s][lane] = node[(size_t)nsrc * 40 + lane];           // xs
      } else if (lane < 24) {
        const int u = lane - 16;
        const float x0 = node[(size_t)nsrc * 40 + 16 + u * 3];
        const float x1 = node[(size_t)nsrc * 40 + 16 + u * 3 + 1];
        const float x2 = node[(size_t)nsrc * 40 + 16 + u * 3 + 2];
        sF[wv][s][16 + u]         = x0 * rx + x1 * ry + x2 * rz;    // dot(xv, r^)
        sF[wv][s][24 + u * 3]     = x0;                             // xv
        sF[wv][s][24 + u * 3 + 1] = x1;
        sF[wv][s][24 + u * 3 + 2] = x2;
      } else if (lane < 27) {
        sF[wv][s][48 + (lane - 24)] = (lane == 24) ? rx : ((lane == 25) ? ry : rz);
      }
    }
    // no barrier: sF slices per-wave private; h/hp per-lane registers

    float wacc[6][9];
#pragma unroll
    for (int s = 0; s < 6; ++s)
#pragma unroll
      for (int t = 0; t < 9; ++t) wacc[s][t] = 0.f;

    float wcur[4], wnxt[4];
#pragma unroll
    for (int kk = 0; kk < 4; ++kk) wcur[kk] = Wc[kk * 576 + lane];

    for (int k4 = 0; k4 < 64; k4 += 4) {
      if (k4 < 60) {
#pragma unroll
        for (int kk = 0; kk < 4; ++kk) wnxt[kk] = Wc[(size_t)(k4 + 4 + kk) * 576 + lane];
      }
      const int kp0 = k4 >> 1;
#pragma unroll
      for (int kph = 0; kph < 2; ++kph) {             // two k-pairs = 4 k's
        const int kp = kp0 + kph;
        const uint4 qa = sWa[kp * 64 + lane];
        const uint4 qb = sWb[kp * 64 + lane];
#pragma unroll
        for (int s = 0; s < 6; ++s) {
          const unsigned hv2 = ubcast_lane(hp[s], kp);
          wacc[s][0] = dot2h(qa.x, hv2, wacc[s][0]);
          wacc[s][1] = dot2h(qa.y, hv2, wacc[s][1]);
          wacc[s][2] = dot2h(qa.z, hv2, wacc[s][2]);
          wacc[s][3] = dot2h(qa.w, hv2, wacc[s][3]);
          wacc[s][4] = dot2h(qb.x, hv2, wacc[s][4]);
          wacc[s][5] = dot2h(qb.y, hv2, wacc[s][5]);
          wacc[s][6] = dot2h(qb.z, hv2, wacc[s][6]);
          wacc[s][7] = dot2h(qb.w, hv2, wacc[s][7]);
        }
      }
#pragma unroll
      for (int kk = 0; kk < 4; ++kk) {                // t=8 column, fp32
        const float wc = wcur[kk];
#pragma unroll
        for (int s = 0; s < 6; ++s)
          wacc[s][8] = fmaf(bcast_lane(h[s], k4 + kk), wc, wacc[s][8]);
      }
      if (k4 < 60) {
#pragma unroll
        for (int kk = 0; kk < 4; ++kk) wcur[kk] = wnxt[kk];
      }
    }

    // TP epilogue. t=0..5 scalar-path (out col = lane&15, U=(lane>>4)+4t),
    // t=6..8 vector-path (out col = lane&7, U=(lane>>3)+8(t-6)). 1/8 scale folded.
    const int ub  = lane >> 4;
    const int ub2 = lane >> 3;
#pragma unroll
    for (int s = 0; s < 6; ++s) {
      float cs = 0.f;
#pragma unroll
      for (int t = 0; t < 6; ++t)
        cs = fmaf(PW0s * sF[wv][s][ub + 4 * t], wacc[s][t], cs);
      cs += __shfl_xor(cs, 16);
      cs += __shfl_xor(cs, 32);

      const float rx = sF[wv][s][48], ry = sF[wv][s][49], rz = sF[wv][s][50];
      const float sxw = PW1s * (sF[wv][s][ub2] * wacc[s][6] + sF[wv][s][ub2 + 8] * wacc[s][7]);
      float cv0 = fmaf(PW0s * sF[wv][s][24 + ub2 * 3],     wacc[s][8], sxw * rx);
      float cv1 = fmaf(PW0s * sF[wv][s][24 + ub2 * 3 + 1], wacc[s][8], sxw * ry);
      float cv2 = fmaf(PW0s * sF[wv][s][24 + ub2 * 3 + 2], wacc[s][8], sxw * rz);
      cv0 += __shfl_xor(cv0, 8); cv0 += __shfl_xor(cv0, 16); cv0 += __shfl_xor(cv0, 32);
      cv1 += __shfl_xor(cv1, 8); cv1 += __shfl_xor(cv1, 16); cv1 += __shfl_xor(cv1, 32);
      cv2 += __shfl_xor(cv2, 8); cv2 += __shfl_xor(cv2, 16); cv2 += __shfl_xor(cv2, 32);

      if (val[s]) {
        const size_t ob = (size_t)outn[s] * 40;
        if (MODE == 0) {
          if (lane < 16) atomicAdd(&out[ob + lane], cs);
          if (lane < 8) {
            atomicAdd(&out[ob + 16 + lane * 3],     cv0);
            atomicAdd(&out[ob + 16 + lane * 3 + 1], cv1);
            atomicAdd(&out[ob + 16 + lane * 3 + 2], cv2);
          }
        } else {
          if (lane < 16) out[ob + lane] = cs;
          if (lane < 8) {
            out[ob + 16 + lane * 3]     = cv0;
            out[ob + 16 + lane * 3 + 1] = cv1;
            out[ob + 16 + lane * 3 + 2] = cv2;
          }
        }
      }
    }
  }
}

// ---------------- rec MLP (layer2, 64x2560) + node x node -> 8x0e TP ----------------
// Persistent 512-col chunk per block (blockIdx.y = 0..4), k-pair fp16 packed,
// staged ONCE; inner loop all dot2. Edge loop barrier-free; partials atomicAdd'd.
// LDS 80.9 KB -> 2 blocks/CU. Chunk cg<4 = scalar CG region; cg==4 = vector.
__global__ __launch_bounds__(512, 2)
void rec_kernel(const float* __restrict__ node, const float* __restrict__ ligE,
                const int* __restrict__ iei, const float* __restrict__ RW1,
                const float* __restrict__ hR, float* __restrict__ out, int EI) {
  __shared__ __align__(16) uint4 sWa[32 * 64];      // 32768 B: chunk cols t=0..3
  __shared__ __align__(16) uint4 sWb[32 * 64];      // 32768 B: cols t=4..7
  __shared__ float sF[8][6][80];                    // 15360 B -> 80896 B total
  const int tid  = threadIdx.x;
  const int lane = tid & 63;
  const int wv   = tid >> 6;
  const int cg   = blockIdx.y;                      // 0..4
  const int kl2  = (lane & 31) * 2;

  for (int j = tid; j < 2048; j += 512) {
    const int kp = j >> 6, l = j & 63;
    const float* s0 = &RW1[(size_t)(2 * kp) * 2560 + cg * 512 + l];
    const float* s1 = s0 + 2560;
    uint4 qa, qb;
    qa.x = packh2(s0[0],   s1[0]);
    qa.y = packh2(s0[64],  s1[64]);
    qa.z = packh2(s0[128], s1[128]);
    qa.w = packh2(s0[192], s1[192]);
    qb.x = packh2(s0[256], s1[256]);
    qb.y = packh2(s0[320], s1[320]);
    qb.z = packh2(s0[384], s1[384]);
    qb.w = packh2(s0[448], s1[448]);
    sWa[j] = qa;
    sWb[j] = qb;
  }
  __syncthreads();

  const int nB = (EI + 47) / 48;
  for (int b = blockIdx.x; b < nB; b += (int)gridDim.x) {
    const int ebase = b * 48 + wv * 6;
    bool val[6]; int eidx[6]; unsigned hp[6];
#pragma unroll
    for (int s = 0; s < 6; ++s) {
      const int e0 = ebase + s;
      val[s] = e0 < EI;
      const int e = val[s] ? e0 : 0;
      eidx[s] = e;
      const float hh = hR[(size_t)e * 64 + lane];   // unscaled; 1/8 in epilogue
      hp[s] = packh2(__shfl(hh, kl2), __shfl(hh, kl2 + 1));
      const int rec = iei[e];
      if (lane < 40) {
        sF[wv][s][lane]      = ligE[(size_t)e * 40 + lane];        // xs_l[0:16], xv_l[16:40]
        sF[wv][s][40 + lane] = node[(size_t)rec * 40 + lane];      // ys_r[40:56], yv_r[56:80]
      }
    }

    float wacc[6][8];
#pragma unroll
    for (int s = 0; s < 6; ++s)
#pragma unroll
      for (int t = 0; t < 8; ++t) wacc[s][t] = 0.f;

#pragma unroll 2
    for (int kp = 0; kp < 32; ++kp) {
      const uint4 qa = sWa[kp * 64 + lane];
      const uint4 qb = sWb[kp * 64 + lane];
#pragma unroll
      for (int s = 0; s < 6; ++s) {
        const unsigned hv2 = ubcast_lane(hp[s], kp);
        wacc[s][0] = dot2h(qa.x, hv2, wacc[s][0]);
        wacc[s][1] = dot2h(qa.y, hv2, wacc[s][1]);
        wacc[s][2] = dot2h(qa.z, hv2, wacc[s][2]);
        wacc[s][3] = dot2h(qa.w, hv2, wacc[s][3]);
        wacc[s][4] = dot2h(qb.x, hv2, wacc[s][4]);
        wacc[s][5] = dot2h(qb.y, hv2, wacc[s][5]);
        wacc[s][6] = dot2h(qb.z, hv2, wacc[s][6]);
        wacc[s][7] = dot2h(qb.w, hv2, wacc[s][7]);
      }
    }

    // epilogue: m = cg*512 + t*64 + lane ; col = lane&7 ; uv = cg*64 + t*8 + (lane>>3)
    const int l3 = lane >> 3;
    if (cg < 4) {                 // scalar path: uv < 256
#pragma unroll
      for (int s = 0; s < 6; ++s) {
        float o = 0.f;
#pragma unroll
        for (int t = 0; t < 8; ++t) {
          const int uv = cg * 64 + t * 8 + l3;
          const int u = uv >> 4, v = uv & 15;
          o = fmaf(sF[wv][s][u] * sF[wv][s][40 + v], wacc[s][t], o);
        }
        o += __shfl_xor(o, 8); o += __shfl_xor(o, 16); o += __shfl_xor(o, 32);
        if (val[s] && lane < 8) atomicAdd(&out[(size_t)eidx[s] * 8 + lane], o * PWRECs);
      }
    } else {                      // vector path: u = t, v = l3
#pragma unroll
      for (int s = 0; s < 6; ++s) {
        float o = 0.f;
#pragma unroll
        for (int t = 0; t < 8; ++t) {
          const float dp = sF[wv][s][16 + t * 3]     * sF[wv][s][56 + l3 * 3]
                         + sF[wv][s][16 + t * 3 + 1] * sF[wv][s][56 + l3 * 3 + 1]
                         + sF[wv][s][16 + t * 3 + 2] * sF[wv][s][56 + l3 * 3 + 2];
          o = fmaf(dp * INV_SQ3, wacc[s][t], o);
        }
        o += __shfl_xor(o, 8); o += __shfl_xor(o, 16); o += __shfl_xor(o, 32);
        if (val[s] && lane < 8) atomicAdd(&out[(size_t)eidx[s] * 8 + lane], o * PWRECs);
      }
    }
  }
}

extern "C" void kernel_launch(void* const* d_in, const int* in_sizes, int n_in,
                              void* d_out, int out_size, void* d_ws, size_t ws_size,
                              hipStream_t stream) {
  (void)n_in; (void)ws_size;
  const float* x      = (const float*)d_in[0];
  const float* pos    = (const float*)d_in[1];
  const int*   ei     = (const int*)  d_in[2];
  const float* eattr  = (const float*)d_in[3];
  const int*   iei    = (const int*)  d_in[4];
  const float* emb_w0 = (const float*)d_in[5];
  const float* emb_w1 = (const float*)d_in[6];
  const float* imp0   = (const float*)d_in[7];
  const float* m0w0   = (const float*)d_in[8];
  const float* m0w1   = (const float*)d_in[9];
  const float* u0w0   = (const float*)d_in[10];
  const float* u0w1   = (const float*)d_in[11];
  const float* imp1   = (const float*)d_in[12];
  const float* m1w0   = (const float*)d_in[13];
  const float* m1w1   = (const float*)d_in[14];
  const float* u1w0   = (const float*)d_in[15];
  const float* u1w1   = (const float*)d_in[16];
  const float* lw0    = (const float*)d_in[17];
  const float* lw1    = (const float*)d_in[18];
  const float* rw0    = (const float*)d_in[19];
  const float* rw1    = (const float*)d_in[20];

  const int N  = in_sizes[1] / 3;
  const int E  = in_sizes[2] / 2;
  const int EI = in_sizes[4] / 2;

  float* node = (float*)d_ws;
  float* msgs = node + (size_t)N * 40;
  float* hL   = msgs + (size_t)N * 40;
  float* hR   = hL + (size_t)EI * 64;
  float* ligE = hR + (size_t)EI * 64;
  float* outp = (float*)d_out;

  const float inv_sqrt_deg = 1.0f / sqrtf((float)E / (float)N);

  const int nodeBlocks  = (N + 3) / 4;
  const int interBlocks = (EI + 3) / 4;

  emb_kernel<<<nodeBlocks, 256, 0, stream>>>(x, emb_w0, emb_w1, node, N);

  // message pass 0
  hipMemsetAsync(msgs, 0, (size_t)N * 40 * sizeof(float), stream);
  tp_kernel<0><<<512, 512, 0, stream>>>(node, pos, ei, eattr, m0w0, m0w1, nullptr, msgs, E);
  upd_kernel<<<nodeBlocks, 256, 0, stream>>>(node, msgs, u0w0, u0w1, imp0, 1.0f, inv_sqrt_deg, N);

  // message pass 1
  hipMemsetAsync(msgs, 0, (size_t)N * 40 * sizeof(float), stream);
  tp_kernel<0><<<512, 512, 0, stream>>>(node, pos, ei, eattr, m1w0, m1w1, nullptr, msgs, E);
  upd_kernel<<<nodeBlocks, 256, 0, stream>>>(node, msgs, u1w0, u1w1, imp1, 0.5f, inv_sqrt_deg, N);

  // inter edges
  inter_h_kernel<<<interBlocks, 256, 0, stream>>>(pos, iei, lw0, rw0, hL, hR, EI);
  tp_kernel<1><<<512, 512, 0, stream>>>(node, pos, iei, nullptr, nullptr, lw1, hL, ligE, EI);

  hipMemsetAsync(outp, 0, (size_t)out_size * sizeof(float), stream);
  rec_kernel<<<dim3(102, 5), 512, 0, stream>>>(node, ligE, iei, rw1, hR, outp, EI);
}

// Round 10
// 611.019 us; speedup vs baseline: 3.1324x; 1.0494x over previous
//
#include <hip/hip_runtime.h>
#include <hip/hip_fp16.h>
#include <cmath>

// ---- constants from the reference ----
constexpr float ACT_NORM = 1.6789717f;
constexpr float PW0      = 0.20412414523193154f;   // sqrt(1/24)  (== pw1/sqrt3)
constexpr float PW1      = 0.35355339059327373f;   // sqrt(3/24)
constexpr float PWREC    = 0.05590169943749474f;   // sqrt(1/320)
constexpr float INV_SQ3  = 0.57735026918962576f;
// second-layer 1/sqrt(64) folded into epilogue constants (keeps h in fp16 range)
constexpr float PW0s     = PW0 * 0.125f;
constexpr float PW1s     = PW1 * 0.125f;
constexpr float PWRECs   = PWREC * 0.125f;

__device__ __forceinline__ float silu_n(float x) {
  return x / (1.f + __expf(-x)) * ACT_NORM;
}

__device__ __forceinline__ unsigned ubcast_lane(unsigned v, int k) {
  return (unsigned)__builtin_amdgcn_readlane((int)v, k);
}

// fp16 pair pack / dot2 (v_dot2_f32_f16: 2 MACs per issue, fp32 accumulate)
typedef _Float16 h2v __attribute__((ext_vector_type(2)));
__device__ __forceinline__ unsigned packh2(float a, float b) {
  h2v p; p.x = (_Float16)a; p.y = (_Float16)b;
  return __builtin_bit_cast(unsigned, p);
}
__device__ __forceinline__ float dot2h(unsigned w2, unsigned h2, float acc) {
  return __builtin_amdgcn_fdot2(__builtin_bit_cast(h2v, w2),
                                __builtin_bit_cast(h2v, h2), acc, false);
}

// ---------------- node embedding: node[:, :16] = mlp(x), geo = 0 ----------------
__global__ __launch_bounds__(256)
void emb_kernel(const float* __restrict__ x, const float* __restrict__ w0,
                const float* __restrict__ w1, float* __restrict__ node, int N) {
  const int lane = threadIdx.x & 63;
  const int lw   = threadIdx.x >> 6;
  const int gw   = blockIdx.x * 4 + lw;
  __shared__ float sH[4][64];
  const bool valid = gw < N;
  const int n = valid ? gw : 0;
  float acc = 0.f;
#pragma unroll
  for (int a = 0; a < 10; ++a) acc = fmaf(x[n * 10 + a], w0[a * 64 + lane], acc);
  acc *= 0.31622776601683794f;   // 1/sqrt(10)
  sH[lw][lane] = silu_n(acc);
  __syncthreads();
  if (valid) {
    if (lane < 16) {
      float o = 0.f;
#pragma unroll
      for (int k = 0; k < 64; ++k) o = fmaf(sH[lw][k], w1[k * 16 + lane], o);
      node[(size_t)n * 40 + lane] = o * 0.125f;  // 1/sqrt(64)
    } else if (lane < 40) {
      node[(size_t)n * 40 + lane] = 0.f;
    }
  }
}

// ---------------- node update (per mp step) ----------------
__global__ __launch_bounds__(256)
void upd_kernel(float* __restrict__ node, const float* __restrict__ msgs,
                const float* __restrict__ w0, const float* __restrict__ w1,
                const float* __restrict__ imp, float geo_scale, float inv_sqrt_deg, int N) {
  const int lane = threadIdx.x & 63;
  const int lw   = threadIdx.x >> 6;
  const int gw   = blockIdx.x * 4 + lw;
  __shared__ float sIn[4][32];
  __shared__ float sH[4][64];
  const bool valid = gw < N;
  const int n = valid ? gw : 0;
  const float mscale = imp[0] * inv_sqrt_deg;
  if (lane < 16)      sIn[lw][lane] = msgs[(size_t)n * 40 + lane] * mscale;
  else if (lane < 32) sIn[lw][lane] = node[(size_t)n * 40 + lane - 16];
  __syncthreads();
  float acc = 0.f;
#pragma unroll
  for (int a = 0; a < 32; ++a) acc = fmaf(sIn[lw][a], w0[a * 64 + lane], acc);
  acc *= 0.17677669529663687f;   // 1/sqrt(32)
  sH[lw][lane] = silu_n(acc);
  __syncthreads();
  if (valid) {
    if (lane < 16) {
      float o = 0.f;
#pragma unroll
      for (int k = 0; k < 64; ++k) o = fmaf(sH[lw][k], w1[k * 16 + lane], o);
      node[(size_t)n * 40 + lane] = o * 0.125f;
    } else if (lane < 40) {
      const size_t gi = (size_t)n * 40 + lane;
      node[gi] = fmaf(msgs[gi], mscale, node[gi]) * geo_scale;
    }
  }
}

// ---------------- inter-edge: distance embedding -> both hidden vectors ----------------
__global__ __launch_bounds__(256)
void inter_h_kernel(const float* __restrict__ pos, const int* __restrict__ iei,
                    const float* __restrict__ lw0, const float* __restrict__ rw0,
                    float* __restrict__ hL, float* __restrict__ hR, int EI) {
  const int lane = threadIdx.x & 63;
  const int lw   = threadIdx.x >> 6;
  const int gw   = blockIdx.x * 4 + lw;
  __shared__ float sD[4][20];
  const bool valid = gw < EI;
  const int e = valid ? gw : 0;
  const int rec = iei[e], lig = iei[EI + e];
  const float dx = pos[lig * 3]     - pos[rec * 3];
  const float dy = pos[lig * 3 + 1] - pos[rec * 3 + 1];
  const float dz = pos[lig * 3 + 2] - pos[rec * 3 + 2];
  const float d = sqrtf(dx * dx + dy * dy + dz * dz);
  if (lane < 20) {
    const float diff = d * 4.2f - (float)(lane + 1);
    const float t1 = diff + 1.f, t2 = 1.f - diff;
    float v = 0.f;
    if (t1 > 0.f && t2 > 0.f) {
      const float C = 1.14136f * 7.3890560989306495f * 4.4721359549995794f; // 1.14136*e^2*sqrt(20)
      v = C * __expf(-1.f / t1 - 1.f / t2);
    }
    sD[lw][lane] = v;
  }
  __syncthreads();
  float a0 = 0.f, a1 = 0.f;
#pragma unroll
  for (int b = 0; b < 20; ++b) {
    const float db = sD[lw][b];
    a0 = fmaf(db, lw0[b * 64 + lane], a0);
    a1 = fmaf(db, rw0[b * 64 + lane], a1);
  }
  a0 *= 0.22360679774997896f;  // 1/sqrt(20)
  a1 *= 0.22360679774997896f;
  if (valid) {
    hL[(size_t)e * 64 + lane] = silu_n(a0);
    hR[(size_t)e * 64 + lane] = silu_n(a1);
  }
}

// ---------------- fused edge MLP (layer2) + node x sh tensor product ----------------
// ALL 9 weight cols in LDS as fp16 k-pairs: sWa (cols 0-3) + sWb (cols 4-7) uint4,
// sWc (col 8) uint. Inner loop: pure dot2, zero VMEM, 2-stage register prefetch of
// the next kp's vectors (hides ~120cy LDS latency behind 54 dot2s). sF shrunk to
// 27 floats (xs+dotp+r) — xv read from L2-resident `node` in the epilogue.
// LDS 78912 B -> 2 blocks/CU. S=6 edges/wave, launch_bounds(512,2) (no VGPR squeeze).
template <int MODE>
__global__ __launch_bounds__(512, 2)
void tp_kernel(const float* __restrict__ node, const float* __restrict__ pos,
               const int* __restrict__ ei, const float* __restrict__ eattr,
               const float* __restrict__ w0, const float* __restrict__ W1,
               const float* __restrict__ hSrc, float* __restrict__ out, int E) {
  __shared__ __align__(16) uint4 sWa[32 * 64];      // 32768 B: cols t=0..3, k-paired
  __shared__ __align__(16) uint4 sWb[32 * 64];      // 32768 B: cols t=4..7
  __shared__ unsigned sWc[32 * 64];                 //  8192 B: col  t=8
  __shared__ float sF[8][6][27];                    //  5184 B -> 78912 B total
  const int tid  = threadIdx.x;
  const int lane = tid & 63;
  const int wv   = tid >> 6;

  // stage packed weights once per block: dword = (W[2kp][m], W[2kp+1][m]) fp16
  for (int j = tid; j < 2048; j += 512) {
    const int kp = j >> 6, l = j & 63;
    const float* s0 = &W1[(2 * kp) * 576 + l];
    const float* s1 = s0 + 576;
    uint4 qa, qb;
    qa.x = packh2(s0[0],   s1[0]);
    qa.y = packh2(s0[64],  s1[64]);
    qa.z = packh2(s0[128], s1[128]);
    qa.w = packh2(s0[192], s1[192]);
    qb.x = packh2(s0[256], s1[256]);
    qb.y = packh2(s0[320], s1[320]);
    qb.z = packh2(s0[384], s1[384]);
    qb.w = packh2(s0[448], s1[448]);
    sWa[j] = qa;
    sWb[j] = qb;
    sWc[j] = packh2(s0[512], s1[512]);
  }
  __syncthreads();

  float w0r[5];
  if (MODE == 0) {
#pragma unroll
    for (int a = 0; a < 5; ++a) w0r[a] = w0[a * 64 + lane] * 0.4472135954999579f; // 1/sqrt(5)
  }
  const int kl2 = (lane & 31) * 2;

  const int nB = (E + 47) / 48;
  for (int b = blockIdx.x; b < nB; b += (int)gridDim.x) {
    const int ebase = b * 48 + wv * 6;
    int outn[6], nsrc[6];
    bool val[6];
    unsigned hp[6];
#pragma unroll
    for (int s = 0; s < 6; ++s) {
      const int e0 = ebase + s;
      val[s] = e0 < E;
      const int e = val[s] ? e0 : 0;
      const int ia = ei[e], ib = ei[E + e];
      if (MODE == 0) { nsrc[s] = ia; outn[s] = ib; }   // src features, scatter to dst
      else           { nsrc[s] = ib; outn[s] = e;  }   // lig features, store per edge
      const float vx = pos[ib * 3]     - pos[ia * 3];
      const float vy = pos[ib * 3 + 1] - pos[ia * 3 + 1];
      const float vz = pos[ib * 3 + 2] - pos[ia * 3 + 2];
      const float rn = rsqrtf(vx * vx + vy * vy + vz * vz);
      const float rx = vx * rn, ry = vy * rn, rz = vz * rn;
      float h;
      if (MODE == 0) {
        float acc = 0.f;
#pragma unroll
        for (int a = 0; a < 5; ++a) acc = fmaf(eattr[(size_t)e * 5 + a], w0r[a], acc);
        h = silu_n(acc);                 // unscaled; 1/8 folded into epilogue
      } else {
        h = hSrc[(size_t)e * 64 + lane];
      }
      hp[s] = packh2(__shfl(h, kl2), __shfl(h, kl2 + 1));   // fp16 k-pair
      if (lane < 16) {
        sF[wv][s][lane] = node[(size_t)nsrc[s] * 40 + lane];        // xs
      } else if (lane < 24) {
        const int u = lane - 16;
        const float x0 = node[(size_t)nsrc[s] * 40 + 16 + u * 3];
        const float x1 = node[(size_t)nsrc[s] * 40 + 16 + u * 3 + 1];
        const float x2 = node[(size_t)nsrc[s] * 40 + 16 + u * 3 + 2];
        sF[wv][s][16 + u] = x0 * rx + x1 * ry + x2 * rz;            // dot(xv, r^)
      } else if (lane < 27) {
        sF[wv][s][24 + (lane - 24)] = (lane == 24) ? rx : ((lane == 25) ? ry : rz);
      }
    }
    // no barrier: sF slices per-wave private; hp per-lane registers

    float wacc[6][9];
#pragma unroll
    for (int s = 0; s < 6; ++s)
#pragma unroll
      for (int t = 0; t < 9; ++t) wacc[s][t] = 0.f;

    // 2-stage pipelined K-loop: prefetch kp+1 while dot2-ing kp
    uint4 qa0 = sWa[lane], qb0 = sWb[lane];
    unsigned qc0 = sWc[lane];
#pragma unroll 4
    for (int kp = 0; kp < 32; ++kp) {
      const int kn = (kp + 1) & 31;
      const uint4 qa1 = sWa[kn * 64 + lane];
      const uint4 qb1 = sWb[kn * 64 + lane];
      const unsigned qc1 = sWc[kn * 64 + lane];
#pragma unroll
      for (int s = 0; s < 6; ++s) {
        const unsigned hv2 = ubcast_lane(hp[s], kp);
        wacc[s][0] = dot2h(qa0.x, hv2, wacc[s][0]);
        wacc[s][1] = dot2h(qa0.y, hv2, wacc[s][1]);
        wacc[s][2] = dot2h(qa0.z, hv2, wacc[s][2]);
        wacc[s][3] = dot2h(qa0.w, hv2, wacc[s][3]);
        wacc[s][4] = dot2h(qb0.x, hv2, wacc[s][4]);
        wacc[s][5] = dot2h(qb0.y, hv2, wacc[s][5]);
        wacc[s][6] = dot2h(qb0.z, hv2, wacc[s][6]);
        wacc[s][7] = dot2h(qb0.w, hv2, wacc[s][7]);
        wacc[s][8] = dot2h(qc0,   hv2, wacc[s][8]);
      }
      qa0 = qa1; qb0 = qb1; qc0 = qc1;
    }

    // TP epilogue. t=0..5 scalar-path (out col = lane&15, U=(lane>>4)+4t),
    // t=6..8 vector-path (out col = lane&7, U=(lane>>3)+8(t-6)). 1/8 scale folded.
    const int ub  = lane >> 4;
    const int ub2 = lane >> 3;
#pragma unroll
    for (int s = 0; s < 6; ++s) {
      float cs = 0.f;
#pragma unroll
      for (int t = 0; t < 6; ++t)
        cs = fmaf(PW0s * sF[wv][s][ub + 4 * t], wacc[s][t], cs);
      cs += __shfl_xor(cs, 16);
      cs += __shfl_xor(cs, 32);

      const float rx = sF[wv][s][24], ry = sF[wv][s][25], rz = sF[wv][s][26];
      // xv for this lane's u=ub2 straight from node (L2-resident), once per tile
      const float* xp = &node[(size_t)nsrc[s] * 40 + 16 + ub2 * 3];
      const float xv0 = xp[0], xv1 = xp[1], xv2 = xp[2];
      const float sxw = PW1s * (sF[wv][s][ub2] * wacc[s][6] + sF[wv][s][ub2 + 8] * wacc[s][7]);
      float cv0 = fmaf(PW0s * xv0, wacc[s][8], sxw * rx);
      float cv1 = fmaf(PW0s * xv1, wacc[s][8], sxw * ry);
      float cv2 = fmaf(PW0s * xv2, wacc[s][8], sxw * rz);
      cv0 += __shfl_xor(cv0, 8); cv0 += __shfl_xor(cv0, 16); cv0 += __shfl_xor(cv0, 32);
      cv1 += __shfl_xor(cv1, 8); cv1 += __shfl_xor(cv1, 16); cv1 += __shfl_xor(cv1, 32);
      cv2 += __shfl_xor(cv2, 8); cv2 += __shfl_xor(cv2, 16); cv2 += __shfl_xor(cv2, 32);

      if (val[s]) {
        const size_t ob = (size_t)outn[s] * 40;
        if (MODE == 0) {
          if (lane < 16) atomicAdd(&out[ob + lane], cs);
          if (lane < 8) {
            atomicAdd(&out[ob + 16 + lane * 3],     cv0);
            atomicAdd(&out[ob + 16 + lane * 3 + 1], cv1);
            atomicAdd(&out[ob + 16 + lane * 3 + 2], cv2);
          }
        } else {
          if (lane < 16) out[ob + lane] = cs;
          if (lane < 8) {
            out[ob + 16 + lane * 3]     = cv0;
            out[ob + 16 + lane * 3 + 1] = cv1;
            out[ob + 16 + lane * 3 + 2] = cv2;
          }
        }
      }
    }
  }
}

// ---------------- rec MLP (layer2, 64x2560) + node x node -> 8x0e TP ----------------
// Persistent 512-col chunk per block (blockIdx.y = 0..4), k-pair fp16, staged ONCE;
// inner loop all dot2 with 2-stage register prefetch. Edge loop barrier-free;
// partials atomicAdd'd. LDS 80896 B -> 2 blocks/CU. cg<4 scalar CG; cg==4 vector.
__global__ __launch_bounds__(512, 2)
void rec_kernel(const float* __restrict__ node, const float* __restrict__ ligE,
                const int* __restrict__ iei, const float* __restrict__ RW1,
                const float* __restrict__ hR, float* __restrict__ out, int EI) {
  __shared__ __align__(16) uint4 sWa[32 * 64];      // 32768 B: chunk cols t=0..3
  __shared__ __align__(16) uint4 sWb[32 * 64];      // 32768 B: cols t=4..7
  __shared__ float sF[8][6][80];                    // 15360 B -> 80896 B total
  const int tid  = threadIdx.x;
  const int lane = tid & 63;
  const int wv   = tid >> 6;
  const int cg   = blockIdx.y;                      // 0..4
  const int kl2  = (lane & 31) * 2;

  for (int j = tid; j < 2048; j += 512) {
    const int kp = j >> 6, l = j & 63;
    const float* s0 = &RW1[(size_t)(2 * kp) * 2560 + cg * 512 + l];
    const float* s1 = s0 + 2560;
    uint4 qa, qb;
    qa.x = packh2(s0[0],   s1[0]);
    qa.y = packh2(s0[64],  s1[64]);
    qa.z = packh2(s0[128], s1[128]);
    qa.w = packh2(s0[192], s1[192]);
    qb.x = packh2(s0[256], s1[256]);
    qb.y = packh2(s0[320], s1[320]);
    qb.z = packh2(s0[384], s1[384]);
    qb.w = packh2(s0[448], s1[448]);
    sWa[j] = qa;
    sWb[j] = qb;
  }
  __syncthreads();

  const int nB = (EI + 47) / 48;
  for (int b = blockIdx.x; b < nB; b += (int)gridDim.x) {
    const int ebase = b * 48 + wv * 6;
    bool val[6]; int eidx[6]; unsigned hp[6];
#pragma unroll
    for (int s = 0; s < 6; ++s) {
      const int e0 = ebase + s;
      val[s] = e0 < EI;
      const int e = val[s] ? e0 : 0;
      eidx[s] = e;
      const float hh = hR[(size_t)e * 64 + lane];   // unscaled; 1/8 in epilogue
      hp[s] = packh2(__shfl(hh, kl2), __shfl(hh, kl2 + 1));
      const int rec = iei[e];
      if (lane < 40) {
        sF[wv][s][lane]      = ligE[(size_t)e * 40 + lane];        // xs_l[0:16], xv_l[16:40]
        sF[wv][s][40 + lane] = node[(size_t)rec * 40 + lane];      // ys_r[40:56], yv_r[56:80]
      }
    }

    float wacc[6][8];
#pragma unroll
    for (int s = 0; s < 6; ++s)
#pragma unroll
      for (int t = 0; t < 8; ++t) wacc[s][t] = 0.f;

    // 2-stage pipelined K-loop: prefetch kp+1 while dot2-ing kp
    uint4 qa0 = sWa[lane], qb0 = sWb[lane];
#pragma unroll 4
    for (int kp = 0; kp < 32; ++kp) {
      const int kn = (kp + 1) & 31;
      const uint4 qa1 = sWa[kn * 64 + lane];
      const uint4 qb1 = sWb[kn * 64 + lane];
#pragma unroll
      for (int s = 0; s < 6; ++s) {
        const unsigned hv2 = ubcast_lane(hp[s], kp);
        wacc[s][0] = dot2h(qa0.x, hv2, wacc[s][0]);
        wacc[s][1] = dot2h(qa0.y, hv2, wacc[s][1]);
        wacc[s][2] = dot2h(qa0.z, hv2, wacc[s][2]);
        wacc[s][3] = dot2h(qa0.w, hv2, wacc[s][3]);
        wacc[s][4] = dot2h(qb0.x, hv2, wacc[s][4]);
        wacc[s][5] = dot2h(qb0.y, hv2, wacc[s][5]);
        wacc[s][6] = dot2h(qb0.z, hv2, wacc[s][6]);
        wacc[s][7] = dot2h(qb0.w, hv2, wacc[s][7]);
      }
      qa0 = qa1; qb0 = qb1;
    }

    // epilogue: m = cg*512 + t*64 + lane ; col = lane&7 ; uv = cg*64 + t*8 + (lane>>3)
    const int l3 = lane >> 3;
    if (cg < 4) {                 // scalar path: uv < 256
#pragma unroll
      for (int s = 0; s < 6; ++s) {
        float o = 0.f;
#pragma unroll
        for (int t = 0; t < 8; ++t) {
          const int uv = cg * 64 + t * 8 + l3;
          const int u = uv >> 4, v = uv & 15;
          o = fmaf(sF[wv][s][u] * sF[wv][s][40 + v], wacc[s][t], o);
        }
        o += __shfl_xor(o, 8); o += __shfl_xor(o, 16); o += __shfl_xor(o, 32);
        if (val[s] && lane < 8) atomicAdd(&out[(size_t)eidx[s] * 8 + lane], o * PWRECs);
      }
    } else {                      // vector path: u = t, v = l3
#pragma unroll
      for (int s = 0; s < 6; ++s) {
        float o = 0.f;
#pragma unroll
        for (int t = 0; t < 8; ++t) {
          const float dp = sF[wv][s][16 + t * 3]     * sF[wv][s][56 + l3 * 3]
                         + sF[wv][s][16 + t * 3 + 1] * sF[wv][s][56 + l3 * 3 + 1]
                         + sF[wv][s][16 + t * 3 + 2] * sF[wv][s][56 + l3 * 3 + 2];
          o = fmaf(dp * INV_SQ3, wacc[s][t], o);
        }
        o += __shfl_xor(o, 8); o += __shfl_xor(o, 16); o += __shfl_xor(o, 32);
        if (val[s] && lane < 8) atomicAdd(&out[(size_t)eidx[s] * 8 + lane], o * PWRECs);
      }
    }
  }
}

extern "C" void kernel_launch(void* const* d_in, const int* in_sizes, int n_in,
                              void* d_out, int out_size, void* d_ws, size_t ws_size,
                              hipStream_t stream) {
  (void)n_in; (void)ws_size;
  const float* x      = (const float*)d_in[0];
  const float* pos    = (const float*)d_in[1];
  const int*   ei     = (const int*)  d_in[2];
  const float* eattr  = (const float*)d_in[3];
  const int*   iei    = (const int*)  d_in[4];
  const float* emb_w0 = (const float*)d_in[5];
  const float* emb_w1 = (const float*)d_in[6];
  const float* imp0   = (const float*)d_in[7];
  const float* m0w0   = (const float*)d_in[8];
  const float* m0w1   = (const float*)d_in[9];
  const float* u0w0   = (const float*)d_in[10];
  const float* u0w1   = (const float*)d_in[11];
  const float* imp1   = (const float*)d_in[12];
  const float* m1w0   = (const float*)d_in[13];
  const float* m1w1   = (const float*)d_in[14];
  const float* u1w0   = (const float*)d_in[15];
  const float* u1w1   = (const float*)d_in[16];
  const float* lw0    = (const float*)d_in[17];
  const float* lw1    = (const float*)d_in[18];
  const float* rw0    = (const float*)d_in[19];
  const float* rw1    = (const float*)d_in[20];

  const int N  = in_sizes[1] / 3;
  const int E  = in_sizes[2] / 2;
  const int EI = in_sizes[4] / 2;

  float* node = (float*)d_ws;
  float* msgs = node + (size_t)N * 40;
  float* hL   = msgs + (size_t)N * 40;
  float* hR   = hL + (size_t)EI * 64;
  float* ligE = hR + (size_t)EI * 64;
  float* outp = (float*)d_out;

  const float inv_sqrt_deg = 1.0f / sqrtf((float)E / (float)N);

  const int nodeBlocks  = (N + 3) / 4;
  const int interBlocks = (EI + 3) / 4;

  emb_kernel<<<nodeBlocks, 256, 0, stream>>>(x, emb_w0, emb_w1, node, N);

  // message pass 0
  hipMemsetAsync(msgs, 0, (size_t)N * 40 * sizeof(float), stream);
  tp_kernel<0><<<512, 512, 0, stream>>>(node, pos, ei, eattr, m0w0, m0w1, nullptr, msgs, E);
  upd_kernel<<<nodeBlocks, 256, 0, stream>>>(node, msgs, u0w0, u0w1, imp0, 1.0f, inv_sqrt_deg, N);

  // message pass 1
  hipMemsetAsync(msgs, 0, (size_t)N * 40 * sizeof(float), stream);
  tp_kernel<0><<<512, 512, 0, stream>>>(node, pos, ei, eattr, m1w0, m1w1, nullptr, msgs, E);
  upd_kernel<<<nodeBlocks, 256, 0, stream>>>(node, msgs, u1w0, u1w1, imp1, 0.5f, inv_sqrt_deg, N);

  // inter edges
  inter_h_kernel<<<interBlocks, 256, 0, stream>>>(pos, iei, lw0, rw0, hL, hR, EI);
  tp_kernel<1><<<512, 512, 0, stream>>>(node, pos, iei, nullptr, nullptr, lw1, hL, ligE, EI);

  hipMemsetAsync(outp, 0, (size_t)out_size * sizeof(float), stream);
  rec_kernel<<<dim3(102, 5), 512, 0, stream>>>(node, ligE, iei, rw1, hR, outp, EI);
}

// Round 12
// 492.251 us; speedup vs baseline: 3.8881x; 1.2413x over previous
//
#include <hip/hip_runtime.h>
#include <hip/hip_fp16.h>
#include <cmath>

// ---- constants from the reference ----
constexpr float ACT_NORM = 1.6789717f;
constexpr float PW0      = 0.20412414523193154f;   // sqrt(1/24)  (== pw1/sqrt3)
constexpr float PW1      = 0.35355339059327373f;   // sqrt(3/24)
constexpr float PWREC    = 0.05590169943749474f;   // sqrt(1/320)
constexpr float INV_SQ3  = 0.57735026918962576f;
// second-layer 1/sqrt(64) folded into epilogue constants
constexpr float PW0s     = PW0 * 0.125f;
constexpr float PW1s     = PW1 * 0.125f;
constexpr float PWRECs   = PWREC * 0.125f;

__device__ __forceinline__ float silu_n(float x) {
  return x / (1.f + __expf(-x)) * ACT_NORM;
}

__device__ __forceinline__ unsigned ubcast_lane(unsigned v, int k) {
  return (unsigned)__builtin_amdgcn_readlane((int)v, k);
}

// fp16 helpers
typedef _Float16 h2v __attribute__((ext_vector_type(2)));
typedef _Float16 f16x8 __attribute__((ext_vector_type(8)));
typedef float    f32x4 __attribute__((ext_vector_type(4)));

__device__ __forceinline__ unsigned packh2(float a, float b) {
  h2v p; p.x = (_Float16)a; p.y = (_Float16)b;
  return __builtin_bit_cast(unsigned, p);
}
__device__ __forceinline__ unsigned short f16bits(float a) {
  return __builtin_bit_cast(unsigned short, (_Float16)a);
}
__device__ __forceinline__ float dot2h(unsigned w2, unsigned h2, float acc) {
  return __builtin_amdgcn_fdot2(__builtin_bit_cast(h2v, w2),
                                __builtin_bit_cast(h2v, h2), acc, false);
}
__device__ __forceinline__ float hlo(unsigned d) {
  return (float)__builtin_bit_cast(_Float16, (unsigned short)(d & 0xffffu));
}
__device__ __forceinline__ float hhi(unsigned d) {
  return (float)__builtin_bit_cast(_Float16, (unsigned short)(d >> 16));
}
__device__ __forceinline__ float hsel(unsigned d, int hi) { return hi ? hhi(d) : hlo(d); }
__device__ __forceinline__ unsigned u4sel(const uint4& v, int i) {
  return i == 0 ? v.x : (i == 1 ? v.y : (i == 2 ? v.z : v.w));
}
__device__ __forceinline__ unsigned u2sel(const uint2& v, int i) { return i ? v.y : v.x; }

// mfma_f32_16x16x32_f16: A row = lane&15; B col = lane&15 (k mapping consistent A/B,
// result invariant to the exact k grouping); C/D: col=lane&15, row=(lane>>4)*4+reg
// [HW-verified C/D layout, m89 family].
__device__ __forceinline__ f32x4 mfma16(uint4 a, uint4 b, f32x4 c) {
  return __builtin_amdgcn_mfma_f32_16x16x32_f16(
      __builtin_bit_cast(f16x8, a), __builtin_bit_cast(f16x8, b), c, 0, 0, 0);
}

// ---------------- node embedding: node[:, :16] = mlp(x), geo = 0 ----------------
__global__ __launch_bounds__(256)
void emb_kernel(const float* __restrict__ x, const float* __restrict__ w0,
                const float* __restrict__ w1, float* __restrict__ node, int N) {
  const int lane = threadIdx.x & 63;
  const int lw   = threadIdx.x >> 6;
  const int gw   = blockIdx.x * 4 + lw;
  __shared__ float sH[4][64];
  const bool valid = gw < N;
  const int n = valid ? gw : 0;
  float acc = 0.f;
#pragma unroll
  for (int a = 0; a < 10; ++a) acc = fmaf(x[n * 10 + a], w0[a * 64 + lane], acc);
  acc *= 0.31622776601683794f;   // 1/sqrt(10)
  sH[lw][lane] = silu_n(acc);
  __syncthreads();
  if (valid) {
    if (lane < 16) {
      float o = 0.f;
#pragma unroll
      for (int k = 0; k < 64; ++k) o = fmaf(sH[lw][k], w1[k * 16 + lane], o);
      node[(size_t)n * 40 + lane] = o * 0.125f;  // 1/sqrt(64)
    } else if (lane < 40) {
      node[(size_t)n * 40 + lane] = 0.f;
    }
  }
}

// ---------------- node update (per mp step) ----------------
__global__ __launch_bounds__(256)
void upd_kernel(float* __restrict__ node, const float* __restrict__ msgs,
                const float* __restrict__ w0, const float* __restrict__ w1,
                const float* __restrict__ imp, float geo_scale, float inv_sqrt_deg, int N) {
  const int lane = threadIdx.x & 63;
  const int lw   = threadIdx.x >> 6;
  const int gw   = blockIdx.x * 4 + lw;
  __shared__ float sIn[4][32];
  __shared__ float sH[4][64];
  const bool valid = gw < N;
  const int n = valid ? gw : 0;
  const float mscale = imp[0] * inv_sqrt_deg;
  if (lane < 16)      sIn[lw][lane] = msgs[(size_t)n * 40 + lane] * mscale;
  else if (lane < 32) sIn[lw][lane] = node[(size_t)n * 40 + lane - 16];
  __syncthreads();
  float acc = 0.f;
#pragma unroll
  for (int a = 0; a < 32; ++a) acc = fmaf(sIn[lw][a], w0[a * 64 + lane], acc);
  acc *= 0.17677669529663687f;   // 1/sqrt(32)
  sH[lw][lane] = silu_n(acc);
  __syncthreads();
  if (valid) {
    if (lane < 16) {
      float o = 0.f;
#pragma unroll
      for (int k = 0; k < 64; ++k) o = fmaf(sH[lw][k], w1[k * 16 + lane], o);
      node[(size_t)n * 40 + lane] = o * 0.125f;
    } else if (lane < 40) {
      const size_t gi = (size_t)n * 40 + lane;
      node[gi] = fmaf(msgs[gi], mscale, node[gi]) * geo_scale;
    }
  }
}

// ---------------- inter-edge: distance embedding -> both hidden vectors ----------------
__global__ __launch_bounds__(256)
void inter_h_kernel(const float* __restrict__ pos, const int* __restrict__ iei,
                    const float* __restrict__ lw0, const float* __restrict__ rw0,
                    float* __restrict__ hL, float* __restrict__ hR, int EI) {
  const int lane = threadIdx.x & 63;
  const int lw   = threadIdx.x >> 6;
  const int gw   = blockIdx.x * 4 + lw;
  __shared__ float sD[4][20];
  const bool valid = gw < EI;
  const int e = valid ? gw : 0;
  const int rec = iei[e], lig = iei[EI + e];
  const float dx = pos[lig * 3]     - pos[rec * 3];
  const float dy = pos[lig * 3 + 1] - pos[rec * 3 + 1];
  const float dz = pos[lig * 3 + 2] - pos[rec * 3 + 2];
  const float d = sqrtf(dx * dx + dy * dy + dz * dz);
  if (lane < 20) {
    const float diff = d * 4.2f - (float)(lane + 1);
    const float t1 = diff + 1.f, t2 = 1.f - diff;
    float v = 0.f;
    if (t1 > 0.f && t2 > 0.f) {
      const float C = 1.14136f * 7.3890560989306495f * 4.4721359549995794f; // 1.14136*e^2*sqrt(20)
      v = C * __expf(-1.f / t1 - 1.f / t2);
    }
    sD[lw][lane] = v;
  }
  __syncthreads();
  float a0 = 0.f, a1 = 0.f;
#pragma unroll
  for (int b = 0; b < 20; ++b) {
    const float db = sD[lw][b];
    a0 = fmaf(db, lw0[b * 64 + lane], a0);
    a1 = fmaf(db, rw0[b * 64 + lane], a1);
  }
  a0 *= 0.22360679774997896f;  // 1/sqrt(20)
  a1 *= 0.22360679774997896f;
  if (valid) {
    hL[(size_t)e * 64 + lane] = silu_n(a0);
    hR[(size_t)e * 64 + lane] = silu_n(a1);
  }
}

// ---------------- fused edge MLP (layer2) + node x sh tensor product ----------------
// (unchanged round-10 dot2 kernel — proven)
template <int MODE>
__global__ __launch_bounds__(512, 2)
void tp_kernel(const float* __restrict__ node, const float* __restrict__ pos,
               const int* __restrict__ ei, const float* __restrict__ eattr,
               const float* __restrict__ w0, const float* __restrict__ W1,
               const float* __restrict__ hSrc, float* __restrict__ out, int E) {
  __shared__ __align__(16) uint4 sWa[32 * 64];      // 32768 B: cols t=0..3, k-paired
  __shared__ __align__(16) uint4 sWb[32 * 64];      // 32768 B: cols t=4..7
  __shared__ unsigned sWc[32 * 64];                 //  8192 B: col  t=8
  __shared__ float sF[8][6][27];                    //  5184 B -> 78912 B total
  const int tid  = threadIdx.x;
  const int lane = tid & 63;
  const int wv   = tid >> 6;

  for (int j = tid; j < 2048; j += 512) {
    const int kp = j >> 6, l = j & 63;
    const float* s0 = &W1[(2 * kp) * 576 + l];
    const float* s1 = s0 + 576;
    uint4 qa, qb;
    qa.x = packh2(s0[0],   s1[0]);
    qa.y = packh2(s0[64],  s1[64]);
    qa.z = packh2(s0[128], s1[128]);
    qa.w = packh2(s0[192], s1[192]);
    qb.x = packh2(s0[256], s1[256]);
    qb.y = packh2(s0[320], s1[320]);
    qb.z = packh2(s0[384], s1[384]);
    qb.w = packh2(s0[448], s1[448]);
    sWa[j] = qa;
    sWb[j] = qb;
    sWc[j] = packh2(s0[512], s1[512]);
  }
  __syncthreads();

  float w0r[5];
  if (MODE == 0) {
#pragma unroll
    for (int a = 0; a < 5; ++a) w0r[a] = w0[a * 64 + lane] * 0.4472135954999579f; // 1/sqrt(5)
  }
  const int kl2 = (lane & 31) * 2;

  const int nB = (E + 47) / 48;
  for (int b = blockIdx.x; b < nB; b += (int)gridDim.x) {
    const int ebase = b * 48 + wv * 6;
    int outn[6], nsrc[6];
    bool val[6];
    unsigned hp[6];
#pragma unroll
    for (int s = 0; s < 6; ++s) {
      const int e0 = ebase + s;
      val[s] = e0 < E;
      const int e = val[s] ? e0 : 0;
      const int ia = ei[e], ib = ei[E + e];
      if (MODE == 0) { nsrc[s] = ia; outn[s] = ib; }
      else           { nsrc[s] = ib; outn[s] = e;  }
      const float vx = pos[ib * 3]     - pos[ia * 3];
      const float vy = pos[ib * 3 + 1] - pos[ia * 3 + 1];
      const float vz = pos[ib * 3 + 2] - pos[ia * 3 + 2];
      const float rn = rsqrtf(vx * vx + vy * vy + vz * vz);
      const float rx = vx * rn, ry = vy * rn, rz = vz * rn;
      float h;
      if (MODE == 0) {
        float acc = 0.f;
#pragma unroll
        for (int a = 0; a < 5; ++a) acc = fmaf(eattr[(size_t)e * 5 + a], w0r[a], acc);
        h = silu_n(acc);
      } else {
        h = hSrc[(size_t)e * 64 + lane];
      }
      hp[s] = packh2(__shfl(h, kl2), __shfl(h, kl2 + 1));
      if (lane < 16) {
        sF[wv][s][lane] = node[(size_t)nsrc[s] * 40 + lane];
      } else if (lane < 24) {
        const int u = lane - 16;
        const float x0 = node[(size_t)nsrc[s] * 40 + 16 + u * 3];
        const float x1 = node[(size_t)nsrc[s] * 40 + 16 + u * 3 + 1];
        const float x2 = node[(size_t)nsrc[s] * 40 + 16 + u * 3 + 2];
        sF[wv][s][16 + u] = x0 * rx + x1 * ry + x2 * rz;
      } else if (lane < 27) {
        sF[wv][s][24 + (lane - 24)] = (lane == 24) ? rx : ((lane == 25) ? ry : rz);
      }
    }

    float wacc[6][9];
#pragma unroll
    for (int s = 0; s < 6; ++s)
#pragma unroll
      for (int t = 0; t < 9; ++t) wacc[s][t] = 0.f;

    uint4 qa0 = sWa[lane], qb0 = sWb[lane];
    unsigned qc0 = sWc[lane];
#pragma unroll 4
    for (int kp = 0; kp < 32; ++kp) {
      const int kn = (kp + 1) & 31;
      const uint4 qa1 = sWa[kn * 64 + lane];
      const uint4 qb1 = sWb[kn * 64 + lane];
      const unsigned qc1 = sWc[kn * 64 + lane];
#pragma unroll
      for (int s = 0; s < 6; ++s) {
        const unsigned hv2 = ubcast_lane(hp[s], kp);
        wacc[s][0] = dot2h(qa0.x, hv2, wacc[s][0]);
        wacc[s][1] = dot2h(qa0.y, hv2, wacc[s][1]);
        wacc[s][2] = dot2h(qa0.z, hv2, wacc[s][2]);
        wacc[s][3] = dot2h(qa0.w, hv2, wacc[s][3]);
        wacc[s][4] = dot2h(qb0.x, hv2, wacc[s][4]);
        wacc[s][5] = dot2h(qb0.y, hv2, wacc[s][5]);
        wacc[s][6] = dot2h(qb0.z, hv2, wacc[s][6]);
        wacc[s][7] = dot2h(qb0.w, hv2, wacc[s][7]);
        wacc[s][8] = dot2h(qc0,   hv2, wacc[s][8]);
      }
      qa0 = qa1; qb0 = qb1; qc0 = qc1;
    }

    const int ub  = lane >> 4;
    const int ub2 = lane >> 3;
#pragma unroll
    for (int s = 0; s < 6; ++s) {
      float cs = 0.f;
#pragma unroll
      for (int t = 0; t < 6; ++t)
        cs = fmaf(PW0s * sF[wv][s][ub + 4 * t], wacc[s][t], cs);
      cs += __shfl_xor(cs, 16);
      cs += __shfl_xor(cs, 32);

      const float rx = sF[wv][s][24], ry = sF[wv][s][25], rz = sF[wv][s][26];
      const float* xp = &node[(size_t)nsrc[s] * 40 + 16 + ub2 * 3];
      const float xv0 = xp[0], xv1 = xp[1], xv2 = xp[2];
      const float sxw = PW1s * (sF[wv][s][ub2] * wacc[s][6] + sF[wv][s][ub2 + 8] * wacc[s][7]);
      float cv0 = fmaf(PW0s * xv0, wacc[s][8], sxw * rx);
      float cv1 = fmaf(PW0s * xv1, wacc[s][8], sxw * ry);
      float cv2 = fmaf(PW0s * xv2, wacc[s][8], sxw * rz);
      cv0 += __shfl_xor(cv0, 8); cv0 += __shfl_xor(cv0, 16); cv0 += __shfl_xor(cv0, 32);
      cv1 += __shfl_xor(cv1, 8); cv1 += __shfl_xor(cv1, 16); cv1 += __shfl_xor(cv1, 32);
      cv2 += __shfl_xor(cv2, 8); cv2 += __shfl_xor(cv2, 16); cv2 += __shfl_xor(cv2, 32);

      if (val[s]) {
        const size_t ob = (size_t)outn[s] * 40;
        if (MODE == 0) {
          if (lane < 16) atomicAdd(&out[ob + lane], cs);
          if (lane < 8) {
            atomicAdd(&out[ob + 16 + lane * 3],     cv0);
            atomicAdd(&out[ob + 16 + lane * 3 + 1], cv1);
            atomicAdd(&out[ob + 16 + lane * 3 + 2], cv2);
          }
        } else {
          if (lane < 16) out[ob + lane] = cs;
          if (lane < 8) {
            out[ob + 16 + lane * 3]     = cv0;
            out[ob + 16 + lane * 3 + 1] = cv1;
            out[ob + 16 + lane * 3 + 2] = cv2;
          }
        }
      }
    }
  }
}

// ---------------- pack hR into MFMA A-fragments (fp16) ----------------
// hPf[(T*2+H)*64 + lane] = uint4 of 8 fp16 = h[16T + (lane&15)][H*32 + (lane>>4)*8 + 0..7]
__global__ __launch_bounds__(512)
void pack_h_kernel(const float* __restrict__ h, uint4* __restrict__ hPf, int nT) {
  const int gid = blockIdx.x * 512 + threadIdx.x;
  if (gid >= nT * 128) return;
  const int l = gid & 63;
  const int H = (gid >> 6) & 1;
  const int T = gid >> 7;
  const int e = T * 16 + (l & 15);
  const int kb = H * 32 + (l >> 4) * 8;
  const float* src = &h[(size_t)e * 64 + kb];
  uint4 q;
  q.x = packh2(src[0], src[1]);
  q.y = packh2(src[2], src[3]);
  q.z = packh2(src[4], src[5]);
  q.w = packh2(src[6], src[7]);
  hPf[gid] = q;
}

// ---------------- precompute vector-path dot table (fp16, parity-separated) --------
// Dt[e*64 + b*32 + u*4 + vi] = dot(xv_lig[e,u], yv_rec[e, 2*vi+b]) * INV_SQ3
// (layout matches rec_kernel's per-lane uint2 reads directly — no LDS staging needed)
__global__ __launch_bounds__(256)
void pack_d_kernel(const float* __restrict__ ligE, const float* __restrict__ node,
                   const int* __restrict__ iei, unsigned short* __restrict__ Dt, int EI) {
  const int gid = blockIdx.x * 256 + threadIdx.x;
  if (gid >= EI * 64) return;
  const int e = gid >> 6, rem = gid & 63;
  const int b = rem >> 5, u = (rem >> 2) & 7, vi = rem & 3;
  const int v = 2 * vi + b;
  const int rec = iei[e];
  const float* xp = &ligE[(size_t)e * 40 + 16 + u * 3];
  const float* yp = &node[(size_t)rec * 40 + 16 + v * 3];
  const float d = (xp[0] * yp[0] + xp[1] * yp[1] + xp[2] * yp[2]) * INV_SQ3;
  Dt[gid] = f16bits(d);
}

// ---------------- rec: MFMA GEMM (h @ RW1 chunk) + fused TP epilogue ----------------
// blockIdx.y = cg (0..4): persistent 512-col fp16 B-fragments in LDS (staged once).
// Per wave-tile: 16 edges, 32 ntiles x {2 ds_b128 + 2 MFMA + static-index epilogue}.
// cg<4 (scalar CG): xs/ys fp16 staged in a 320-ushort per-wave LDS slice (in-bounds).
// cg==4 (vector CG): D values read directly from the L2-resident parity-separated
// global table (fixes round-11's 1024-halfword overflow of the 512-slot slice).
__global__ __launch_bounds__(512, 2)
void rec_kernel(const float* __restrict__ node, const float* __restrict__ ligE,
                const int* __restrict__ iei, const float* __restrict__ RW1,
                const uint4* __restrict__ hPf, const uint2* __restrict__ Dt2,
                float* __restrict__ out, int nT) {
  __shared__ __align__(16) uint4 sB[4096];               // 65536 B: B-fragments
  __shared__ __align__(16) unsigned short sFeat[8][320]; //  5120 B -> 70656 total
  const int tid = threadIdx.x, lane = tid & 63, wv = tid >> 6;
  const int cg = blockIdx.y;

  // stage B fragments: sB[t*128 + H*64 + l] = 8 fp16 of RW1[kb..kb+7][cg*512+t*16+(l&15)]
  for (int j = tid; j < 4096; j += 512) {
    const int t = j >> 7, H = (j >> 6) & 1, l = j & 63;
    const int kb = H * 32 + (l >> 4) * 8;
    const float* src = &RW1[(size_t)kb * 2560 + cg * 512 + t * 16 + (l & 15)];
    uint4 q;
    q.x = packh2(src[0],        src[2560]);
    q.y = packh2(src[2 * 2560], src[3 * 2560]);
    q.z = packh2(src[4 * 2560], src[5 * 2560]);
    q.w = packh2(src[6 * 2560], src[7 * 2560]);
    sB[j] = q;
  }
  __syncthreads();

  unsigned short* fW = sFeat[wv];
  // scalar: ys at fW[0..255] ([e][b][vi]: (e*2+b)*8+vi), xs at fW[256..319] ([e][u']: e*4+u')
  const int er0 = (lane >> 4) * 4;
  const int bpar = (lane >> 3) & 1;
  const int c    = lane & 7;
  const int se = lane >> 2, si = lane & 3;

  for (int T = blockIdx.x * 8 + wv; T < nT; T += (int)gridDim.x * 8) {
    const uint4 a0 = hPf[(T * 2 + 0) * 64 + lane];
    const uint4 a1 = hPf[(T * 2 + 1) * 64 + lane];
    const int eg = T * 16 + se;

    // stage features into per-wave LDS slice (same-wave RAW; scalar path only)
    if (cg < 4) {
      const int rn = iei[eg];
      const float4 yv = *(const float4*)&node[(size_t)rn * 40 + si * 4];
      *(unsigned*)&fW[(se * 2 + 0) * 8 + 2 * si] = packh2(yv.x, yv.z); // v even
      *(unsigned*)&fW[(se * 2 + 1) * 8 + 2 * si] = packh2(yv.y, yv.w); // v odd
      fW[256 + se * 4 + si] = f16bits(ligE[(size_t)eg * 40 + cg * 4 + si]);
    }

    float o[4] = {0.f, 0.f, 0.f, 0.f};
    uint4 b0 = sB[lane], b1 = sB[64 + lane];

    if (cg < 4) {
      uint2 xsR[4]; uint4 ysR[4];
#pragma unroll
      for (int r = 0; r < 4; ++r) {
        const int er = er0 + r;
        ysR[r] = *(const uint4*)&fW[(er * 2 + bpar) * 8];
        xsR[r] = *(const uint2*)&fW[256 + er * 4];
      }
#pragma unroll
      for (int t = 0; t < 32; ++t) {
        uint4 n0, n1;
        if (t < 31) { n0 = sB[(t + 1) * 128 + lane]; n1 = sB[(t + 1) * 128 + 64 + lane]; }
        f32x4 C = {0.f, 0.f, 0.f, 0.f};
        C = mfma16(a0, b0, C);
        C = mfma16(a1, b1, C);
        const int up = t >> 3, vi = t & 7;
#pragma unroll
        for (int r = 0; r < 4; ++r) {
          const float xs = hsel(u2sel(xsR[r], up >> 1), up & 1);
          const float ys = hsel(u4sel(ysR[r], vi >> 1), vi & 1);
          o[r] = fmaf(xs * ys, C[r], o[r]);
        }
        if (t < 31) { b0 = n0; b1 = n1; }
      }
    } else {
#pragma unroll
      for (int pass = 0; pass < 2; ++pass) {
        // D rows for this pass, straight from global (L2-hot, 16B-coalesced-ish):
        // Dt2[e*16 + bpar*8 + u] = 4 fp16 (vi=0..3) at u; pass covers u = pass*4 + 0..3
        uint2 dR[4][4];
#pragma unroll
        for (int r = 0; r < 4; ++r) {
          const int e = T * 16 + er0 + r;
#pragma unroll
          for (int uu = 0; uu < 4; ++uu)
            dR[r][uu] = Dt2[(size_t)e * 16 + bpar * 8 + pass * 4 + uu];
        }
#pragma unroll
        for (int tt = 0; tt < 16; ++tt) {
          const int t = pass * 16 + tt;
          uint4 n0, n1;
          if (t < 31) { n0 = sB[(t + 1) * 128 + lane]; n1 = sB[(t + 1) * 128 + 64 + lane]; }
          f32x4 C = {0.f, 0.f, 0.f, 0.f};
          C = mfma16(a0, b0, C);
          C = mfma16(a1, b1, C);
          const int uu = tt >> 2, vi = tt & 3;
#pragma unroll
          for (int r = 0; r < 4; ++r) {
            const float f = hsel(u2sel(dR[r][uu], vi >> 1), vi & 1);
            o[r] = fmaf(f, C[r], o[r]);
          }
          if (t < 31) { b0 = n0; b1 = n1; }
        }
      }
    }

#pragma unroll
    for (int r = 0; r < 4; ++r) {
      const float v = o[r] + __shfl_xor(o[r], 8);
      if ((lane & 8) == 0)
        atomicAdd(&out[(size_t)(T * 16 + er0 + r) * 8 + c], v * PWRECs);
    }
  }
}

extern "C" void kernel_launch(void* const* d_in, const int* in_sizes, int n_in,
                              void* d_out, int out_size, void* d_ws, size_t ws_size,
                              hipStream_t stream) {
  (void)n_in; (void)ws_size;
  const float* x      = (const float*)d_in[0];
  const float* pos    = (const float*)d_in[1];
  const int*   ei     = (const int*)  d_in[2];
  const float* eattr  = (const float*)d_in[3];
  const int*   iei    = (const int*)  d_in[4];
  const float* emb_w0 = (const float*)d_in[5];
  const float* emb_w1 = (const float*)d_in[6];
  const float* imp0   = (const float*)d_in[7];
  const float* m0w0   = (const float*)d_in[8];
  const float* m0w1   = (const float*)d_in[9];
  const float* u0w0   = (const float*)d_in[10];
  const float* u0w1   = (const float*)d_in[11];
  const float* imp1   = (const float*)d_in[12];
  const float* m1w0   = (const float*)d_in[13];
  const float* m1w1   = (const float*)d_in[14];
  const float* u1w0   = (const float*)d_in[15];
  const float* u1w1   = (const float*)d_in[16];
  const float* lw0    = (const float*)d_in[17];
  const float* lw1    = (const float*)d_in[18];
  const float* rw0    = (const float*)d_in[19];
  const float* rw1    = (const float*)d_in[20];

  const int N  = in_sizes[1] / 3;
  const int E  = in_sizes[2] / 2;
  const int EI = in_sizes[4] / 2;

  float* node = (float*)d_ws;
  float* msgs = node + (size_t)N * 40;
  float* hL   = msgs + (size_t)N * 40;
  float* hR   = hL + (size_t)EI * 64;
  float* ligE = hR + (size_t)EI * 64;
  float* outp = (float*)d_out;

  // buffer reuse (sequential stream ordering makes this safe):
  //  - hPf (A-fragments, 5.12 MB) overwrites hL AFTER tp<1> consumed hL
  //  - Dt  (dot table,  5.12 MB) overwrites hR AFTER pack_h consumed hR
  uint4*          hPf = (uint4*)hL;
  unsigned short* Dt  = (unsigned short*)hR;

  const float inv_sqrt_deg = 1.0f / sqrtf((float)E / (float)N);
  const int nodeBlocks  = (N + 3) / 4;
  const int interBlocks = (EI + 3) / 4;
  const int nT = EI / 16;   // 2500 for this problem (EI divisible by 16)

  emb_kernel<<<nodeBlocks, 256, 0, stream>>>(x, emb_w0, emb_w1, node, N);

  // message pass 0
  hipMemsetAsync(msgs, 0, (size_t)N * 40 * sizeof(float), stream);
  tp_kernel<0><<<512, 512, 0, stream>>>(node, pos, ei, eattr, m0w0, m0w1, nullptr, msgs, E);
  upd_kernel<<<nodeBlocks, 256, 0, stream>>>(node, msgs, u0w0, u0w1, imp0, 1.0f, inv_sqrt_deg, N);

  // message pass 1
  hipMemsetAsync(msgs, 0, (size_t)N * 40 * sizeof(float), stream);
  tp_kernel<0><<<512, 512, 0, stream>>>(node, pos, ei, eattr, m1w0, m1w1, nullptr, msgs, E);
  upd_kernel<<<nodeBlocks, 256, 0, stream>>>(node, msgs, u1w0, u1w1, imp1, 0.5f, inv_sqrt_deg, N);

  // inter edges
  inter_h_kernel<<<interBlocks, 256, 0, stream>>>(pos, iei, lw0, rw0, hL, hR, EI);
  tp_kernel<1><<<512, 512, 0, stream>>>(node, pos, iei, nullptr, nullptr, lw1, hL, ligE, EI);

  // pack A-fragments (reads hR, writes over hL) and D-table (writes over hR)
  pack_h_kernel<<<(nT * 128 + 511) / 512, 512, 0, stream>>>(hR, hPf, nT);
  pack_d_kernel<<<(EI * 64 + 255) / 256, 256, 0, stream>>>(ligE, node, iei, Dt, EI);

  hipMemsetAsync(outp, 0, (size_t)out_size * sizeof(float), stream);
  rec_kernel<<<dim3(102, 5), 512, 0, stream>>>(node, ligE, iei, rw1, hPf, (const uint2*)Dt,
                                               outp, nT);
}

// Round 13
// 375.046 us; speedup vs baseline: 5.1032x; 1.3125x over previous
//
#include <hip/hip_runtime.h>
#include <hip/hip_fp16.h>
#include <cmath>

// ---- constants from the reference ----
constexpr float ACT_NORM = 1.6789717f;
constexpr float PW0      = 0.20412414523193154f;   // sqrt(1/24)  (== pw1/sqrt3)
constexpr float PW1      = 0.35355339059327373f;   // sqrt(3/24)
constexpr float PWREC    = 0.05590169943749474f;   // sqrt(1/320)
constexpr float INV_SQ3  = 0.57735026918962576f;
// second-layer 1/sqrt(64) folded into epilogue constants
constexpr float PW0s     = PW0 * 0.125f;
constexpr float PW1s     = PW1 * 0.125f;
constexpr float PWRECs   = PWREC * 0.125f;

__device__ __forceinline__ float silu_n(float x) {
  return x / (1.f + __expf(-x)) * ACT_NORM;
}

__device__ __forceinline__ unsigned ubcast_lane(unsigned v, int k) {
  return (unsigned)__builtin_amdgcn_readlane((int)v, k);
}

// fp16 helpers
typedef _Float16 h2v __attribute__((ext_vector_type(2)));
typedef _Float16 f16x8 __attribute__((ext_vector_type(8)));
typedef float    f32x4 __attribute__((ext_vector_type(4)));

__device__ __forceinline__ unsigned packh2(float a, float b) {
  h2v p; p.x = (_Float16)a; p.y = (_Float16)b;
  return __builtin_bit_cast(unsigned, p);
}
__device__ __forceinline__ unsigned short f16bits(float a) {
  return __builtin_bit_cast(unsigned short, (_Float16)a);
}
__device__ __forceinline__ float h2f(unsigned short b) {
  return (float)__builtin_bit_cast(_Float16, b);
}
__device__ __forceinline__ float dot2h(unsigned w2, unsigned h2, float acc) {
  return __builtin_amdgcn_fdot2(__builtin_bit_cast(h2v, w2),
                                __builtin_bit_cast(h2v, h2), acc, false);
}
__device__ __forceinline__ float hlo(unsigned d) {
  return (float)__builtin_bit_cast(_Float16, (unsigned short)(d & 0xffffu));
}
__device__ __forceinline__ float hhi(unsigned d) {
  return (float)__builtin_bit_cast(_Float16, (unsigned short)(d >> 16));
}
__device__ __forceinline__ float hsel(unsigned d, int hi) { return hi ? hhi(d) : hlo(d); }
__device__ __forceinline__ unsigned u4sel(const uint4& v, int i) {
  return i == 0 ? v.x : (i == 1 ? v.y : (i == 2 ? v.z : v.w));
}
__device__ __forceinline__ unsigned u2sel(const uint2& v, int i) { return i ? v.y : v.x; }

// mfma_f32_16x16x32_f16: A row = lane&15; B col = lane&15 (consistent k grouping);
// C/D: col=lane&15, row=(lane>>4)*4+reg [HW-verified C/D layout, m89 family;
// proven in-round by rec_kernel (round 12 passed)].
__device__ __forceinline__ f32x4 mfma16(uint4 a, uint4 b, f32x4 c) {
  return __builtin_amdgcn_mfma_f32_16x16x32_f16(
      __builtin_bit_cast(f16x8, a), __builtin_bit_cast(f16x8, b), c, 0, 0, 0);
}

// ---------------- node embedding: node[:, :16] = mlp(x), geo = 0 ----------------
__global__ __launch_bounds__(256)
void emb_kernel(const float* __restrict__ x, const float* __restrict__ w0,
                const float* __restrict__ w1, float* __restrict__ node, int N) {
  const int lane = threadIdx.x & 63;
  const int lw   = threadIdx.x >> 6;
  const int gw   = blockIdx.x * 4 + lw;
  __shared__ float sH[4][64];
  const bool valid = gw < N;
  const int n = valid ? gw : 0;
  float acc = 0.f;
#pragma unroll
  for (int a = 0; a < 10; ++a) acc = fmaf(x[n * 10 + a], w0[a * 64 + lane], acc);
  acc *= 0.31622776601683794f;   // 1/sqrt(10)
  sH[lw][lane] = silu_n(acc);
  __syncthreads();
  if (valid) {
    if (lane < 16) {
      float o = 0.f;
#pragma unroll
      for (int k = 0; k < 64; ++k) o = fmaf(sH[lw][k], w1[k * 16 + lane], o);
      node[(size_t)n * 40 + lane] = o * 0.125f;  // 1/sqrt(64)
    } else if (lane < 40) {
      node[(size_t)n * 40 + lane] = 0.f;
    }
  }
}

// ---------------- node update (per mp step) ----------------
__global__ __launch_bounds__(256)
void upd_kernel(float* __restrict__ node, const float* __restrict__ msgs,
                const float* __restrict__ w0, const float* __restrict__ w1,
                const float* __restrict__ imp, float geo_scale, float inv_sqrt_deg, int N) {
  const int lane = threadIdx.x & 63;
  const int lw   = threadIdx.x >> 6;
  const int gw   = blockIdx.x * 4 + lw;
  __shared__ float sIn[4][32];
  __shared__ float sH[4][64];
  const bool valid = gw < N;
  const int n = valid ? gw : 0;
  const float mscale = imp[0] * inv_sqrt_deg;
  if (lane < 16)      sIn[lw][lane] = msgs[(size_t)n * 40 + lane] * mscale;
  else if (lane < 32) sIn[lw][lane] = node[(size_t)n * 40 + lane - 16];
  __syncthreads();
  float acc = 0.f;
#pragma unroll
  for (int a = 0; a < 32; ++a) acc = fmaf(sIn[lw][a], w0[a * 64 + lane], acc);
  acc *= 0.17677669529663687f;   // 1/sqrt(32)
  sH[lw][lane] = silu_n(acc);
  __syncthreads();
  if (valid) {
    if (lane < 16) {
      float o = 0.f;
#pragma unroll
      for (int k = 0; k < 64; ++k) o = fmaf(sH[lw][k], w1[k * 16 + lane], o);
      node[(size_t)n * 40 + lane] = o * 0.125f;
    } else if (lane < 40) {
      const size_t gi = (size_t)n * 40 + lane;
      node[gi] = fmaf(msgs[gi], mscale, node[gi]) * geo_scale;
    }
  }
}

// ---------------- inter-edge: distance embedding -> both hidden vectors ----------------
__global__ __launch_bounds__(256)
void inter_h_kernel(const float* __restrict__ pos, const int* __restrict__ iei,
                    const float* __restrict__ lw0, const float* __restrict__ rw0,
                    float* __restrict__ hL, float* __restrict__ hR, int EI) {
  const int lane = threadIdx.x & 63;
  const int lw   = threadIdx.x >> 6;
  const int gw   = blockIdx.x * 4 + lw;
  __shared__ float sD[4][20];
  const bool valid = gw < EI;
  const int e = valid ? gw : 0;
  const int rec = iei[e], lig = iei[EI + e];
  const float dx = pos[lig * 3]     - pos[rec * 3];
  const float dy = pos[lig * 3 + 1] - pos[rec * 3 + 1];
  const float dz = pos[lig * 3 + 2] - pos[rec * 3 + 2];
  const float d = sqrtf(dx * dx + dy * dy + dz * dz);
  if (lane < 20) {
    const float diff = d * 4.2f - (float)(lane + 1);
    const float t1 = diff + 1.f, t2 = 1.f - diff;
    float v = 0.f;
    if (t1 > 0.f && t2 > 0.f) {
      const float C = 1.14136f * 7.3890560989306495f * 4.4721359549995794f; // 1.14136*e^2*sqrt(20)
      v = C * __expf(-1.f / t1 - 1.f / t2);
    }
    sD[lw][lane] = v;
  }
  __syncthreads();
  float a0 = 0.f, a1 = 0.f;
#pragma unroll
  for (int b = 0; b < 20; ++b) {
    const float db = sD[lw][b];
    a0 = fmaf(db, lw0[b * 64 + lane], a0);
    a1 = fmaf(db, rw0[b * 64 + lane], a1);
  }
  a0 *= 0.22360679774997896f;  // 1/sqrt(20)
  a1 *= 0.22360679774997896f;
  if (valid) {
    hL[(size_t)e * 64 + lane] = silu_n(a0);
    hR[(size_t)e * 64 + lane] = silu_n(a1);
  }
}

// ---------------- edge MLP layer for msg passes -> packed A-fragments ----------------
// hEf[T*128 + H*64 + l] = uint4 of 8 fp16 = h[T*16+(l&15)][H*32+(l>>4)*8 + 0..7],
// h = silu_n(eattr @ w0 / sqrt(5)) (unscaled; 1/8 folded into epilogue constants).
__global__ __launch_bounds__(256)
void edge_hf_kernel(const float* __restrict__ eattr, const float* __restrict__ w0,
                    const int* __restrict__ ei, uint4* __restrict__ hEf, int E, int nTe) {
  const int gid = blockIdx.x * 256 + threadIdx.x;
  if (gid >= nTe * 128) return;
  const int T = gid >> 7, rem = gid & 127, H = rem >> 6, l = rem & 63;
  (void)ei;
  int e = T * 16 + (l & 15);
  if (e >= E) e = E - 1;
  const int k0 = H * 32 + (l >> 4) * 8;
  float ea[5];
#pragma unroll
  for (int a = 0; a < 5; ++a) ea[a] = eattr[(size_t)e * 5 + a] * 0.4472135954999579f;
  unsigned q[4];
#pragma unroll
  for (int jj = 0; jj < 4; ++jj) {
    float hh[2];
#pragma unroll
    for (int p = 0; p < 2; ++p) {
      const int k = k0 + jj * 2 + p;
      float acc = 0.f;
#pragma unroll
      for (int a = 0; a < 5; ++a) acc = fmaf(ea[a], w0[a * 64 + k], acc);
      hh[p] = silu_n(acc);
    }
    q[jj] = packh2(hh[0], hh[1]);
  }
  uint4 out; out.x = q[0]; out.y = q[1]; out.z = q[2]; out.w = q[3];
  hEf[gid] = out;
}

// ---------------- msg pass: MFMA GEMM (h @ W1, all 576 cols) + fused TP epilogue ----
// Tile = 16 edges/wave. sB: all 36 ntiles fp16 (73728 B, staged once). Per-wave fW
// slice (56 half/edge): xs[0..15], xv[16+i*8+par*4+(u>>1)], r[40..42], dotp[48..55].
// Phase map (ntile t, lane col c=lane&15, cp=(lane>>3)&1):
//   t<16: o_s += xs[e][t]*C      ; t in [16,24): o_s += dotp[e][t-16]*C
//   t in [24,32): sxw += xs[e][2(t-24)+cp]*C ; t>=32: ov[i] += xv[e][2(t-32)+cp][i]*C
// out_s: unique (edge,c) per lane, no reduction. out_v: shfl_xor(8) pair-reduce.
__global__ __launch_bounds__(256, 2)
void msg_mfma_kernel(const float* __restrict__ node, const float* __restrict__ pos,
                     const int* __restrict__ ei, const float* __restrict__ W1,
                     const uint4* __restrict__ hEf, float* __restrict__ msgs,
                     int E, int nTe) {
  __shared__ __align__(16) uint4 sB[36 * 128];              // 73728 B
  __shared__ __align__(16) unsigned short sFt[4][16][56];   //  7168 B -> 80896 total
  const int tid = threadIdx.x, lane = tid & 63, wv = tid >> 6;

  // stage B fragments: sB[t*128+H*64+l] = W1[kb..kb+7][t*16+(l&15)], kb=H*32+(l>>4)*8
  for (int j = tid; j < 4608; j += 256) {
    const int t = j >> 7, H = (j >> 6) & 1, l = j & 63;
    const int kb = H * 32 + (l >> 4) * 8;
    const float* src = &W1[(size_t)kb * 576 + t * 16 + (l & 15)];
    uint4 q;
    q.x = packh2(src[0],       src[576]);
    q.y = packh2(src[2 * 576], src[3 * 576]);
    q.z = packh2(src[4 * 576], src[5 * 576]);
    q.w = packh2(src[6 * 576], src[7 * 576]);
    sB[j] = q;
  }
  __syncthreads();

  unsigned short (*fW)[56] = sFt[wv];
  const int er0 = (lane >> 4) * 4;
  const int c   = lane & 15;
  const int cp  = (lane >> 3) & 1;
  const int w   = c & 7;

  for (int T = blockIdx.x * 4 + wv; T < nTe; T += (int)gridDim.x * 4) {
    // ---- prologue: per-wave feature staging (same-wave LDS RAW, no barrier) ----
    if (lane < 16) {                         // r-hat
      int ge = T * 16 + lane; if (ge >= E) ge = E - 1;
      const int ia = ei[ge], ib = ei[E + ge];
      const float vx = pos[ib * 3]     - pos[ia * 3];
      const float vy = pos[ib * 3 + 1] - pos[ia * 3 + 1];
      const float vz = pos[ib * 3 + 2] - pos[ia * 3 + 2];
      const float rn = rsqrtf(vx * vx + vy * vy + vz * vz);
      fW[lane][40] = f16bits(vx * rn);
      fW[lane][41] = f16bits(vy * rn);
      fW[lane][42] = f16bits(vz * rn);
    }
#pragma unroll
    for (int j = 0; j < 4; ++j) {            // xs: e = j*4+(lane>>4), u = c
      const int e = j * 4 + (lane >> 4);
      int ge = T * 16 + e; if (ge >= E) ge = E - 1;
      const int ns = ei[ge];
      fW[e][c] = f16bits(node[(size_t)ns * 40 + c]);
    }
#pragma unroll
    for (int j = 0; j < 6; ++j) {            // xv: flat = e*24 + (u*3+i)
      const int flat = j * 64 + lane;
      const int e = flat / 24, q = flat - e * 24;
      const int u = q / 3, i = q - u * 3;
      int ge = T * 16 + e; if (ge >= E) ge = E - 1;
      const int ns = ei[ge];
      fW[e][16 + i * 8 + (u & 1) * 4 + (u >> 1)] = f16bits(node[(size_t)ns * 40 + 16 + q]);
    }
#pragma unroll
    for (int j = 0; j < 2; ++j) {            // dotp[e][u] = sum_i xv*rhat
      const int flat = j * 64 + lane;
      const int e = flat >> 3, u = flat & 7;
      float d = 0.f;
#pragma unroll
      for (int i = 0; i < 3; ++i)
        d = fmaf(h2f(fW[e][16 + i * 8 + (u & 1) * 4 + (u >> 1)]), h2f(fW[e][40 + i]), d);
      fW[e][48 + u] = f16bits(d);
    }

    const uint4 a0 = hEf[T * 128 + lane];
    const uint4 a1 = hEf[T * 128 + 64 + lane];

    // feature registers (static-indexed in the unrolled loop)
    uint4 xsR[4][2], dpR[4];
    uint2 xvR[4][3];
    float rf[4][3];
#pragma unroll
    for (int r = 0; r < 4; ++r) {
      const int e = er0 + r;
      xsR[r][0] = *(const uint4*)&fW[e][0];
      xsR[r][1] = *(const uint4*)&fW[e][8];
      dpR[r]    = *(const uint4*)&fW[e][48];
#pragma unroll
      for (int i = 0; i < 3; ++i) {
        xvR[r][i] = *(const uint2*)&fW[e][16 + i * 8 + cp * 4];
        rf[r][i]  = h2f(fW[e][40 + i]);
      }
    }

    float o_s[4] = {0.f, 0.f, 0.f, 0.f};
    float sxw[4] = {0.f, 0.f, 0.f, 0.f};
    float ov[3][4];
#pragma unroll
    for (int i = 0; i < 3; ++i)
#pragma unroll
      for (int r = 0; r < 4; ++r) ov[i][r] = 0.f;

    uint4 b0 = sB[lane], b1 = sB[64 + lane];
#pragma unroll
    for (int t = 0; t < 36; ++t) {
      uint4 n0, n1;
      if (t < 35) { n0 = sB[(t + 1) * 128 + lane]; n1 = sB[(t + 1) * 128 + 64 + lane]; }
      f32x4 C = {0.f, 0.f, 0.f, 0.f};
      C = mfma16(a0, b0, C);
      C = mfma16(a1, b1, C);
      if (t < 16) {
#pragma unroll
        for (int r = 0; r < 4; ++r)
          o_s[r] = fmaf(hsel(u4sel(xsR[r][t >> 3], (t >> 1) & 3), t & 1), C[r], o_s[r]);
      } else if (t < 24) {
        const int u = t - 16;
#pragma unroll
        for (int r = 0; r < 4; ++r)
          o_s[r] = fmaf(hsel(u4sel(dpR[r], u >> 1), u & 1), C[r], o_s[r]);
      } else if (t < 32) {
        const int j = t - 24;  // u = 2j+cp
#pragma unroll
        for (int r = 0; r < 4; ++r) {
          const int idx = 2 * j + cp;
          sxw[r] = fmaf(hsel(u4sel(xsR[r][idx >> 3], (idx >> 1) & 3), idx & 1), C[r], sxw[r]);
        }
      } else {
        const int j = t - 32;  // u = 2j+cp
#pragma unroll
        for (int i = 0; i < 3; ++i)
#pragma unroll
          for (int r = 0; r < 4; ++r)
            ov[i][r] = fmaf(hsel(u2sel(xvR[r][i], j >> 1), j & 1), C[r], ov[i][r]);
      }
      if (t < 35) { b0 = n0; b1 = n1; }
    }

    // ---- write ----
#pragma unroll
    for (int r = 0; r < 4; ++r) {
      const int ge = T * 16 + er0 + r;
      const bool valid = ge < E;
      const int dst = ei[E + (valid ? ge : 0)];
      if (valid) atomicAdd(&msgs[(size_t)dst * 40 + c], PW0s * o_s[r]);
#pragma unroll
      for (int i = 0; i < 3; ++i) {
        float v = fmaf(PW1s * rf[r][i], sxw[r], PW0s * ov[i][r]);
        v += __shfl_xor(v, 8);
        if (valid && (lane & 8) == 0)
          atomicAdd(&msgs[(size_t)dst * 40 + 16 + w * 3 + i], v);
      }
    }
  }
}

// ---------------- fused edge MLP (layer2) + node x sh tensor product (dot2) ---------
// Retained for MODE1 (lig TP) only — proven round-10 kernel.
template <int MODE>
__global__ __launch_bounds__(512, 2)
void tp_kernel(const float* __restrict__ node, const float* __restrict__ pos,
               const int* __restrict__ ei, const float* __restrict__ eattr,
               const float* __restrict__ w0, const float* __restrict__ W1,
               const float* __restrict__ hSrc, float* __restrict__ out, int E) {
  __shared__ __align__(16) uint4 sWa[32 * 64];
  __shared__ __align__(16) uint4 sWb[32 * 64];
  __shared__ unsigned sWc[32 * 64];
  __shared__ float sF[8][6][27];
  const int tid  = threadIdx.x;
  const int lane = tid & 63;
  const int wv   = tid >> 6;

  for (int j = tid; j < 2048; j += 512) {
    const int kp = j >> 6, l = j & 63;
    const float* s0 = &W1[(2 * kp) * 576 + l];
    const float* s1 = s0 + 576;
    uint4 qa, qb;
    qa.x = packh2(s0[0],   s1[0]);
    qa.y = packh2(s0[64],  s1[64]);
    qa.z = packh2(s0[128], s1[128]);
    qa.w = packh2(s0[192], s1[192]);
    qb.x = packh2(s0[256], s1[256]);
    qb.y = packh2(s0[320], s1[320]);
    qb.z = packh2(s0[384], s1[384]);
    qb.w = packh2(s0[448], s1[448]);
    sWa[j] = qa;
    sWb[j] = qb;
    sWc[j] = packh2(s0[512], s1[512]);
  }
  __syncthreads();

  float w0r[5];
  if (MODE == 0) {
#pragma unroll
    for (int a = 0; a < 5; ++a) w0r[a] = w0[a * 64 + lane] * 0.4472135954999579f;
  }
  const int kl2 = (lane & 31) * 2;

  const int nB = (E + 47) / 48;
  for (int b = blockIdx.x; b < nB; b += (int)gridDim.x) {
    const int ebase = b * 48 + wv * 6;
    int outn[6], nsrc[6];
    bool val[6];
    unsigned hp[6];
#pragma unroll
    for (int s = 0; s < 6; ++s) {
      const int e0 = ebase + s;
      val[s] = e0 < E;
      const int e = val[s] ? e0 : 0;
      const int ia = ei[e], ib = ei[E + e];
      if (MODE == 0) { nsrc[s] = ia; outn[s] = ib; }
      else           { nsrc[s] = ib; outn[s] = e;  }
      const float vx = pos[ib * 3]     - pos[ia * 3];
      const float vy = pos[ib * 3 + 1] - pos[ia * 3 + 1];
      const float vz = pos[ib * 3 + 2] - pos[ia * 3 + 2];
      const float rn = rsqrtf(vx * vx + vy * vy + vz * vz);
      const float rx = vx * rn, ry = vy * rn, rz = vz * rn;
      float h;
      if (MODE == 0) {
        float acc = 0.f;
#pragma unroll
        for (int a = 0; a < 5; ++a) acc = fmaf(eattr[(size_t)e * 5 + a], w0r[a], acc);
        h = silu_n(acc);
      } else {
        h = hSrc[(size_t)e * 64 + lane];
      }
      hp[s] = packh2(__shfl(h, kl2), __shfl(h, kl2 + 1));
      if (lane < 16) {
        sF[wv][s][lane] = node[(size_t)nsrc[s] * 40 + lane];
      } else if (lane < 24) {
        const int u = lane - 16;
        const float x0 = node[(size_t)nsrc[s] * 40 + 16 + u * 3];
        const float x1 = node[(size_t)nsrc[s] * 40 + 16 + u * 3 + 1];
        const float x2 = node[(size_t)nsrc[s] * 40 + 16 + u * 3 + 2];
        sF[wv][s][16 + u] = x0 * rx + x1 * ry + x2 * rz;
      } else if (lane < 27) {
        sF[wv][s][24 + (lane - 24)] = (lane == 24) ? rx : ((lane == 25) ? ry : rz);
      }
    }

    float wacc[6][9];
#pragma unroll
    for (int s = 0; s < 6; ++s)
#pragma unroll
      for (int t = 0; t < 9; ++t) wacc[s][t] = 0.f;

    uint4 qa0 = sWa[lane], qb0 = sWb[lane];
    unsigned qc0 = sWc[lane];
#pragma unroll 4
    for (int kp = 0; kp < 32; ++kp) {
      const int kn = (kp + 1) & 31;
      const uint4 qa1 = sWa[kn * 64 + lane];
      const uint4 qb1 = sWb[kn * 64 + lane];
      const unsigned qc1 = sWc[kn * 64 + lane];
#pragma unroll
      for (int s = 0; s < 6; ++s) {
        const unsigned hv2 = ubcast_lane(hp[s], kp);
        wacc[s][0] = dot2h(qa0.x, hv2, wacc[s][0]);
        wacc[s][1] = dot2h(qa0.y, hv2, wacc[s][1]);
        wacc[s][2] = dot2h(qa0.z, hv2, wacc[s][2]);
        wacc[s][3] = dot2h(qa0.w, hv2, wacc[s][3]);
        wacc[s][4] = dot2h(qb0.x, hv2, wacc[s][4]);
        wacc[s][5] = dot2h(qb0.y, hv2, wacc[s][5]);
        wacc[s][6] = dot2h(qb0.z, hv2, wacc[s][6]);
        wacc[s][7] = dot2h(qb0.w, hv2, wacc[s][7]);
        wacc[s][8] = dot2h(qc0,   hv2, wacc[s][8]);
      }
      qa0 = qa1; qb0 = qb1; qc0 = qc1;
    }

    const int ub  = lane >> 4;
    const int ub2 = lane >> 3;
#pragma unroll
    for (int s = 0; s < 6; ++s) {
      float cs = 0.f;
#pragma unroll
      for (int t = 0; t < 6; ++t)
        cs = fmaf(PW0s * sF[wv][s][ub + 4 * t], wacc[s][t], cs);
      cs += __shfl_xor(cs, 16);
      cs += __shfl_xor(cs, 32);

      const float rx = sF[wv][s][24], ry = sF[wv][s][25], rz = sF[wv][s][26];
      const float* xp = &node[(size_t)nsrc[s] * 40 + 16 + ub2 * 3];
      const float xv0 = xp[0], xv1 = xp[1], xv2 = xp[2];
      const float sxw = PW1s * (sF[wv][s][ub2] * wacc[s][6] + sF[wv][s][ub2 + 8] * wacc[s][7]);
      float cv0 = fmaf(PW0s * xv0, wacc[s][8], sxw * rx);
      float cv1 = fmaf(PW0s * xv1, wacc[s][8], sxw * ry);
      float cv2 = fmaf(PW0s * xv2, wacc[s][8], sxw * rz);
      cv0 += __shfl_xor(cv0, 8); cv0 += __shfl_xor(cv0, 16); cv0 += __shfl_xor(cv0, 32);
      cv1 += __shfl_xor(cv1, 8); cv1 += __shfl_xor(cv1, 16); cv1 += __shfl_xor(cv1, 32);
      cv2 += __shfl_xor(cv2, 8); cv2 += __shfl_xor(cv2, 16); cv2 += __shfl_xor(cv2, 32);

      if (val[s]) {
        const size_t ob = (size_t)outn[s] * 40;
        if (MODE == 0) {
          if (lane < 16) atomicAdd(&out[ob + lane], cs);
          if (lane < 8) {
            atomicAdd(&out[ob + 16 + lane * 3],     cv0);
            atomicAdd(&out[ob + 16 + lane * 3 + 1], cv1);
            atomicAdd(&out[ob + 16 + lane * 3 + 2], cv2);
          }
        } else {
          if (lane < 16) out[ob + lane] = cs;
          if (lane < 8) {
            out[ob + 16 + lane * 3]     = cv0;
            out[ob + 16 + lane * 3 + 1] = cv1;
            out[ob + 16 + lane * 3 + 2] = cv2;
          }
        }
      }
    }
  }
}

// ---------------- pack hR into MFMA A-fragments (fp16) ----------------
__global__ __launch_bounds__(512)
void pack_h_kernel(const float* __restrict__ h, uint4* __restrict__ hPf, int nT) {
  const int gid = blockIdx.x * 512 + threadIdx.x;
  if (gid >= nT * 128) return;
  const int l = gid & 63;
  const int H = (gid >> 6) & 1;
  const int T = gid >> 7;
  const int e = T * 16 + (l & 15);
  const int kb = H * 32 + (l >> 4) * 8;
  const float* src = &h[(size_t)e * 64 + kb];
  uint4 q;
  q.x = packh2(src[0], src[1]);
  q.y = packh2(src[2], src[3]);
  q.z = packh2(src[4], src[5]);
  q.w = packh2(src[6], src[7]);
  hPf[gid] = q;
}

// ---------------- precompute vector-path dot table (fp16, parity-separated) --------
__global__ __launch_bounds__(256)
void pack_d_kernel(const float* __restrict__ ligE, const float* __restrict__ node,
                   const int* __restrict__ iei, unsigned short* __restrict__ Dt, int EI) {
  const int gid = blockIdx.x * 256 + threadIdx.x;
  if (gid >= EI * 64) return;
  const int e = gid >> 6, rem = gid & 63;
  const int b = rem >> 5, u = (rem >> 2) & 7, vi = rem & 3;
  const int v = 2 * vi + b;
  const int rec = iei[e];
  const float* xp = &ligE[(size_t)e * 40 + 16 + u * 3];
  const float* yp = &node[(size_t)rec * 40 + 16 + v * 3];
  const float d = (xp[0] * yp[0] + xp[1] * yp[1] + xp[2] * yp[2]) * INV_SQ3;
  Dt[gid] = f16bits(d);
}

// ---------------- rec: MFMA GEMM (h @ RW1 chunk) + fused TP epilogue ----------------
__global__ __launch_bounds__(512, 2)
void rec_kernel(const float* __restrict__ node, const float* __restrict__ ligE,
                const int* __restrict__ iei, const float* __restrict__ RW1,
                const uint4* __restrict__ hPf, const uint2* __restrict__ Dt2,
                float* __restrict__ out, int nT) {
  __shared__ __align__(16) uint4 sB[4096];
  __shared__ __align__(16) unsigned short sFeat[8][320];
  const int tid = threadIdx.x, lane = tid & 63, wv = tid >> 6;
  const int cg = blockIdx.y;

  for (int j = tid; j < 4096; j += 512) {
    const int t = j >> 7, H = (j >> 6) & 1, l = j & 63;
    const int kb = H * 32 + (l >> 4) * 8;
    const float* src = &RW1[(size_t)kb * 2560 + cg * 512 + t * 16 + (l & 15)];
    uint4 q;
    q.x = packh2(src[0],        src[2560]);
    q.y = packh2(src[2 * 2560], src[3 * 2560]);
    q.z = packh2(src[4 * 2560], src[5 * 2560]);
    q.w = packh2(src[6 * 2560], src[7 * 2560]);
    sB[j] = q;
  }
  __syncthreads();

  unsigned short* fW = sFeat[wv];
  const int er0 = (lane >> 4) * 4;
  const int bpar = (lane >> 3) & 1;
  const int c    = lane & 7;
  const int se = lane >> 2, si = lane & 3;

  for (int T = blockIdx.x * 8 + wv; T < nT; T += (int)gridDim.x * 8) {
    const uint4 a0 = hPf[(T * 2 + 0) * 64 + lane];
    const uint4 a1 = hPf[(T * 2 + 1) * 64 + lane];
    const int eg = T * 16 + se;

    if (cg < 4) {
      const int rn = iei[eg];
      const float4 yv = *(const float4*)&node[(size_t)rn * 40 + si * 4];
      *(unsigned*)&fW[(se * 2 + 0) * 8 + 2 * si] = packh2(yv.x, yv.z);
      *(unsigned*)&fW[(se * 2 + 1) * 8 + 2 * si] = packh2(yv.y, yv.w);
      fW[256 + se * 4 + si] = f16bits(ligE[(size_t)eg * 40 + cg * 4 + si]);
    }

    float o[4] = {0.f, 0.f, 0.f, 0.f};
    uint4 b0 = sB[lane], b1 = sB[64 + lane];

    if (cg < 4) {
      uint2 xsR[4]; uint4 ysR[4];
#pragma unroll
      for (int r = 0; r < 4; ++r) {
        const int er = er0 + r;
        ysR[r] = *(const uint4*)&fW[(er * 2 + bpar) * 8];
        xsR[r] = *(const uint2*)&fW[256 + er * 4];
      }
#pragma unroll
      for (int t = 0; t < 32; ++t) {
        uint4 n0, n1;
        if (t < 31) { n0 = sB[(t + 1) * 128 + lane]; n1 = sB[(t + 1) * 128 + 64 + lane]; }
        f32x4 C = {0.f, 0.f, 0.f, 0.f};
        C = mfma16(a0, b0, C);
        C = mfma16(a1, b1, C);
        const int up = t >> 3, vi = t & 7;
#pragma unroll
        for (int r = 0; r < 4; ++r) {
          const float xs = hsel(u2sel(xsR[r], up >> 1), up & 1);
          const float ys = hsel(u4sel(ysR[r], vi >> 1), vi & 1);
          o[r] = fmaf(xs * ys, C[r], o[r]);
        }
        if (t < 31) { b0 = n0; b1 = n1; }
      }
    } else {
#pragma unroll
      for (int pass = 0; pass < 2; ++pass) {
        uint2 dR[4][4];
#pragma unroll
        for (int r = 0; r < 4; ++r) {
          const int e = T * 16 + er0 + r;
#pragma unroll
          for (int uu = 0; uu < 4; ++uu)
            dR[r][uu] = Dt2[(size_t)e * 16 + bpar * 8 + pass * 4 + uu];
        }
#pragma unroll
        for (int tt = 0; tt < 16; ++tt) {
          const int t = pass * 16 + tt;
          uint4 n0, n1;
          if (t < 31) { n0 = sB[(t + 1) * 128 + lane]; n1 = sB[(t + 1) * 128 + 64 + lane]; }
          f32x4 C = {0.f, 0.f, 0.f, 0.f};
          C = mfma16(a0, b0, C);
          C = mfma16(a1, b1, C);
          const int uu = tt >> 2, vi = tt & 3;
#pragma unroll
          for (int r = 0; r < 4; ++r) {
            const float f = hsel(u2sel(dR[r][uu], vi >> 1), vi & 1);
            o[r] = fmaf(f, C[r], o[r]);
          }
          if (t < 31) { b0 = n0; b1 = n1; }
        }
      }
    }

#pragma unroll
    for (int r = 0; r < 4; ++r) {
      const float v = o[r] + __shfl_xor(o[r], 8);
      if ((lane & 8) == 0)
        atomicAdd(&out[(size_t)(T * 16 + er0 + r) * 8 + c], v * PWRECs);
    }
  }
}

extern "C" void kernel_launch(void* const* d_in, const int* in_sizes, int n_in,
                              void* d_out, int out_size, void* d_ws, size_t ws_size,
                              hipStream_t stream) {
  (void)n_in; (void)ws_size;
  const float* x      = (const float*)d_in[0];
  const float* pos    = (const float*)d_in[1];
  const int*   ei     = (const int*)  d_in[2];
  const float* eattr  = (const float*)d_in[3];
  const int*   iei    = (const int*)  d_in[4];
  const float* emb_w0 = (const float*)d_in[5];
  const float* emb_w1 = (const float*)d_in[6];
  const float* imp0   = (const float*)d_in[7];
  const float* m0w0   = (const float*)d_in[8];
  const float* m0w1   = (const float*)d_in[9];
  const float* u0w0   = (const float*)d_in[10];
  const float* u0w1   = (const float*)d_in[11];
  const float* imp1   = (const float*)d_in[12];
  const float* m1w0   = (const float*)d_in[13];
  const float* m1w1   = (const float*)d_in[14];
  const float* u1w0   = (const float*)d_in[15];
  const float* u1w1   = (const float*)d_in[16];
  const float* lw0    = (const float*)d_in[17];
  const float* lw1    = (const float*)d_in[18];
  const float* rw0    = (const float*)d_in[19];
  const float* rw1    = (const float*)d_in[20];

  const int N  = in_sizes[1] / 3;
  const int E  = in_sizes[2] / 2;
  const int EI = in_sizes[4] / 2;

  float* node = (float*)d_ws;
  float* msgs = node + (size_t)N * 40;
  float* hL   = msgs + (size_t)N * 40;
  float* hR   = hL + (size_t)EI * 64;
  float* ligE = hR + (size_t)EI * 64;
  float* outp = (float*)d_out;

  // buffer reuse (sequential stream ordering makes this safe):
  //  - hEf (msg A-fragments, 15.36 MB) lives in hL∪hR region, used only during
  //    msg passes (inter_h overwrites afterwards; region is 20.48 MB)
  //  - hPf (rec A-fragments) overwrites hL AFTER tp<1> consumed hL
  //  - Dt  (dot table) overwrites hR AFTER pack_h consumed hR
  uint4*          hEf = (uint4*)hL;
  uint4*          hPf = (uint4*)hL;
  unsigned short* Dt  = (unsigned short*)hR;

  const float inv_sqrt_deg = 1.0f / sqrtf((float)E / (float)N);
  const int nodeBlocks  = (N + 3) / 4;
  const int interBlocks = (EI + 3) / 4;
  const int nT  = EI / 16;             // 2500 (EI divisible by 16)
  const int nTe = (E + 15) / 16;       // 7500
  const int hfBlocks = (nTe * 128 + 255) / 256;

  emb_kernel<<<nodeBlocks, 256, 0, stream>>>(x, emb_w0, emb_w1, node, N);

  // message pass 0
  edge_hf_kernel<<<hfBlocks, 256, 0, stream>>>(eattr, m0w0, ei, hEf, E, nTe);
  hipMemsetAsync(msgs, 0, (size_t)N * 40 * sizeof(float), stream);
  msg_mfma_kernel<<<512, 256, 0, stream>>>(node, pos, ei, m0w1, hEf, msgs, E, nTe);
  upd_kernel<<<nodeBlocks, 256, 0, stream>>>(node, msgs, u0w0, u0w1, imp0, 1.0f, inv_sqrt_deg, N);

  // message pass 1
  edge_hf_kernel<<<hfBlocks, 256, 0, stream>>>(eattr, m1w0, ei, hEf, E, nTe);
  hipMemsetAsync(msgs, 0, (size_t)N * 40 * sizeof(float), stream);
  msg_mfma_kernel<<<512, 256, 0, stream>>>(node, pos, ei, m1w1, hEf, msgs, E, nTe);
  upd_kernel<<<nodeBlocks, 256, 0, stream>>>(node, msgs, u1w0, u1w1, imp1, 0.5f, inv_sqrt_deg, N);

  // inter edges
  inter_h_kernel<<<interBlocks, 256, 0, stream>>>(pos, iei, lw0, rw0, hL, hR, EI);
  tp_kernel<1><<<512, 512, 0, stream>>>(node, pos, iei, nullptr, nullptr, lw1, hL, ligE, EI);

  // pack A-fragments (reads hR, writes over hL) and D-table (writes over hR)
  pack_h_kernel<<<(nT * 128 + 511) / 512, 512, 0, stream>>>(hR, hPf, nT);
  pack_d_kernel<<<(EI * 64 + 255) / 256, 256, 0, stream>>>(ligE, node, iei, Dt, EI);

  hipMemsetAsync(outp, 0, (size_t)out_size * sizeof(float), stream);
  rec_kernel<<<dim3(102, 5), 512, 0, stream>>>(node, ligE, iei, rw1, hPf, (const uint2*)Dt,
                                               outp, nT);
}